// Round 1
// baseline (486.731 us; speedup 1.0000x reference)
//
#include <hip/hip_runtime.h>

#define L 1024
#define DM 1024
#define NH 16
#define DK 64
#define M_TOT 2048  // B*L

// ---------------------------------------------------------------------------
// Shared GEMM microkernel pattern: C = A @ B^T-ish with 64x64 tile, BK=64,
// 256 threads, 4x4 microtile. LDS staged transposed so inner loop is
// float4 (ds_read_b128) loads: At[kk][m], Bt[kk][n].
// ---------------------------------------------------------------------------

// Projection: Y = X @ W^T.  X:(2048,1024) row-major, W:(1024,1024) [out][in].
// Output in (B,H,L,DK) layout. grid (16 ntiles, 32 mtiles, 3 which).
__global__ __launch_bounds__(256) void proj_qkv(
    const float* __restrict__ xq, const float* __restrict__ xk, const float* __restrict__ xv,
    const float* __restrict__ wq, const float* __restrict__ wk, const float* __restrict__ wv,
    float* __restrict__ Qp, float* __restrict__ Kp, float* __restrict__ Vp)
{
    const int z = blockIdx.z;
    const float* X = z == 0 ? xq : (z == 1 ? xk : xv);
    const float* W = z == 0 ? wq : (z == 1 ? wk : wv);
    float*       O = z == 0 ? Qp : (z == 1 ? Kp : Vp);

    __shared__ float At[64][68];
    __shared__ float Bt[64][68];

    const int t = threadIdx.x;
    const int tx = t & 15, ty = t >> 4;
    const int mbase = blockIdx.y * 64;
    const int nbase = blockIdx.x * 64;

    float acc[4][4] = {};

    for (int kt = 0; kt < 16; ++kt) {
        const int kbase = kt * 64;
#pragma unroll
        for (int r = 0; r < 4; ++r) {
            int f = t + 256 * r;           // 0..1023
            int mm = f >> 4;               // 0..63
            int kg = (f & 15) << 2;        // 0..60
            float4 a4 = *(const float4*)&X[(size_t)(mbase + mm) * DM + kbase + kg];
            At[kg + 0][mm] = a4.x; At[kg + 1][mm] = a4.y;
            At[kg + 2][mm] = a4.z; At[kg + 3][mm] = a4.w;
            float4 b4 = *(const float4*)&W[(size_t)(nbase + mm) * DM + kbase + kg];
            Bt[kg + 0][mm] = b4.x; Bt[kg + 1][mm] = b4.y;
            Bt[kg + 2][mm] = b4.z; Bt[kg + 3][mm] = b4.w;
        }
        __syncthreads();
#pragma unroll 8
        for (int kk = 0; kk < 64; ++kk) {
            float4 av = *(const float4*)&At[kk][ty * 4];
            float4 bv = *(const float4*)&Bt[kk][tx * 4];
            float aa[4] = {av.x, av.y, av.z, av.w};
            float bb[4] = {bv.x, bv.y, bv.z, bv.w};
#pragma unroll
            for (int i = 0; i < 4; ++i)
#pragma unroll
                for (int j = 0; j < 4; ++j)
                    acc[i][j] = fmaf(aa[i], bb[j], acc[i][j]);
        }
        __syncthreads();
    }
#pragma unroll
    for (int i = 0; i < 4; ++i) {
        int m = mbase + ty * 4 + i;        // m = b*L + l
        int b = m >> 10, l = m & 1023;
#pragma unroll
        for (int j = 0; j < 4; ++j) {
            int n = nbase + tx * 4 + j;    // n = h*64 + d
            int h = n >> 6, d = n & 63;
            O[(size_t)((b * NH + h) * L + l) * DK + d] = acc[i][j];
        }
    }
}

// Output projection: out = AO @ Wo^T, plain (2048,1024) output.
__global__ __launch_bounds__(256) void out_proj(
    const float* __restrict__ X, const float* __restrict__ W, float* __restrict__ O)
{
    __shared__ float At[64][68];
    __shared__ float Bt[64][68];

    const int t = threadIdx.x;
    const int tx = t & 15, ty = t >> 4;
    const int mbase = blockIdx.y * 64;
    const int nbase = blockIdx.x * 64;

    float acc[4][4] = {};

    for (int kt = 0; kt < 16; ++kt) {
        const int kbase = kt * 64;
#pragma unroll
        for (int r = 0; r < 4; ++r) {
            int f = t + 256 * r;
            int mm = f >> 4;
            int kg = (f & 15) << 2;
            float4 a4 = *(const float4*)&X[(size_t)(mbase + mm) * DM + kbase + kg];
            At[kg + 0][mm] = a4.x; At[kg + 1][mm] = a4.y;
            At[kg + 2][mm] = a4.z; At[kg + 3][mm] = a4.w;
            float4 b4 = *(const float4*)&W[(size_t)(nbase + mm) * DM + kbase + kg];
            Bt[kg + 0][mm] = b4.x; Bt[kg + 1][mm] = b4.y;
            Bt[kg + 2][mm] = b4.z; Bt[kg + 3][mm] = b4.w;
        }
        __syncthreads();
#pragma unroll 8
        for (int kk = 0; kk < 64; ++kk) {
            float4 av = *(const float4*)&At[kk][ty * 4];
            float4 bv = *(const float4*)&Bt[kk][tx * 4];
            float aa[4] = {av.x, av.y, av.z, av.w};
            float bb[4] = {bv.x, bv.y, bv.z, bv.w};
#pragma unroll
            for (int i = 0; i < 4; ++i)
#pragma unroll
                for (int j = 0; j < 4; ++j)
                    acc[i][j] = fmaf(aa[i], bb[j], acc[i][j]);
        }
        __syncthreads();
    }
#pragma unroll
    for (int i = 0; i < 4; ++i) {
        int m = mbase + ty * 4 + i;
#pragma unroll
        for (int j = 0; j < 4; ++j) {
            int n = nbase + tx * 4 + j;
            O[(size_t)m * DM + n] = acc[i][j];
        }
    }
}

// Scores: S = (Q K^T) / 16  (scores/8 from ref, then /2 from entmax prologue),
// masked to -3e38. Per (b,h): 1024x1024, K-dim = 64 (single stage).
// grid (16 ntiles, 16 mtiles, chunk).
__global__ __launch_bounds__(256) void qk_scores(
    const float* __restrict__ Qp, const float* __restrict__ Kp,
    const int* __restrict__ mask, float* __restrict__ S, int bh0)
{
    const int z = blockIdx.z;
    const int bh = bh0 + z;
    const float* Q = Qp + (size_t)bh * L * DK;
    const float* K = Kp + (size_t)bh * L * DK;
    float* Sz = S + (size_t)z * L * L;

    __shared__ float Qt[64][68];
    __shared__ float Kt[64][68];

    const int t = threadIdx.x;
    const int tx = t & 15, ty = t >> 4;
    const int mbase = blockIdx.y * 64;
    const int nbase = blockIdx.x * 64;

#pragma unroll
    for (int r = 0; r < 4; ++r) {
        int f = t + 256 * r;
        int mm = f >> 4;
        int kg = (f & 15) << 2;
        float4 a4 = *(const float4*)&Q[(size_t)(mbase + mm) * DK + kg];
        Qt[kg + 0][mm] = a4.x; Qt[kg + 1][mm] = a4.y;
        Qt[kg + 2][mm] = a4.z; Qt[kg + 3][mm] = a4.w;
        float4 b4 = *(const float4*)&K[(size_t)(nbase + mm) * DK + kg];
        Kt[kg + 0][mm] = b4.x; Kt[kg + 1][mm] = b4.y;
        Kt[kg + 2][mm] = b4.z; Kt[kg + 3][mm] = b4.w;
    }
    __syncthreads();

    float acc[4][4] = {};
#pragma unroll 8
    for (int kk = 0; kk < 64; ++kk) {
        float4 av = *(const float4*)&Qt[kk][ty * 4];
        float4 bv = *(const float4*)&Kt[kk][tx * 4];
        float aa[4] = {av.x, av.y, av.z, av.w};
        float bb[4] = {bv.x, bv.y, bv.z, bv.w};
#pragma unroll
        for (int i = 0; i < 4; ++i)
#pragma unroll
            for (int j = 0; j < 4; ++j)
                acc[i][j] = fmaf(aa[i], bb[j], acc[i][j]);
    }

#pragma unroll
    for (int i = 0; i < 4; ++i) {
        int row = mbase + ty * 4 + i;   // l index
        int col0 = nbase + tx * 4;
        int4 mk = *(const int4*)&mask[(size_t)row * L + col0];
        int mv[4] = {mk.x, mk.y, mk.z, mk.w};
        float4 ov;
        float* op = &ov.x;
#pragma unroll
        for (int j = 0; j < 4; ++j) {
            float sv = acc[i][j] * 0.0625f;
            op[j] = (mv[j] == 0) ? -3.0e38f : sv;
        }
        *(float4*)&Sz[(size_t)row * L + col0] = ov;
    }
}

// Entmax-1.5 per row, in place on S. One wave per row; row held in 16
// regs/lane. tau via 12 bisections + 4 Newton steps on
// f(tau) = sum relu(x - tau)^2 - 1  (convex, decreasing; root in [-1,0]).
__global__ __launch_bounds__(256) void entmax_rows(float* __restrict__ S, int nrows)
{
    const int wave = threadIdx.x >> 6;
    const int lane = threadIdx.x & 63;
    const int row = blockIdx.x * 4 + wave;
    if (row >= nrows) return;
    float* Sr = S + (size_t)row * L;

    float x[16];
#pragma unroll
    for (int s = 0; s < 4; ++s) {
        float4 v = *(const float4*)&Sr[s * 256 + lane * 4];
        x[s * 4 + 0] = v.x; x[s * 4 + 1] = v.y;
        x[s * 4 + 2] = v.z; x[s * 4 + 3] = v.w;
    }

    float mx = x[0];
#pragma unroll
    for (int i = 1; i < 16; ++i) mx = fmaxf(mx, x[i]);
#pragma unroll
    for (int off = 32; off; off >>= 1) mx = fmaxf(mx, __shfl_xor(mx, off));
#pragma unroll
    for (int i = 0; i < 16; ++i) x[i] -= mx;

    float lo = -1.0f, hi = 0.0f;
    for (int it = 0; it < 12; ++it) {
        float mid = 0.5f * (lo + hi);
        float f = 0.0f;
#pragma unroll
        for (int i = 0; i < 16; ++i) {
            float r = fmaxf(x[i] - mid, 0.0f);
            f = fmaf(r, r, f);
        }
#pragma unroll
        for (int off = 32; off; off >>= 1) f += __shfl_xor(f, off);
        if (f >= 1.0f) lo = mid; else hi = mid;
    }
    float tau = lo;
    for (int it = 0; it < 4; ++it) {
        float s1 = 0.0f, s2 = 0.0f;
#pragma unroll
        for (int i = 0; i < 16; ++i) {
            float r = fmaxf(x[i] - tau, 0.0f);
            s1 += r;
            s2 = fmaf(r, r, s2);
        }
#pragma unroll
        for (int off = 32; off; off >>= 1) {
            s1 += __shfl_xor(s1, off);
            s2 += __shfl_xor(s2, off);
        }
        tau += (s2 - 1.0f) / (2.0f * s1);   // s1 > 0 guaranteed (tau <= tau* < 0)
    }

#pragma unroll
    for (int s = 0; s < 4; ++s) {
        float4 v;
        float* vp = &v.x;
#pragma unroll
        for (int j = 0; j < 4; ++j) {
            float r = fmaxf(x[s * 4 + j] - tau, 0.0f);
            vp[j] = r * r;
        }
        *(float4*)&Sr[s * 256 + lane * 4] = v;
    }
}

// PV: AO[b,l, h*64+d] = sum_j P[l,j] V[j,d].  Per (b,h): M=1024, N=64, K=1024.
// grid (16 mtiles, chunk).
__global__ __launch_bounds__(256) void pv_gemm(
    const float* __restrict__ S, const float* __restrict__ Vp,
    float* __restrict__ AO, int bh0)
{
    const int z = blockIdx.y;
    const int bh = bh0 + z;
    const int b = bh >> 4, h = bh & 15;
    const float* P = S + (size_t)z * L * L;
    const float* V = Vp + (size_t)bh * L * DK;

    __shared__ float Pt[64][68];
    __shared__ float Vs[64][68];

    const int t = threadIdx.x;
    const int tx = t & 15, ty = t >> 4;
    const int mbase = blockIdx.x * 64;

    float acc[4][4] = {};

    for (int jt = 0; jt < 16; ++jt) {
        const int jbase = jt * 64;
#pragma unroll
        for (int r = 0; r < 4; ++r) {
            int f = t + 256 * r;
            int mm = f >> 4;
            int kg = (f & 15) << 2;
            float4 p4 = *(const float4*)&P[(size_t)(mbase + mm) * L + jbase + kg];
            Pt[kg + 0][mm] = p4.x; Pt[kg + 1][mm] = p4.y;
            Pt[kg + 2][mm] = p4.z; Pt[kg + 3][mm] = p4.w;
            float4 v4 = *(const float4*)&V[(size_t)(jbase + mm) * DK + kg];
            *(float4*)&Vs[mm][kg] = v4;   // direct copy: Vs[j][d]
        }
        __syncthreads();
#pragma unroll 8
        for (int kk = 0; kk < 64; ++kk) {
            float4 av = *(const float4*)&Pt[kk][ty * 4];
            float4 bv = *(const float4*)&Vs[kk][tx * 4];
            float aa[4] = {av.x, av.y, av.z, av.w};
            float bb[4] = {bv.x, bv.y, bv.z, bv.w};
#pragma unroll
            for (int i = 0; i < 4; ++i)
#pragma unroll
                for (int j = 0; j < 4; ++j)
                    acc[i][j] = fmaf(aa[i], bb[j], acc[i][j]);
        }
        __syncthreads();
    }
#pragma unroll
    for (int i = 0; i < 4; ++i) {
        int l = mbase + ty * 4 + i;
#pragma unroll
        for (int j = 0; j < 4; ++j) {
            int d = tx * 4 + j;
            AO[(size_t)(b * L + l) * DM + h * DK + d] = acc[i][j];
        }
    }
}

extern "C" void kernel_launch(void* const* d_in, const int* in_sizes, int n_in,
                              void* d_out, int out_size, void* d_ws, size_t ws_size,
                              hipStream_t stream)
{
    const float* q  = (const float*)d_in[0];
    const float* k  = (const float*)d_in[1];
    const float* v  = (const float*)d_in[2];
    const int* mask = (const int*)d_in[3];
    const float* wq = (const float*)d_in[4];
    const float* wk = (const float*)d_in[5];
    const float* wv = (const float*)d_in[6];
    const float* wo = (const float*)d_in[7];
    float* out = (float*)d_out;

    float* ws = (float*)d_ws;
    float* Qp = ws;                         // 2M floats (B,H,L,DK)
    float* Kp = ws + (size_t)2 * 1024 * 1024;
    float* Vp = ws + (size_t)4 * 1024 * 1024;
    float* AO = ws + (size_t)6 * 1024 * 1024;   // (B,L,DM)
    float* S  = ws + (size_t)8 * 1024 * 1024;   // chunked scores

    // How many (b,h) score planes (4 MB each) fit in the remaining workspace?
    size_t base_bytes = (size_t)8 * 1024 * 1024 * sizeof(float);  // 32 MB
    size_t avail_f = ws_size > base_bytes ? (ws_size - base_bytes) / sizeof(float) : 0;
    int chunk = (int)(avail_f / ((size_t)L * L));
    if (chunk > 32) chunk = 32;
    if (chunk < 1) chunk = 1;

    proj_qkv<<<dim3(16, 32, 3), 256, 0, stream>>>(q, k, v, wq, wk, wv, Qp, Kp, Vp);

    for (int bh0 = 0; bh0 < 32; bh0 += chunk) {
        int c = 32 - bh0 < chunk ? 32 - bh0 : chunk;
        qk_scores<<<dim3(16, 16, c), 256, 0, stream>>>(Qp, Kp, mask, S, bh0);
        entmax_rows<<<dim3(c * 256), 256, 0, stream>>>(S, c * 1024);
        pv_gemm<<<dim3(16, c), 256, 0, stream>>>(S, Vp, AO, bh0);
    }

    out_proj<<<dim3(16, 32, 1), 256, 0, stream>>>(AO, wo, out);
}

// Round 2
// 326.899 us; speedup vs baseline: 1.4889x; 1.4889x over previous
//
#include <hip/hip_runtime.h>

#define L 1024
#define DM 1024
#define NH 16
#define DK 64

typedef __attribute__((ext_vector_type(8))) short bf16x8;
typedef __attribute__((ext_vector_type(4))) float f32x4;

#define MFMA(a, b, c) __builtin_amdgcn_mfma_f32_16x16x32_bf16(a, b, c, 0, 0, 0)

__device__ inline unsigned short f2bf(float f) {
    unsigned int u = __builtin_bit_cast(unsigned int, f);
    u += 0x7FFFu + ((u >> 16) & 1u);
    return (unsigned short)(u >> 16);
}
__device__ inline float bf2f(unsigned short h) {
    unsigned int u = ((unsigned int)h) << 16;
    return __builtin_bit_cast(float, u);
}

// ---------------------------------------------------------------------------
// Q/K projections with hi/lo split bf16 (3-term MFMA): Y = X @ W^T.
// Outputs hi/lo bf16 planes in (B,H,L,DK) layout.
// grid (8 ntiles, 16 mtiles, 2 which). BM=BN=128, BK=32, 4 waves @ 64x64.
// ---------------------------------------------------------------------------
__global__ __launch_bounds__(256) void proj_qk_split(
    const float* __restrict__ Xq, const float* __restrict__ Xk,
    const float* __restrict__ Wq, const float* __restrict__ Wk,
    unsigned short* __restrict__ Qh, unsigned short* __restrict__ Ql,
    unsigned short* __restrict__ Kh, unsigned short* __restrict__ Kl)
{
    const int z = blockIdx.z;
    const float* X = z ? Xk : Xq;
    const float* W = z ? Wk : Wq;
    unsigned short* Oh = z ? Kh : Qh;
    unsigned short* Ol = z ? Kl : Ql;

    __shared__ unsigned short Ah[128][56], Al[128][56], Bh[128][56], Bl[128][56];

    const int t = threadIdx.x;
    const int w = t >> 6, lane = t & 63, q = lane >> 4, lr = lane & 15;
    const int wr = w >> 1, wc = w & 1;
    const int mbase = blockIdx.y * 128, nbase = blockIdx.x * 128;

    f32x4 acc[4][4] = {};

    for (int kt = 0; kt < 32; ++kt) {
        const int kb = kt * 32;
#pragma unroll
        for (int r = 0; r < 4; ++r) {
            int f = t + 256 * r;
            int row = f >> 3;
            int kq = (f & 7) << 2;
            float4 a4 = *(const float4*)&X[(size_t)(mbase + row) * DM + kb + kq];
            float4 b4 = *(const float4*)&W[(size_t)(nbase + row) * DM + kb + kq];
            ushort4 ah, al, bh, bl;
            ah.x = f2bf(a4.x); al.x = f2bf(a4.x - bf2f(ah.x));
            ah.y = f2bf(a4.y); al.y = f2bf(a4.y - bf2f(ah.y));
            ah.z = f2bf(a4.z); al.z = f2bf(a4.z - bf2f(ah.z));
            ah.w = f2bf(a4.w); al.w = f2bf(a4.w - bf2f(ah.w));
            bh.x = f2bf(b4.x); bl.x = f2bf(b4.x - bf2f(bh.x));
            bh.y = f2bf(b4.y); bl.y = f2bf(b4.y - bf2f(bh.y));
            bh.z = f2bf(b4.z); bl.z = f2bf(b4.z - bf2f(bh.z));
            bh.w = f2bf(b4.w); bl.w = f2bf(b4.w - bf2f(bh.w));
            *(ushort4*)&Ah[row][kq] = ah; *(ushort4*)&Al[row][kq] = al;
            *(ushort4*)&Bh[row][kq] = bh; *(ushort4*)&Bl[row][kq] = bl;
        }
        __syncthreads();

        bf16x8 xh[4], xl[4], yh[4], yl[4];
#pragma unroll
        for (int i = 0; i < 4; ++i) {
            xh[i] = *(const bf16x8*)&Ah[wr * 64 + i * 16 + lr][q * 8];
            xl[i] = *(const bf16x8*)&Al[wr * 64 + i * 16 + lr][q * 8];
            yh[i] = *(const bf16x8*)&Bh[wc * 64 + i * 16 + lr][q * 8];
            yl[i] = *(const bf16x8*)&Bl[wc * 64 + i * 16 + lr][q * 8];
        }
#pragma unroll
        for (int i = 0; i < 4; ++i)
#pragma unroll
            for (int j = 0; j < 4; ++j) {
                acc[i][j] = MFMA(xh[i], yh[j], acc[i][j]);
                acc[i][j] = MFMA(xh[i], yl[j], acc[i][j]);
                acc[i][j] = MFMA(xl[i], yh[j], acc[i][j]);
            }
        __syncthreads();
    }

#pragma unroll
    for (int i = 0; i < 4; ++i)
#pragma unroll
        for (int j = 0; j < 4; ++j)
#pragma unroll
            for (int r = 0; r < 4; ++r) {
                int m = mbase + wr * 64 + i * 16 + q * 4 + r;
                int n = nbase + wc * 64 + j * 16 + lr;
                int b = m >> 10, l = m & 1023;
                int h = n >> 6, d = n & 63;
                float v = acc[i][j][r];
                unsigned short hi = f2bf(v);
                size_t idx = ((size_t)((b * NH + h) * L + l)) * DK + d;
                Oh[idx] = hi;
                Ol[idx] = f2bf(v - bf2f(hi));
            }
}

// ---------------------------------------------------------------------------
// V projection, plain bf16. Output Vb bf16 (B,H,L,DK).
// grid (8 ntiles, 16 mtiles). BM=BN=128, BK=64.
// ---------------------------------------------------------------------------
__global__ __launch_bounds__(256) void proj_v(
    const float* __restrict__ X, const float* __restrict__ W,
    unsigned short* __restrict__ V)
{
    __shared__ unsigned short Ab[128][72], Bb[128][72];

    const int t = threadIdx.x;
    const int w = t >> 6, lane = t & 63, q = lane >> 4, lr = lane & 15;
    const int wr = w >> 1, wc = w & 1;
    const int mbase = blockIdx.y * 128, nbase = blockIdx.x * 128;

    f32x4 acc[4][4] = {};

    for (int kt = 0; kt < 16; ++kt) {
        const int kb = kt * 64;
#pragma unroll
        for (int r = 0; r < 8; ++r) {
            int f = t + 256 * r;
            int row = f >> 4;
            int kq = (f & 15) << 2;
            float4 a4 = *(const float4*)&X[(size_t)(mbase + row) * DM + kb + kq];
            float4 b4 = *(const float4*)&W[(size_t)(nbase + row) * DM + kb + kq];
            ushort4 av, bv;
            av.x = f2bf(a4.x); av.y = f2bf(a4.y); av.z = f2bf(a4.z); av.w = f2bf(a4.w);
            bv.x = f2bf(b4.x); bv.y = f2bf(b4.y); bv.z = f2bf(b4.z); bv.w = f2bf(b4.w);
            *(ushort4*)&Ab[row][kq] = av;
            *(ushort4*)&Bb[row][kq] = bv;
        }
        __syncthreads();
#pragma unroll
        for (int ks = 0; ks < 2; ++ks) {
            bf16x8 a[4], b[4];
            const int k0 = ks * 32 + q * 8;
#pragma unroll
            for (int i = 0; i < 4; ++i) {
                a[i] = *(const bf16x8*)&Ab[wr * 64 + i * 16 + lr][k0];
                b[i] = *(const bf16x8*)&Bb[wc * 64 + i * 16 + lr][k0];
            }
#pragma unroll
            for (int i = 0; i < 4; ++i)
#pragma unroll
                for (int j = 0; j < 4; ++j)
                    acc[i][j] = MFMA(a[i], b[j], acc[i][j]);
        }
        __syncthreads();
    }

#pragma unroll
    for (int i = 0; i < 4; ++i)
#pragma unroll
        for (int j = 0; j < 4; ++j)
#pragma unroll
            for (int r = 0; r < 4; ++r) {
                int m = mbase + wr * 64 + i * 16 + q * 4 + r;
                int n = nbase + wc * 64 + j * 16 + lr;
                int b = m >> 10, jl = m & 1023;
                int h = n >> 6, d = n & 63;
                V[((size_t)((b * NH + h) * L + jl)) * DK + d] = f2bf(acc[i][j][r]);
            }
}

// ---------------------------------------------------------------------------
// Scores via split bf16: S = (QK^T)/16, masked. Per (b,h) plane.
// grid (8 ntiles, 8 mtiles, chunk). BM=BN=128, K=64 as 2 x BK=32.
// ---------------------------------------------------------------------------
__global__ __launch_bounds__(256) void qk_mfma(
    const unsigned short* __restrict__ Qh, const unsigned short* __restrict__ Ql,
    const unsigned short* __restrict__ Kh, const unsigned short* __restrict__ Kl,
    const int* __restrict__ mask, float* __restrict__ S, int bh0)
{
    const int z = blockIdx.z;
    const int bh = bh0 + z;
    const unsigned short* Qhp = Qh + (size_t)bh * L * DK;
    const unsigned short* Qlp = Ql + (size_t)bh * L * DK;
    const unsigned short* Khp = Kh + (size_t)bh * L * DK;
    const unsigned short* Klp = Kl + (size_t)bh * L * DK;
    float* Sz = S + (size_t)z * L * L;

    __shared__ unsigned short Ah[128][56], Al[128][56], Bh[128][56], Bl[128][56];

    const int t = threadIdx.x;
    const int w = t >> 6, lane = t & 63, q = lane >> 4, lr = lane & 15;
    const int wr = w >> 1, wc = w & 1;
    const int mbase = blockIdx.y * 128, nbase = blockIdx.x * 128;

    f32x4 acc[4][4] = {};

    for (int kt = 0; kt < 2; ++kt) {
        const int kb = kt * 32;
#pragma unroll
        for (int r = 0; r < 4; ++r) {
            int f = t + 256 * r;
            int row = f >> 3;
            int kq = (f & 7) << 2;
            *(ushort4*)&Ah[row][kq] = *(const ushort4*)&Qhp[(size_t)(mbase + row) * DK + kb + kq];
            *(ushort4*)&Al[row][kq] = *(const ushort4*)&Qlp[(size_t)(mbase + row) * DK + kb + kq];
            *(ushort4*)&Bh[row][kq] = *(const ushort4*)&Khp[(size_t)(nbase + row) * DK + kb + kq];
            *(ushort4*)&Bl[row][kq] = *(const ushort4*)&Klp[(size_t)(nbase + row) * DK + kb + kq];
        }
        __syncthreads();

        bf16x8 xh[4], xl[4], yh[4], yl[4];
#pragma unroll
        for (int i = 0; i < 4; ++i) {
            xh[i] = *(const bf16x8*)&Ah[wr * 64 + i * 16 + lr][q * 8];
            xl[i] = *(const bf16x8*)&Al[wr * 64 + i * 16 + lr][q * 8];
            yh[i] = *(const bf16x8*)&Bh[wc * 64 + i * 16 + lr][q * 8];
            yl[i] = *(const bf16x8*)&Bl[wc * 64 + i * 16 + lr][q * 8];
        }
#pragma unroll
        for (int i = 0; i < 4; ++i)
#pragma unroll
            for (int j = 0; j < 4; ++j) {
                acc[i][j] = MFMA(xh[i], yh[j], acc[i][j]);
                acc[i][j] = MFMA(xh[i], yl[j], acc[i][j]);
                acc[i][j] = MFMA(xl[i], yh[j], acc[i][j]);
            }
        __syncthreads();
    }

#pragma unroll
    for (int i = 0; i < 4; ++i)
#pragma unroll
        for (int j = 0; j < 4; ++j)
#pragma unroll
            for (int r = 0; r < 4; ++r) {
                int row = mbase + wr * 64 + i * 16 + q * 4 + r;
                int col = nbase + wc * 64 + j * 16 + lr;
                float sv = acc[i][j][r] * 0.0625f;
                int mv = mask[(size_t)row * L + col];
                Sz[(size_t)row * L + col] = (mv == 0) ? -3.0e38f : sv;
            }
}

// ---------------------------------------------------------------------------
// Entmax-1.5 per row: S fp32 in, P bf16 out. One wave per row.
// ---------------------------------------------------------------------------
__global__ __launch_bounds__(256) void entmax_bf(
    const float* __restrict__ S, unsigned short* __restrict__ P, int nrows)
{
    const int wave = threadIdx.x >> 6;
    const int lane = threadIdx.x & 63;
    const int row = blockIdx.x * 4 + wave;
    if (row >= nrows) return;
    const float* Sr = S + (size_t)row * L;

    float x[16];
#pragma unroll
    for (int s = 0; s < 4; ++s) {
        float4 v = *(const float4*)&Sr[s * 256 + lane * 4];
        x[s * 4 + 0] = v.x; x[s * 4 + 1] = v.y;
        x[s * 4 + 2] = v.z; x[s * 4 + 3] = v.w;
    }

    float mx = x[0];
#pragma unroll
    for (int i = 1; i < 16; ++i) mx = fmaxf(mx, x[i]);
#pragma unroll
    for (int off = 32; off; off >>= 1) mx = fmaxf(mx, __shfl_xor(mx, off));
#pragma unroll
    for (int i = 0; i < 16; ++i) x[i] -= mx;

    float lo = -1.0f, hi = 0.0f;
    for (int it = 0; it < 12; ++it) {
        float mid = 0.5f * (lo + hi);
        float f = 0.0f;
#pragma unroll
        for (int i = 0; i < 16; ++i) {
            float r = fmaxf(x[i] - mid, 0.0f);
            f = fmaf(r, r, f);
        }
#pragma unroll
        for (int off = 32; off; off >>= 1) f += __shfl_xor(f, off);
        if (f >= 1.0f) lo = mid; else hi = mid;
    }
    float tau = lo;
    for (int it = 0; it < 4; ++it) {
        float s1 = 0.0f, s2 = 0.0f;
#pragma unroll
        for (int i = 0; i < 16; ++i) {
            float r = fmaxf(x[i] - tau, 0.0f);
            s1 += r;
            s2 = fmaf(r, r, s2);
        }
#pragma unroll
        for (int off = 32; off; off >>= 1) {
            s1 += __shfl_xor(s1, off);
            s2 += __shfl_xor(s2, off);
        }
        tau += (s2 - 1.0f) / (2.0f * s1);
    }

#pragma unroll
    for (int s = 0; s < 4; ++s) {
        ushort4 o;
        float r0 = fmaxf(x[s * 4 + 0] - tau, 0.0f);
        float r1 = fmaxf(x[s * 4 + 1] - tau, 0.0f);
        float r2 = fmaxf(x[s * 4 + 2] - tau, 0.0f);
        float r3 = fmaxf(x[s * 4 + 3] - tau, 0.0f);
        o.x = f2bf(r0 * r0); o.y = f2bf(r1 * r1);
        o.z = f2bf(r2 * r2); o.w = f2bf(r3 * r3);
        *(ushort4*)&P[(size_t)row * L + s * 256 + lane * 4] = o;
    }
}

// ---------------------------------------------------------------------------
// PV: AO[b*L+l][h*64+d] = sum_j P[l][j] V[j][d], bf16 MFMA.
// grid (8 mtiles, chunk). BM=128, BN=64, BK=64, 4 waves @ 64x32.
// ---------------------------------------------------------------------------
__global__ __launch_bounds__(256) void pv_mfma(
    const unsigned short* __restrict__ P, const unsigned short* __restrict__ V,
    unsigned short* __restrict__ AO, int bh0)
{
    const int z = blockIdx.y;
    const int bh = bh0 + z;
    const int b = bh >> 4, h = bh & 15;
    const unsigned short* Pz = P + (size_t)z * L * L;
    const unsigned short* Vp = V + (size_t)bh * L * DK;

    __shared__ unsigned short Pt[128][72], Vs[64][72];

    const int t = threadIdx.x;
    const int w = t >> 6, lane = t & 63, q = lane >> 4, lr = lane & 15;
    const int wr = w >> 1, wc = w & 1;
    const int mbase = blockIdx.x * 128;

    f32x4 acc[4][2] = {};

    for (int jt = 0; jt < 16; ++jt) {
        const int jb = jt * 64;
#pragma unroll
        for (int r = 0; r < 8; ++r) {
            int f = t + 256 * r;
            int row = f >> 4;
            int kq = (f & 15) << 2;
            *(ushort4*)&Pt[row][kq] = *(const ushort4*)&Pz[(size_t)(mbase + row) * L + jb + kq];
        }
#pragma unroll
        for (int r = 0; r < 4; ++r) {
            int f = t + 256 * r;
            int j = f >> 4;
            int dq = (f & 15) << 2;
            ushort4 v4 = *(const ushort4*)&Vp[(size_t)(jb + j) * DK + dq];
            Vs[dq + 0][j] = v4.x; Vs[dq + 1][j] = v4.y;
            Vs[dq + 2][j] = v4.z; Vs[dq + 3][j] = v4.w;
        }
        __syncthreads();
#pragma unroll
        for (int ks = 0; ks < 2; ++ks) {
            const int k0 = ks * 32 + q * 8;
            bf16x8 a[4], bb[2];
#pragma unroll
            for (int i = 0; i < 4; ++i)
                a[i] = *(const bf16x8*)&Pt[wr * 64 + i * 16 + lr][k0];
#pragma unroll
            for (int j = 0; j < 2; ++j)
                bb[j] = *(const bf16x8*)&Vs[wc * 32 + j * 16 + lr][k0];
#pragma unroll
            for (int i = 0; i < 4; ++i)
#pragma unroll
                for (int j = 0; j < 2; ++j)
                    acc[i][j] = MFMA(a[i], bb[j], acc[i][j]);
        }
        __syncthreads();
    }

#pragma unroll
    for (int i = 0; i < 4; ++i)
#pragma unroll
        for (int j = 0; j < 2; ++j)
#pragma unroll
            for (int r = 0; r < 4; ++r) {
                int l = mbase + wr * 64 + i * 16 + q * 4 + r;
                int d = wc * 32 + j * 16 + lr;
                AO[(size_t)(b * L + l) * DM + h * DK + d] = f2bf(acc[i][j][r]);
            }
}

// ---------------------------------------------------------------------------
// Out projection: out = AO(bf16) @ Wo^T, fp32 out.
// grid (16 ntiles, 16 mtiles). BM=128, BN=64, BK=64, 4 waves @ 64x32.
// ---------------------------------------------------------------------------
__global__ __launch_bounds__(256) void out_mfma(
    const unsigned short* __restrict__ A, const float* __restrict__ W,
    float* __restrict__ O)
{
    __shared__ unsigned short Ab[128][72], Bb[64][72];

    const int t = threadIdx.x;
    const int w = t >> 6, lane = t & 63, q = lane >> 4, lr = lane & 15;
    const int wr = w >> 1, wc = w & 1;
    const int mbase = blockIdx.y * 128, nbase = blockIdx.x * 64;

    f32x4 acc[4][2] = {};

    for (int kt = 0; kt < 16; ++kt) {
        const int kb = kt * 64;
#pragma unroll
        for (int r = 0; r < 8; ++r) {
            int f = t + 256 * r;
            int row = f >> 4;
            int kq = (f & 15) << 2;
            *(ushort4*)&Ab[row][kq] = *(const ushort4*)&A[(size_t)(mbase + row) * DM + kb + kq];
        }
#pragma unroll
        for (int r = 0; r < 4; ++r) {
            int f = t + 256 * r;
            int row = f >> 4;
            int kq = (f & 15) << 2;
            float4 b4 = *(const float4*)&W[(size_t)(nbase + row) * DM + kb + kq];
            ushort4 bv;
            bv.x = f2bf(b4.x); bv.y = f2bf(b4.y); bv.z = f2bf(b4.z); bv.w = f2bf(b4.w);
            *(ushort4*)&Bb[row][kq] = bv;
        }
        __syncthreads();
#pragma unroll
        for (int ks = 0; ks < 2; ++ks) {
            const int k0 = ks * 32 + q * 8;
            bf16x8 a[4], bb[2];
#pragma unroll
            for (int i = 0; i < 4; ++i)
                a[i] = *(const bf16x8*)&Ab[wr * 64 + i * 16 + lr][k0];
#pragma unroll
            for (int j = 0; j < 2; ++j)
                bb[j] = *(const bf16x8*)&Bb[wc * 32 + j * 16 + lr][k0];
#pragma unroll
            for (int i = 0; i < 4; ++i)
#pragma unroll
                for (int j = 0; j < 2; ++j)
                    acc[i][j] = MFMA(a[i], bb[j], acc[i][j]);
        }
        __syncthreads();
    }

#pragma unroll
    for (int i = 0; i < 4; ++i)
#pragma unroll
        for (int j = 0; j < 2; ++j)
#pragma unroll
            for (int r = 0; r < 4; ++r) {
                int m = mbase + wr * 64 + i * 16 + q * 4 + r;
                int n = nbase + wc * 32 + j * 16 + lr;
                O[(size_t)m * DM + n] = acc[i][j][r];
            }
}

extern "C" void kernel_launch(void* const* d_in, const int* in_sizes, int n_in,
                              void* d_out, int out_size, void* d_ws, size_t ws_size,
                              hipStream_t stream)
{
    const float* q  = (const float*)d_in[0];
    const float* k  = (const float*)d_in[1];
    const float* v  = (const float*)d_in[2];
    const int* mask = (const int*)d_in[3];
    const float* wq = (const float*)d_in[4];
    const float* wk = (const float*)d_in[5];
    const float* wv = (const float*)d_in[6];
    const float* wo = (const float*)d_in[7];

    char* wsb = (char*)d_ws;
    const size_t MB = (size_t)1 << 20;
    unsigned short* Qh = (unsigned short*)(wsb + 0 * MB);
    unsigned short* Ql = (unsigned short*)(wsb + 4 * MB);
    unsigned short* Kh = (unsigned short*)(wsb + 8 * MB);
    unsigned short* Kl = (unsigned short*)(wsb + 12 * MB);
    unsigned short* Vb = (unsigned short*)(wsb + 16 * MB);
    unsigned short* AO = (unsigned short*)(wsb + 20 * MB);
    float* S = (float*)(wsb + 24 * MB);

    size_t base = 24 * MB;
    size_t per = 6 * MB;  // 4 MB fp32 scores + 2 MB bf16 probs per (b,h)
    int chunk = (ws_size > base + per) ? (int)((ws_size - base) / per) : 1;
    if (chunk > 32) chunk = 32;
    if (chunk < 1) chunk = 1;
    unsigned short* Pb = (unsigned short*)(wsb + base + (size_t)chunk * 4 * MB);

    proj_qk_split<<<dim3(8, 16, 2), 256, 0, stream>>>(q, k, wq, wk, Qh, Ql, Kh, Kl);
    proj_v<<<dim3(8, 16), 256, 0, stream>>>(v, wv, Vb);

    for (int bh0 = 0; bh0 < 32; bh0 += chunk) {
        int c = 32 - bh0 < chunk ? 32 - bh0 : chunk;
        qk_mfma<<<dim3(8, 8, c), 256, 0, stream>>>(Qh, Ql, Kh, Kl, mask, S, bh0);
        entmax_bf<<<dim3(c * 256), 256, 0, stream>>>(S, Pb, c * 1024);
        pv_mfma<<<dim3(8, c), 256, 0, stream>>>(Pb, Vb, AO, bh0);
    }

    out_mfma<<<dim3(16, 16), 256, 0, stream>>>(AO, wo, (float*)d_out);
}

// Round 3
// 232.268 us; speedup vs baseline: 2.0956x; 1.4074x over previous
//
#include <hip/hip_runtime.h>

#define L 1024
#define DM 1024
#define NH 16
#define DK 64

typedef __attribute__((ext_vector_type(8))) short bf16x8;
typedef __attribute__((ext_vector_type(4))) float f32x4;

#define MFMA(a, b, c) __builtin_amdgcn_mfma_f32_16x16x32_bf16(a, b, c, 0, 0, 0)

__device__ inline unsigned short f2bf(float f) {
    unsigned int u = __builtin_bit_cast(unsigned int, f);
    u += 0x7FFFu + ((u >> 16) & 1u);
    return (unsigned short)(u >> 16);
}
__device__ inline float bf2f(unsigned short h) {
    unsigned int u = ((unsigned int)h) << 16;
    return __builtin_bit_cast(float, u);
}

// ---------------------------------------------------------------------------
// Projections: Y = X @ W^T (bf16 MFMA, fp32->bf16 conversion during staging).
// z=0: Q -> Qh/Ql (B,H,L,DK) hi/lo split of fp32 result
// z=1: K -> Kh/Kl
// z=2: V -> Vt (B,H,DK,L) bf16 transposed (for PV B-fragments)
// BM=128, BN=64, BK=64, 4 waves (wave tile 64x32). grid (16,16,3)=768 blocks.
// ---------------------------------------------------------------------------
__global__ __launch_bounds__(256) void proj_kernel(
    const float* __restrict__ Xq, const float* __restrict__ Xk, const float* __restrict__ Xv,
    const float* __restrict__ Wq, const float* __restrict__ Wk, const float* __restrict__ Wv,
    unsigned short* __restrict__ Qh, unsigned short* __restrict__ Ql,
    unsigned short* __restrict__ Kh, unsigned short* __restrict__ Kl,
    unsigned short* __restrict__ Vt)
{
    const int z = blockIdx.z;
    const float* X = z == 0 ? Xq : (z == 1 ? Xk : Xv);
    const float* W = z == 0 ? Wq : (z == 1 ? Wk : Wv);

    __shared__ unsigned short Ab[128][72];
    __shared__ unsigned short Bb[64][72];

    const int t = threadIdx.x;
    const int w = t >> 6, lane = t & 63, qg = lane >> 4, lr = lane & 15;
    const int wr = w >> 1, wc = w & 1;
    const int mbase = blockIdx.y * 128, nbase = blockIdx.x * 64;

    f32x4 acc[4][2] = {};

    for (int kt = 0; kt < 16; ++kt) {
        const int kb = kt * 64;
#pragma unroll
        for (int rr = 0; rr < 8; ++rr) {
            int f = t + 256 * rr;            // 0..2047
            int row = f >> 4;                // 0..127
            int kq = (f & 15) << 2;          // 0..60
            float4 a4 = *(const float4*)&X[(size_t)(mbase + row) * DM + kb + kq];
            ushort4 av;
            av.x = f2bf(a4.x); av.y = f2bf(a4.y); av.z = f2bf(a4.z); av.w = f2bf(a4.w);
            *(ushort4*)&Ab[row][kq] = av;
        }
#pragma unroll
        for (int rr = 0; rr < 4; ++rr) {
            int f = t + 256 * rr;            // 0..1023
            int row = f >> 4;                // 0..63
            int kq = (f & 15) << 2;
            float4 b4 = *(const float4*)&W[(size_t)(nbase + row) * DM + kb + kq];
            ushort4 bv;
            bv.x = f2bf(b4.x); bv.y = f2bf(b4.y); bv.z = f2bf(b4.z); bv.w = f2bf(b4.w);
            *(ushort4*)&Bb[row][kq] = bv;
        }
        __syncthreads();
#pragma unroll
        for (int ks = 0; ks < 2; ++ks) {
            const int k0 = ks * 32 + qg * 8;
            bf16x8 a[4], bfr[2];
#pragma unroll
            for (int i = 0; i < 4; ++i)
                a[i] = *(const bf16x8*)&Ab[wr * 64 + i * 16 + lr][k0];
#pragma unroll
            for (int j = 0; j < 2; ++j)
                bfr[j] = *(const bf16x8*)&Bb[wc * 32 + j * 16 + lr][k0];
#pragma unroll
            for (int i = 0; i < 4; ++i)
#pragma unroll
                for (int j = 0; j < 2; ++j)
                    acc[i][j] = MFMA(a[i], bfr[j], acc[i][j]);
        }
        __syncthreads();
    }

    if (z < 2) {
        unsigned short* Oh = z ? Kh : Qh;
        unsigned short* Ol = z ? Kl : Ql;
#pragma unroll
        for (int i = 0; i < 4; ++i)
#pragma unroll
            for (int j = 0; j < 2; ++j)
#pragma unroll
                for (int r = 0; r < 4; ++r) {
                    int m = mbase + wr * 64 + i * 16 + qg * 4 + r;
                    int n = nbase + wc * 32 + j * 16 + lr;
                    int b = m >> 10, lp = m & 1023;
                    int h = n >> 6, d = n & 63;
                    float vv = acc[i][j][r];
                    unsigned short hi_ = f2bf(vv);
                    size_t idx = ((size_t)((b * NH + h) * L + lp)) * DK + d;
                    Oh[idx] = hi_;
                    Ol[idx] = f2bf(vv - bf2f(hi_));
                }
    } else {
        // transpose 128(m) x 64(d) tile through LDS, write Vt[d][l] coalesced
        __syncthreads();
        unsigned short (*T)[136] = (unsigned short (*)[136])&Ab[0][0];  // 64x136x2=17408B
#pragma unroll
        for (int i = 0; i < 4; ++i)
#pragma unroll
            for (int j = 0; j < 2; ++j)
#pragma unroll
                for (int r = 0; r < 4; ++r) {
                    int ml = wr * 64 + i * 16 + qg * 4 + r;
                    int d  = wc * 32 + j * 16 + lr;
                    T[d][ml] = f2bf(acc[i][j][r]);
                }
        __syncthreads();
        int b = mbase >> 10, h = blockIdx.x;
        int lp0 = mbase & 1023;
        int d = t >> 2, mc = (t & 3) * 32;
        unsigned short* dst = &Vt[((size_t)((b * NH + h) * DK + d)) * L + lp0 + mc];
#pragma unroll
        for (int s = 0; s < 4; ++s)
            *(uint4*)&dst[s * 8] = *(const uint4*)&T[d][mc + s * 8];
    }
}

// ---------------------------------------------------------------------------
// Fused attention: per block = (16 Q-rows, one bh plane). 512 threads, 8 waves.
// Phase 1: S = mask(QK^T/16) via 3-term compensated bf16 MFMA -> S LDS (64KB)
// Phase 2: entmax-1.5 per row (2 rows/wave, 32 f32/lane), P bf16 -> LDS
// Phase 3: PV via MFMA (V frags direct from global Vt), AO bf16 out
// grid (64 qtiles, 32 bh) = 2048 blocks, 2 blocks/CU.
// ---------------------------------------------------------------------------
__global__ __launch_bounds__(512) void attn_kernel(
    const unsigned short* __restrict__ Qh, const unsigned short* __restrict__ Ql,
    const unsigned short* __restrict__ Kh, const unsigned short* __restrict__ Kl,
    const unsigned short* __restrict__ Vt, const int* __restrict__ mask,
    unsigned short* __restrict__ AO)
{
    __shared__ char smem[65536];
    float* S = (float*)smem;                       // [16][1024] fp32
    unsigned short* P = (unsigned short*)smem;     // [16][1032] bf16 (33024 B)
    float* Red = (float*)(smem + 33024);           // 4KB reduction scratch

    const int t = threadIdx.x;
    const int w = t >> 6, lane = t & 63, qg = lane >> 4, lr = lane & 15;
    const int bh = blockIdx.y;
    const int b = bh >> 4, h = bh & 15;
    const int qt = blockIdx.x;
    const size_t qkoff = (size_t)bh * L * DK;

    // Q fragments (all waves share the block's 16 q-rows)
    bf16x8 qh_[2], ql_[2];
#pragma unroll
    for (int ks = 0; ks < 2; ++ks) {
        size_t qa = qkoff + (size_t)(qt * 16 + lr) * DK + ks * 32 + qg * 8;
        qh_[ks] = *(const bf16x8*)&Qh[qa];
        ql_[ks] = *(const bf16x8*)&Ql[qa];
    }

    // ---- Phase 1: scores ----
#pragma unroll
    for (int j = 0; j < 8; ++j) {
        int kblk = w * 8 + j;                      // 0..63
        int krow = kblk * 16 + lr;
        f32x4 acc = {};
#pragma unroll
        for (int ks = 0; ks < 2; ++ks) {
            size_t ka = qkoff + (size_t)krow * DK + ks * 32 + qg * 8;
            bf16x8 kh_ = *(const bf16x8*)&Kh[ka];
            bf16x8 kl_ = *(const bf16x8*)&Kl[ka];
            acc = MFMA(qh_[ks], kh_, acc);
            acc = MFMA(qh_[ks], kl_, acc);
            acc = MFMA(ql_[ks], kh_, acc);
        }
        int kcol = kblk * 16 + lr;
#pragma unroll
        for (int r = 0; r < 4; ++r) {
            int qrow = qg * 4 + r;
            int qabs = qt * 16 + qrow;
            int mv = mask[(size_t)qabs * L + kcol];
            float sv = acc[r] * 0.0625f;
            S[qrow * 1024 + kcol] = (mv == 0) ? -3.0e38f : sv;
        }
    }
    __syncthreads();

    // ---- Phase 2: entmax-1.5 ----
    const int erow = w * 2 + (lane >> 5);          // 0..15
    const int c = lane & 31;
    float x[32];
#pragma unroll
    for (int j = 0; j < 8; ++j) {
        float4 v = *(const float4*)&S[erow * 1024 + c * 4 + 128 * j];
        x[4 * j + 0] = v.x; x[4 * j + 1] = v.y;
        x[4 * j + 2] = v.z; x[4 * j + 3] = v.w;
    }
    __syncthreads();   // all rows loaded before P overwrites S

    float mx = x[0];
#pragma unroll
    for (int i = 1; i < 32; ++i) mx = fmaxf(mx, x[i]);
#pragma unroll
    for (int off = 1; off < 32; off <<= 1) mx = fmaxf(mx, __shfl_xor(mx, off));
#pragma unroll
    for (int i = 0; i < 32; ++i) x[i] -= mx;

    float lo = -1.0f, hi = 0.0f;
    for (int it = 0; it < 8; ++it) {
        float mid = 0.5f * (lo + hi);
        float f = 0.0f;
#pragma unroll
        for (int i = 0; i < 32; ++i) {
            float r = fmaxf(x[i] - mid, 0.0f);
            f = fmaf(r, r, f);
        }
#pragma unroll
        for (int off = 1; off < 32; off <<= 1) f += __shfl_xor(f, off);
        if (f >= 1.0f) lo = mid; else hi = mid;
    }
    float tau = lo;
    for (int it = 0; it < 3; ++it) {
        float s1 = 0.0f, s2 = 0.0f;
#pragma unroll
        for (int i = 0; i < 32; ++i) {
            float r = fmaxf(x[i] - tau, 0.0f);
            s1 += r;
            s2 = fmaf(r, r, s2);
        }
#pragma unroll
        for (int off = 1; off < 32; off <<= 1) {
            s1 += __shfl_xor(s1, off);
            s2 += __shfl_xor(s2, off);
        }
        tau += (s2 - 1.0f) / (2.0f * s1);
    }

#pragma unroll
    for (int j = 0; j < 8; ++j) {
        ushort4 pk;
        float r0 = fmaxf(x[4 * j + 0] - tau, 0.0f);
        float r1 = fmaxf(x[4 * j + 1] - tau, 0.0f);
        float r2 = fmaxf(x[4 * j + 2] - tau, 0.0f);
        float r3 = fmaxf(x[4 * j + 3] - tau, 0.0f);
        pk.x = f2bf(r0 * r0); pk.y = f2bf(r1 * r1);
        pk.z = f2bf(r2 * r2); pk.w = f2bf(r3 * r3);
        *(ushort4*)&P[erow * 1032 + c * 4 + 128 * j] = pk;
    }
    __syncthreads();

    // ---- Phase 3: PV ----
    const int fb = w & 3;        // output d-block (16 cols)
    const int kh2 = w >> 2;      // k-half
    const size_t vtoff = (size_t)bh * DK * L;
    f32x4 pacc = {};
#pragma unroll
    for (int s = 0; s < 16; ++s) {
        int kstep = kh2 * 16 + s;
        int k0 = kstep * 32 + qg * 8;
        bf16x8 pa = *(const bf16x8*)&P[lr * 1032 + k0];
        bf16x8 vb = *(const bf16x8*)&Vt[vtoff + (size_t)(fb * 16 + lr) * L + k0];
        pacc = MFMA(pa, vb, pacc);
    }
    if (kh2 == 1)
        *(f32x4*)&Red[(fb * 64 + lane) * 4] = pacc;
    __syncthreads();
    if (kh2 == 0) {
        f32x4 o = *(const f32x4*)&Red[(fb * 64 + lane) * 4];
#pragma unroll
        for (int r = 0; r < 4; ++r) {
            float vv = pacc[r] + o[r];
            int qrow = qg * 4 + r;
            int m = b * L + qt * 16 + qrow;
            int d = fb * 16 + lr;
            AO[(size_t)m * DM + h * DK + d] = f2bf(vv);
        }
    }
}

// ---------------------------------------------------------------------------
// Out projection: out = AO(bf16) @ Wo^T (fp32->bf16 in staging), fp32 out.
// BM=128, BN=64, BK=64, 4 waves. grid (16,16)=256 blocks.
// ---------------------------------------------------------------------------
__global__ __launch_bounds__(256) void out_kernel(
    const unsigned short* __restrict__ A, const float* __restrict__ W,
    float* __restrict__ O)
{
    __shared__ unsigned short Ab[128][72];
    __shared__ unsigned short Bb[64][72];

    const int t = threadIdx.x;
    const int w = t >> 6, lane = t & 63, qg = lane >> 4, lr = lane & 15;
    const int wr = w >> 1, wc = w & 1;
    const int mbase = blockIdx.y * 128, nbase = blockIdx.x * 64;

    f32x4 acc[4][2] = {};

    for (int kt = 0; kt < 16; ++kt) {
        const int kb = kt * 64;
#pragma unroll
        for (int rr = 0; rr < 4; ++rr) {
            int f = t + 256 * rr;            // 0..1023
            int row = f >> 3;                // 0..127
            int kq = (f & 7) << 3;           // 0..56
            *(bf16x8*)&Ab[row][kq] = *(const bf16x8*)&A[(size_t)(mbase + row) * DM + kb + kq];
        }
#pragma unroll
        for (int rr = 0; rr < 4; ++rr) {
            int f = t + 256 * rr;
            int row = f >> 4;                // 0..63
            int kq = (f & 15) << 2;
            float4 b4 = *(const float4*)&W[(size_t)(nbase + row) * DM + kb + kq];
            ushort4 bv;
            bv.x = f2bf(b4.x); bv.y = f2bf(b4.y); bv.z = f2bf(b4.z); bv.w = f2bf(b4.w);
            *(ushort4*)&Bb[row][kq] = bv;
        }
        __syncthreads();
#pragma unroll
        for (int ks = 0; ks < 2; ++ks) {
            const int k0 = ks * 32 + qg * 8;
            bf16x8 a[4], bfr[2];
#pragma unroll
            for (int i = 0; i < 4; ++i)
                a[i] = *(const bf16x8*)&Ab[wr * 64 + i * 16 + lr][k0];
#pragma unroll
            for (int j = 0; j < 2; ++j)
                bfr[j] = *(const bf16x8*)&Bb[wc * 32 + j * 16 + lr][k0];
#pragma unroll
            for (int i = 0; i < 4; ++i)
#pragma unroll
                for (int j = 0; j < 2; ++j)
                    acc[i][j] = MFMA(a[i], bfr[j], acc[i][j]);
        }
        __syncthreads();
    }

#pragma unroll
    for (int i = 0; i < 4; ++i)
#pragma unroll
        for (int j = 0; j < 2; ++j)
#pragma unroll
            for (int r = 0; r < 4; ++r) {
                int m = mbase + wr * 64 + i * 16 + qg * 4 + r;
                int n = nbase + wc * 32 + j * 16 + lr;
                O[(size_t)m * DM + n] = acc[i][j][r];
            }
}

extern "C" void kernel_launch(void* const* d_in, const int* in_sizes, int n_in,
                              void* d_out, int out_size, void* d_ws, size_t ws_size,
                              hipStream_t stream)
{
    const float* q  = (const float*)d_in[0];
    const float* k  = (const float*)d_in[1];
    const float* v  = (const float*)d_in[2];
    const int* mask = (const int*)d_in[3];
    const float* wq = (const float*)d_in[4];
    const float* wk = (const float*)d_in[5];
    const float* wv = (const float*)d_in[6];
    const float* wo = (const float*)d_in[7];

    char* wsb = (char*)d_ws;
    const size_t MB = (size_t)1 << 20;
    unsigned short* Qh = (unsigned short*)(wsb + 0 * MB);
    unsigned short* Ql = (unsigned short*)(wsb + 4 * MB);
    unsigned short* Kh = (unsigned short*)(wsb + 8 * MB);
    unsigned short* Kl = (unsigned short*)(wsb + 12 * MB);
    unsigned short* Vt = (unsigned short*)(wsb + 16 * MB);
    unsigned short* AO = (unsigned short*)(wsb + 20 * MB);

    proj_kernel<<<dim3(16, 16, 3), 256, 0, stream>>>(q, k, v, wq, wk, wv,
                                                     Qh, Ql, Kh, Kl, Vt);
    attn_kernel<<<dim3(64, 32), 512, 0, stream>>>(Qh, Ql, Kh, Kl, Vt, mask, AO);
    out_kernel<<<dim3(16, 16), 256, 0, stream>>>(AO, wo, (float*)d_out);
}

// Round 4
// 176.820 us; speedup vs baseline: 2.7527x; 1.3136x over previous
//
#include <hip/hip_runtime.h>

#define L 1024
#define DM 1024
#define NH 16
#define DK 64

typedef __attribute__((ext_vector_type(8))) short bf16x8;
typedef __attribute__((ext_vector_type(4))) float f32x4;

#define MFMA(a, b, c) __builtin_amdgcn_mfma_f32_16x16x32_bf16(a, b, c, 0, 0, 0)

__device__ inline unsigned short f2bf(float f) {
    unsigned int u = __builtin_bit_cast(unsigned int, f);
    u += 0x7FFFu + ((u >> 16) & 1u);
    return (unsigned short)(u >> 16);
}
__device__ inline float bf2f(unsigned short h) {
    unsigned int u = ((unsigned int)h) << 16;
    return __builtin_bit_cast(float, u);
}

// ---------------------------------------------------------------------------
// One-shot fp32 -> bf16 conversion of all GEMM inputs.
// Regions: q,k,v (2M elems each), wq,wk,wv,wo (1M each) = 10M elems.
// ---------------------------------------------------------------------------
__global__ __launch_bounds__(256) void convert_bf16(
    const float* __restrict__ q, const float* __restrict__ k, const float* __restrict__ v,
    const float* __restrict__ wq, const float* __restrict__ wk,
    const float* __restrict__ wv, const float* __restrict__ wo,
    unsigned short* __restrict__ Xq, unsigned short* __restrict__ Xk,
    unsigned short* __restrict__ Xv, unsigned short* __restrict__ Wq,
    unsigned short* __restrict__ Wk, unsigned short* __restrict__ Wv,
    unsigned short* __restrict__ Wo)
{
    const size_t M2 = (size_t)1 << 21, M1 = (size_t)1 << 20;
    const size_t nchunks = (3 * M2 + 4 * M1) / 8;
    for (size_t c = (size_t)blockIdx.x * blockDim.x + threadIdx.x; c < nchunks;
         c += (size_t)gridDim.x * blockDim.x) {
        size_t e = c * 8;
        const float* src;
        unsigned short* dst;
        size_t off;
        if (e < 3 * M2) {
            size_t r = e / M2;
            off = e - r * M2;
            src = r == 0 ? q : (r == 1 ? k : v);
            dst = r == 0 ? Xq : (r == 1 ? Xk : Xv);
        } else {
            size_t e2 = e - 3 * M2;
            size_t r = e2 / M1;
            off = e2 - r * M1;
            src = r == 0 ? wq : (r == 1 ? wk : (r == 2 ? wv : wo));
            dst = r == 0 ? Wq : (r == 1 ? Wk : (r == 2 ? Wv : Wo));
        }
        float4 a = *(const float4*)&src[off];
        float4 b = *(const float4*)&src[off + 4];
        ushort4 o0, o1;
        o0.x = f2bf(a.x); o0.y = f2bf(a.y); o0.z = f2bf(a.z); o0.w = f2bf(a.w);
        o1.x = f2bf(b.x); o1.y = f2bf(b.y); o1.z = f2bf(b.z); o1.w = f2bf(b.w);
        *(ushort4*)&dst[off] = o0;
        *(ushort4*)&dst[off + 4] = o1;
    }
}

// ---------------------------------------------------------------------------
// Projections from pre-converted bf16: Y = X @ W^T.
// z=0: Q -> Qh/Ql hi/lo split (B,H,L,DK);  z=1: K -> Kh/Kl;
// z=2: V -> Vt (B,H,DK,L) transposed bf16.
// BM=128, BN=64, BK=64, 4 waves (64x32 wave tile). grid (16,16,3)=768.
// ---------------------------------------------------------------------------
__global__ __launch_bounds__(256) void proj_kernel(
    const unsigned short* __restrict__ Xq, const unsigned short* __restrict__ Xk,
    const unsigned short* __restrict__ Xv, const unsigned short* __restrict__ Wq,
    const unsigned short* __restrict__ Wk, const unsigned short* __restrict__ Wv,
    unsigned short* __restrict__ Qh, unsigned short* __restrict__ Ql,
    unsigned short* __restrict__ Kh, unsigned short* __restrict__ Kl,
    unsigned short* __restrict__ Vt)
{
    const int z = blockIdx.z;
    const unsigned short* X = z == 0 ? Xq : (z == 1 ? Xk : Xv);
    const unsigned short* W = z == 0 ? Wq : (z == 1 ? Wk : Wv);

    __shared__ unsigned short Ab[128][72];
    __shared__ unsigned short Bb[64][72];

    const int t = threadIdx.x;
    const int w = t >> 6, lane = t & 63, qg = lane >> 4, lr = lane & 15;
    const int wr = w >> 1, wc = w & 1;
    const int mbase = blockIdx.y * 128, nbase = blockIdx.x * 64;

    f32x4 acc[4][2] = {};

    for (int kt = 0; kt < 16; ++kt) {
        const int kb = kt * 64;
#pragma unroll
        for (int rr = 0; rr < 4; ++rr) {
            int f = t + 256 * rr;            // 0..1023
            int row = f >> 3;                // 0..127
            int c8 = (f & 7) << 3;           // 0..56
            *(bf16x8*)&Ab[row][c8] = *(const bf16x8*)&X[(size_t)(mbase + row) * DM + kb + c8];
        }
#pragma unroll
        for (int rr = 0; rr < 2; ++rr) {
            int f = t + 256 * rr;            // 0..511
            int row = f >> 3;                // 0..63
            int c8 = (f & 7) << 3;
            *(bf16x8*)&Bb[row][c8] = *(const bf16x8*)&W[(size_t)(nbase + row) * DM + kb + c8];
        }
        __syncthreads();
#pragma unroll
        for (int ks = 0; ks < 2; ++ks) {
            const int k0 = ks * 32 + qg * 8;
            bf16x8 a[4], bfr[2];
#pragma unroll
            for (int i = 0; i < 4; ++i)
                a[i] = *(const bf16x8*)&Ab[wr * 64 + i * 16 + lr][k0];
#pragma unroll
            for (int j = 0; j < 2; ++j)
                bfr[j] = *(const bf16x8*)&Bb[wc * 32 + j * 16 + lr][k0];
#pragma unroll
            for (int i = 0; i < 4; ++i)
#pragma unroll
                for (int j = 0; j < 2; ++j)
                    acc[i][j] = MFMA(a[i], bfr[j], acc[i][j]);
        }
        __syncthreads();
    }

    if (z < 2) {
        unsigned short* Oh = z ? Kh : Qh;
        unsigned short* Ol = z ? Kl : Ql;
#pragma unroll
        for (int i = 0; i < 4; ++i)
#pragma unroll
            for (int j = 0; j < 2; ++j)
#pragma unroll
                for (int r = 0; r < 4; ++r) {
                    int m = mbase + wr * 64 + i * 16 + qg * 4 + r;
                    int n = nbase + wc * 32 + j * 16 + lr;
                    int b = m >> 10, lp = m & 1023;
                    int h = n >> 6, d = n & 63;
                    float vv = acc[i][j][r];
                    unsigned short hi_ = f2bf(vv);
                    size_t idx = ((size_t)((b * NH + h) * L + lp)) * DK + d;
                    Oh[idx] = hi_;
                    Ol[idx] = f2bf(vv - bf2f(hi_));
                }
    } else {
        __syncthreads();
        unsigned short (*T)[136] = (unsigned short (*)[136])&Ab[0][0];  // 64x136 fits in Ab
#pragma unroll
        for (int i = 0; i < 4; ++i)
#pragma unroll
            for (int j = 0; j < 2; ++j)
#pragma unroll
                for (int r = 0; r < 4; ++r) {
                    int ml = wr * 64 + i * 16 + qg * 4 + r;
                    int d  = wc * 32 + j * 16 + lr;
                    T[d][ml] = f2bf(acc[i][j][r]);
                }
        __syncthreads();
        int b = mbase >> 10, h = blockIdx.x;
        int lp0 = mbase & 1023;
        int d = t >> 2, mc = (t & 3) * 32;
        unsigned short* dst = &Vt[((size_t)((b * NH + h) * DK + d)) * L + lp0 + mc];
#pragma unroll
        for (int s = 0; s < 4; ++s)
            *(uint4*)&dst[s * 8] = *(const uint4*)&T[d][mc + s * 8];
    }
}

// ---------------------------------------------------------------------------
// Fused attention. Block = (16 Q-rows, one bh). 512 threads, 8 waves.
// S LDS stride 1036 f32 (conflict-reduced), P bf16 stride 1032 in-place.
// Phase 1 double-buffers K fragments. __launch_bounds__(512,4): 128 VGPR.
// ---------------------------------------------------------------------------
#define SSTR 1036
#define PSTR 1032
__global__ __launch_bounds__(512, 4) void attn_kernel(
    const unsigned short* __restrict__ Qh, const unsigned short* __restrict__ Ql,
    const unsigned short* __restrict__ Kh, const unsigned short* __restrict__ Kl,
    const unsigned short* __restrict__ Vt, const int* __restrict__ mask,
    unsigned short* __restrict__ AO)
{
    __shared__ char smem[70400];
    float* S = (float*)smem;                       // [16][SSTR] f32 = 66304 B
    unsigned short* P = (unsigned short*)smem;     // [16][PSTR] bf16 = 33024 B
    float* Red = (float*)(smem + 66304);           // 4096 B

    const int t = threadIdx.x;
    const int w = t >> 6, lane = t & 63, qg = lane >> 4, lr = lane & 15;
    const int bh = blockIdx.y;
    const int b = bh >> 4, h = bh & 15;
    const int qt = blockIdx.x;
    const size_t qkoff = (size_t)bh * L * DK;

    bf16x8 qh_[2], ql_[2];
#pragma unroll
    for (int ks = 0; ks < 2; ++ks) {
        size_t qa = qkoff + (size_t)(qt * 16 + lr) * DK + ks * 32 + qg * 8;
        qh_[ks] = *(const bf16x8*)&Qh[qa];
        ql_[ks] = *(const bf16x8*)&Ql[qa];
    }

    // ---- Phase 1: scores (double-buffered K fragments) ----
    const int j0 = w * 8;
    const size_t kaBase = qkoff + (size_t)(j0 * 16 + lr) * DK + qg * 8;
    bf16x8 kh_[2][2], kl_[2][2];
#pragma unroll
    for (int ks = 0; ks < 2; ++ks) {
        kh_[0][ks] = *(const bf16x8*)&Kh[kaBase + ks * 32];
        kl_[0][ks] = *(const bf16x8*)&Kl[kaBase + ks * 32];
    }
#pragma unroll
    for (int j = 0; j < 8; ++j) {
        const int cur = j & 1, nxt = cur ^ 1;
        if (j < 7) {
            size_t ka = kaBase + (size_t)(j + 1) * 16 * DK;
#pragma unroll
            for (int ks = 0; ks < 2; ++ks) {
                kh_[nxt][ks] = *(const bf16x8*)&Kh[ka + ks * 32];
                kl_[nxt][ks] = *(const bf16x8*)&Kl[ka + ks * 32];
            }
        }
        f32x4 acc = {};
#pragma unroll
        for (int ks = 0; ks < 2; ++ks) {
            acc = MFMA(qh_[ks], kh_[cur][ks], acc);
            acc = MFMA(qh_[ks], kl_[cur][ks], acc);
            acc = MFMA(ql_[ks], kh_[cur][ks], acc);
        }
        int kcol = (j0 + j) * 16 + lr;
#pragma unroll
        for (int r = 0; r < 4; ++r) {
            int qrow = qg * 4 + r;
            int qabs = qt * 16 + qrow;
            int mv = mask[(size_t)qabs * L + kcol];
            float sv = acc[r] * 0.0625f;
            S[qrow * SSTR + kcol] = (mv == 0) ? -3.0e38f : sv;
        }
    }
    __syncthreads();

    // ---- Phase 2: entmax-1.5 (2 rows/wave, 32 f32/lane) ----
    const int erow = w * 2 + (lane >> 5);
    const int c = lane & 31;
    float x[32];
#pragma unroll
    for (int j = 0; j < 8; ++j) {
        float4 v = *(const float4*)&S[erow * SSTR + c * 4 + 128 * j];
        x[4 * j + 0] = v.x; x[4 * j + 1] = v.y;
        x[4 * j + 2] = v.z; x[4 * j + 3] = v.w;
    }
    __syncthreads();

    float mx = x[0];
#pragma unroll
    for (int i = 1; i < 32; ++i) mx = fmaxf(mx, x[i]);
#pragma unroll
    for (int off = 1; off < 32; off <<= 1) mx = fmaxf(mx, __shfl_xor(mx, off));
#pragma unroll
    for (int i = 0; i < 32; ++i) x[i] -= mx;

    float lo = -1.0f, hi = 0.0f;
    for (int it = 0; it < 6; ++it) {
        float mid = 0.5f * (lo + hi);
        float f = 0.0f;
#pragma unroll
        for (int i = 0; i < 32; ++i) {
            float r = fmaxf(x[i] - mid, 0.0f);
            f = fmaf(r, r, f);
        }
#pragma unroll
        for (int off = 1; off < 32; off <<= 1) f += __shfl_xor(f, off);
        if (f >= 1.0f) lo = mid; else hi = mid;
    }
    float tau = lo;
    for (int it = 0; it < 3; ++it) {
        float s1 = 0.0f, s2 = 0.0f;
#pragma unroll
        for (int i = 0; i < 32; ++i) {
            float r = fmaxf(x[i] - tau, 0.0f);
            s1 += r;
            s2 = fmaf(r, r, s2);
        }
#pragma unroll
        for (int off = 1; off < 32; off <<= 1) {
            s1 += __shfl_xor(s1, off);
            s2 += __shfl_xor(s2, off);
        }
        tau += (s2 - 1.0f) / (2.0f * s1);
    }

#pragma unroll
    for (int j = 0; j < 8; ++j) {
        ushort4 pk;
        float r0 = fmaxf(x[4 * j + 0] - tau, 0.0f);
        float r1 = fmaxf(x[4 * j + 1] - tau, 0.0f);
        float r2 = fmaxf(x[4 * j + 2] - tau, 0.0f);
        float r3 = fmaxf(x[4 * j + 3] - tau, 0.0f);
        pk.x = f2bf(r0 * r0); pk.y = f2bf(r1 * r1);
        pk.z = f2bf(r2 * r2); pk.w = f2bf(r3 * r3);
        *(ushort4*)&P[erow * PSTR + c * 4 + 128 * j] = pk;
    }
    __syncthreads();

    // ---- Phase 3: PV ----
    const int fb = w & 3;
    const int kh2 = w >> 2;
    const size_t vtoff = (size_t)bh * DK * L;
    f32x4 pacc = {};
#pragma unroll
    for (int s = 0; s < 16; ++s) {
        int kstep = kh2 * 16 + s;
        int k0 = kstep * 32 + qg * 8;
        bf16x8 pa = *(const bf16x8*)&P[lr * PSTR + k0];
        bf16x8 vb = *(const bf16x8*)&Vt[vtoff + (size_t)(fb * 16 + lr) * L + k0];
        pacc = MFMA(pa, vb, pacc);
    }
    if (kh2 == 1)
        *(f32x4*)&Red[(fb * 64 + lane) * 4] = pacc;
    __syncthreads();
    if (kh2 == 0) {
        f32x4 o = *(const f32x4*)&Red[(fb * 64 + lane) * 4];
#pragma unroll
        for (int r = 0; r < 4; ++r) {
            float vv = pacc[r] + o[r];
            int qrow = qg * 4 + r;
            int m = b * L + qt * 16 + qrow;
            int d = fb * 16 + lr;
            AO[(size_t)m * DM + h * DK + d] = f2bf(vv);
        }
    }
}

// ---------------------------------------------------------------------------
// Out projection: out = AO(bf16) @ Wo^T(bf16), fp32 out.
// BM=128, BN=64, BK=64, 4 waves. grid (16,16)=256 blocks.
// ---------------------------------------------------------------------------
__global__ __launch_bounds__(256) void out_kernel(
    const unsigned short* __restrict__ A, const unsigned short* __restrict__ W,
    float* __restrict__ O)
{
    __shared__ unsigned short Ab[128][72];
    __shared__ unsigned short Bb[64][72];

    const int t = threadIdx.x;
    const int w = t >> 6, lane = t & 63, qg = lane >> 4, lr = lane & 15;
    const int wr = w >> 1, wc = w & 1;
    const int mbase = blockIdx.y * 128, nbase = blockIdx.x * 64;

    f32x4 acc[4][2] = {};

    for (int kt = 0; kt < 16; ++kt) {
        const int kb = kt * 64;
#pragma unroll
        for (int rr = 0; rr < 4; ++rr) {
            int f = t + 256 * rr;
            int row = f >> 3;                // 0..127
            int c8 = (f & 7) << 3;
            *(bf16x8*)&Ab[row][c8] = *(const bf16x8*)&A[(size_t)(mbase + row) * DM + kb + c8];
        }
#pragma unroll
        for (int rr = 0; rr < 2; ++rr) {
            int f = t + 256 * rr;
            int row = f >> 3;                // 0..63
            int c8 = (f & 7) << 3;
            *(bf16x8*)&Bb[row][c8] = *(const bf16x8*)&W[(size_t)(nbase + row) * DM + kb + c8];
        }
        __syncthreads();
#pragma unroll
        for (int ks = 0; ks < 2; ++ks) {
            const int k0 = ks * 32 + qg * 8;
            bf16x8 a[4], bfr[2];
#pragma unroll
            for (int i = 0; i < 4; ++i)
                a[i] = *(const bf16x8*)&Ab[wr * 64 + i * 16 + lr][k0];
#pragma unroll
            for (int j = 0; j < 2; ++j)
                bfr[j] = *(const bf16x8*)&Bb[wc * 32 + j * 16 + lr][k0];
#pragma unroll
            for (int i = 0; i < 4; ++i)
#pragma unroll
                for (int j = 0; j < 2; ++j)
                    acc[i][j] = MFMA(a[i], bfr[j], acc[i][j]);
        }
        __syncthreads();
    }

#pragma unroll
    for (int i = 0; i < 4; ++i)
#pragma unroll
        for (int j = 0; j < 2; ++j)
#pragma unroll
            for (int r = 0; r < 4; ++r) {
                int m = mbase + wr * 64 + i * 16 + qg * 4 + r;
                int n = nbase + wc * 32 + j * 16 + lr;
                O[(size_t)m * DM + n] = acc[i][j][r];
            }
}

extern "C" void kernel_launch(void* const* d_in, const int* in_sizes, int n_in,
                              void* d_out, int out_size, void* d_ws, size_t ws_size,
                              hipStream_t stream)
{
    const float* q  = (const float*)d_in[0];
    const float* k  = (const float*)d_in[1];
    const float* v  = (const float*)d_in[2];
    const int* mask = (const int*)d_in[3];
    const float* wq = (const float*)d_in[4];
    const float* wk = (const float*)d_in[5];
    const float* wv = (const float*)d_in[6];
    const float* wo = (const float*)d_in[7];

    char* wsb = (char*)d_ws;
    const size_t MB = (size_t)1 << 20;
    unsigned short* Qh  = (unsigned short*)(wsb + 0 * MB);
    unsigned short* Ql  = (unsigned short*)(wsb + 4 * MB);
    unsigned short* Kh  = (unsigned short*)(wsb + 8 * MB);
    unsigned short* Kl  = (unsigned short*)(wsb + 12 * MB);
    unsigned short* Vt  = (unsigned short*)(wsb + 16 * MB);
    unsigned short* AO  = (unsigned short*)(wsb + 20 * MB);
    unsigned short* Xqb = (unsigned short*)(wsb + 24 * MB);
    unsigned short* Xkb = (unsigned short*)(wsb + 28 * MB);
    unsigned short* Xvb = (unsigned short*)(wsb + 32 * MB);
    unsigned short* Wqb = (unsigned short*)(wsb + 36 * MB);
    unsigned short* Wkb = (unsigned short*)(wsb + 38 * MB);
    unsigned short* Wvb = (unsigned short*)(wsb + 40 * MB);
    unsigned short* Wob = (unsigned short*)(wsb + 42 * MB);

    convert_bf16<<<dim3(1024), 256, 0, stream>>>(q, k, v, wq, wk, wv, wo,
                                                 Xqb, Xkb, Xvb, Wqb, Wkb, Wvb, Wob);
    proj_kernel<<<dim3(16, 16, 3), 256, 0, stream>>>(Xqb, Xkb, Xvb, Wqb, Wkb, Wvb,
                                                     Qh, Ql, Kh, Kl, Vt);
    attn_kernel<<<dim3(64, 32), 512, 0, stream>>>(Qh, Ql, Kh, Kl, Vt, mask, AO);
    out_kernel<<<dim3(16, 16), 256, 0, stream>>>(AO, Wob, (float*)d_out);
}

// Round 5
// 169.483 us; speedup vs baseline: 2.8719x; 1.0433x over previous
//
#include <hip/hip_runtime.h>

#define L 1024
#define DM 1024
#define NH 16
#define DK 64

typedef __attribute__((ext_vector_type(8))) short bf16x8;
typedef __attribute__((ext_vector_type(4))) float f32x4;

#define MFMA(a, b, c) __builtin_amdgcn_mfma_f32_16x16x32_bf16(a, b, c, 0, 0, 0)

__device__ inline unsigned short f2bf(float f) {
    unsigned int u = __builtin_bit_cast(unsigned int, f);
    u += 0x7FFFu + ((u >> 16) & 1u);
    return (unsigned short)(u >> 16);
}
__device__ inline float bf2f(unsigned short h) {
    unsigned int u = ((unsigned int)h) << 16;
    return __builtin_bit_cast(float, u);
}

// ---------------------------------------------------------------------------
// One-shot fp32 -> bf16 conversion of all GEMM inputs.
// ---------------------------------------------------------------------------
__global__ __launch_bounds__(256) void convert_bf16(
    const float* __restrict__ q, const float* __restrict__ k, const float* __restrict__ v,
    const float* __restrict__ wq, const float* __restrict__ wk,
    const float* __restrict__ wv, const float* __restrict__ wo,
    unsigned short* __restrict__ Xq, unsigned short* __restrict__ Xk,
    unsigned short* __restrict__ Xv, unsigned short* __restrict__ Wq,
    unsigned short* __restrict__ Wk, unsigned short* __restrict__ Wv,
    unsigned short* __restrict__ Wo)
{
    const size_t M2 = (size_t)1 << 21, M1 = (size_t)1 << 20;
    const size_t nchunks = (3 * M2 + 4 * M1) / 8;
    for (size_t c = (size_t)blockIdx.x * blockDim.x + threadIdx.x; c < nchunks;
         c += (size_t)gridDim.x * blockDim.x) {
        size_t e = c * 8;
        const float* src;
        unsigned short* dst;
        size_t off;
        if (e < 3 * M2) {
            size_t r = e / M2;
            off = e - r * M2;
            src = r == 0 ? q : (r == 1 ? k : v);
            dst = r == 0 ? Xq : (r == 1 ? Xk : Xv);
        } else {
            size_t e2 = e - 3 * M2;
            size_t r = e2 / M1;
            off = e2 - r * M1;
            src = r == 0 ? wq : (r == 1 ? wk : (r == 2 ? wv : wo));
            dst = r == 0 ? Wq : (r == 1 ? Wk : (r == 2 ? Wv : Wo));
        }
        float4 a = *(const float4*)&src[off];
        float4 b = *(const float4*)&src[off + 4];
        ushort4 o0, o1;
        o0.x = f2bf(a.x); o0.y = f2bf(a.y); o0.z = f2bf(a.z); o0.w = f2bf(a.w);
        o1.x = f2bf(b.x); o1.y = f2bf(b.y); o1.z = f2bf(b.z); o1.w = f2bf(b.w);
        *(ushort4*)&dst[off] = o0;
        *(ushort4*)&dst[off + 4] = o1;
    }
}

// ---------------------------------------------------------------------------
// Projections from pre-converted bf16: Y = X @ W^T.
// z=0: Q -> Qh/Ql hi/lo split (B,H,L,DK);  z=1: K -> Kh/Kl;
// z=2: V -> Vt (B,H,DK,L) transposed bf16.
// BM=128, BN=64, BK=64, 4 waves. grid (16,16,3)=768.
// ---------------------------------------------------------------------------
__global__ __launch_bounds__(256) void proj_kernel(
    const unsigned short* __restrict__ Xq, const unsigned short* __restrict__ Xk,
    const unsigned short* __restrict__ Xv, const unsigned short* __restrict__ Wq,
    const unsigned short* __restrict__ Wk, const unsigned short* __restrict__ Wv,
    unsigned short* __restrict__ Qh, unsigned short* __restrict__ Ql,
    unsigned short* __restrict__ Kh, unsigned short* __restrict__ Kl,
    unsigned short* __restrict__ Vt)
{
    const int z = blockIdx.z;
    const unsigned short* X = z == 0 ? Xq : (z == 1 ? Xk : Xv);
    const unsigned short* W = z == 0 ? Wq : (z == 1 ? Wk : Wv);

    __shared__ unsigned short Ab[128][72];
    __shared__ unsigned short Bb[64][72];

    const int t = threadIdx.x;
    const int w = t >> 6, lane = t & 63, qg = lane >> 4, lr = lane & 15;
    const int wr = w >> 1, wc = w & 1;
    const int mbase = blockIdx.y * 128, nbase = blockIdx.x * 64;

    f32x4 acc[4][2] = {};

    for (int kt = 0; kt < 16; ++kt) {
        const int kb = kt * 64;
#pragma unroll
        for (int rr = 0; rr < 4; ++rr) {
            int f = t + 256 * rr;
            int row = f >> 3;
            int c8 = (f & 7) << 3;
            *(bf16x8*)&Ab[row][c8] = *(const bf16x8*)&X[(size_t)(mbase + row) * DM + kb + c8];
        }
#pragma unroll
        for (int rr = 0; rr < 2; ++rr) {
            int f = t + 256 * rr;
            int row = f >> 3;
            int c8 = (f & 7) << 3;
            *(bf16x8*)&Bb[row][c8] = *(const bf16x8*)&W[(size_t)(nbase + row) * DM + kb + c8];
        }
        __syncthreads();
#pragma unroll
        for (int ks = 0; ks < 2; ++ks) {
            const int k0 = ks * 32 + qg * 8;
            bf16x8 a[4], bfr[2];
#pragma unroll
            for (int i = 0; i < 4; ++i)
                a[i] = *(const bf16x8*)&Ab[wr * 64 + i * 16 + lr][k0];
#pragma unroll
            for (int j = 0; j < 2; ++j)
                bfr[j] = *(const bf16x8*)&Bb[wc * 32 + j * 16 + lr][k0];
#pragma unroll
            for (int i = 0; i < 4; ++i)
#pragma unroll
                for (int j = 0; j < 2; ++j)
                    acc[i][j] = MFMA(a[i], bfr[j], acc[i][j]);
        }
        __syncthreads();
    }

    if (z < 2) {
        unsigned short* Oh = z ? Kh : Qh;
        unsigned short* Ol = z ? Kl : Ql;
#pragma unroll
        for (int i = 0; i < 4; ++i)
#pragma unroll
            for (int j = 0; j < 2; ++j)
#pragma unroll
                for (int r = 0; r < 4; ++r) {
                    int m = mbase + wr * 64 + i * 16 + qg * 4 + r;
                    int n = nbase + wc * 32 + j * 16 + lr;
                    int b = m >> 10, lp = m & 1023;
                    int h = n >> 6, d = n & 63;
                    float vv = acc[i][j][r];
                    unsigned short hi_ = f2bf(vv);
                    size_t idx = ((size_t)((b * NH + h) * L + lp)) * DK + d;
                    Oh[idx] = hi_;
                    Ol[idx] = f2bf(vv - bf2f(hi_));
                }
    } else {
        __syncthreads();
        unsigned short (*T)[136] = (unsigned short (*)[136])&Ab[0][0];
#pragma unroll
        for (int i = 0; i < 4; ++i)
#pragma unroll
            for (int j = 0; j < 2; ++j)
#pragma unroll
                for (int r = 0; r < 4; ++r) {
                    int ml = wr * 64 + i * 16 + qg * 4 + r;
                    int d  = wc * 32 + j * 16 + lr;
                    T[d][ml] = f2bf(acc[i][j][r]);
                }
        __syncthreads();
        int b = mbase >> 10, h = blockIdx.x;
        int lp0 = mbase & 1023;
        int d = t >> 2, mc = (t & 3) * 32;
        unsigned short* dst = &Vt[((size_t)((b * NH + h) * DK + d)) * L + lp0 + mc];
#pragma unroll
        for (int s = 0; s < 4; ++s)
            *(uint4*)&dst[s * 8] = *(const uint4*)&T[d][mc + s * 8];
    }
}

// ---------------------------------------------------------------------------
// Fused attention. Block = (16 Q-rows, one bh). 512 threads, 8 waves.
// S stored fp16 (stride 1048 halves = 2096 B) -> LDS 37.6 KB -> 4 blocks/CU.
// __launch_bounds__(512,8) pins VGPR <= 64 for 32 waves/CU.
// ---------------------------------------------------------------------------
#define SSTR 1048   // fp16 elements per S row
#define PSTR 1032   // bf16 elements per P row
__global__ __launch_bounds__(512, 8) void attn_kernel(
    const unsigned short* __restrict__ Qh, const unsigned short* __restrict__ Ql,
    const unsigned short* __restrict__ Kh, const unsigned short* __restrict__ Kl,
    const unsigned short* __restrict__ Vt, const int* __restrict__ mask,
    unsigned short* __restrict__ AO)
{
    __shared__ char smem[37632];
    _Float16* S = (_Float16*)smem;                 // [16][SSTR] = 33536 B
    unsigned short* P = (unsigned short*)smem;     // [16][PSTR] bf16 = 33024 B
    float* Red = (float*)(smem + 33536);           // 4096 B

    const int t = threadIdx.x;
    const int w = t >> 6, lane = t & 63, qg = lane >> 4, lr = lane & 15;
    const int bh = blockIdx.y;
    const int b = bh >> 4, h = bh & 15;
    const int qt = blockIdx.x;
    const size_t qkoff = (size_t)bh * L * DK;

    bf16x8 qh_[2], ql_[2];
#pragma unroll
    for (int ks = 0; ks < 2; ++ks) {
        size_t qa = qkoff + (size_t)(qt * 16 + lr) * DK + ks * 32 + qg * 8;
        qh_[ks] = *(const bf16x8*)&Qh[qa];
        ql_[ks] = *(const bf16x8*)&Ql[qa];
    }

    // ---- Phase 1: scores -> S (fp16) ----
    const int j0 = w * 8;
#pragma unroll
    for (int j = 0; j < 8; ++j) {
        const int kblk = j0 + j;
        const size_t ka = qkoff + (size_t)(kblk * 16 + lr) * DK + qg * 8;
        f32x4 acc = {};
#pragma unroll
        for (int ks = 0; ks < 2; ++ks) {
            bf16x8 kh_ = *(const bf16x8*)&Kh[ka + ks * 32];
            bf16x8 kl_ = *(const bf16x8*)&Kl[ka + ks * 32];
            acc = MFMA(qh_[ks], kh_, acc);
            acc = MFMA(qh_[ks], kl_, acc);
            acc = MFMA(ql_[ks], kh_, acc);
        }
        int kcol = kblk * 16 + lr;
#pragma unroll
        for (int r = 0; r < 4; ++r) {
            int qrow = qg * 4 + r;
            int qabs = qt * 16 + qrow;
            int mv = mask[(size_t)qabs * L + kcol];
            float sv = (mv == 0) ? -60000.0f : acc[r] * 0.0625f;
            S[qrow * SSTR + kcol] = (_Float16)sv;
        }
    }
    __syncthreads();

    // ---- Phase 2: entmax-1.5 (2 rows/wave, 32 elems/lane) ----
    const int erow = w * 2 + (lane >> 5);
    const int c = lane & 31;
    float x[32];
#pragma unroll
    for (int j = 0; j < 4; ++j) {
        uint4 u = *(const uint4*)&S[erow * SSTR + c * 8 + 256 * j];
        const _Float16* hp = (const _Float16*)&u;
#pragma unroll
        for (int m = 0; m < 8; ++m)
            x[8 * j + m] = (float)hp[m];
    }
    __syncthreads();

    float mx = x[0];
#pragma unroll
    for (int i = 1; i < 32; ++i) mx = fmaxf(mx, x[i]);
#pragma unroll
    for (int off = 1; off < 32; off <<= 1) mx = fmaxf(mx, __shfl_xor(mx, off));
#pragma unroll
    for (int i = 0; i < 32; ++i) x[i] -= mx;

    float lo = -1.0f, hi = 0.0f;
    for (int it = 0; it < 4; ++it) {
        float mid = 0.5f * (lo + hi);
        float f = 0.0f;
#pragma unroll
        for (int i = 0; i < 32; ++i) {
            float r = fmaxf(x[i] - mid, 0.0f);
            f = fmaf(r, r, f);
        }
#pragma unroll
        for (int off = 1; off < 32; off <<= 1) f += __shfl_xor(f, off);
        if (f >= 1.0f) lo = mid; else hi = mid;
    }
    float tau = lo;
    for (int it = 0; it < 2; ++it) {
        float s1 = 0.0f, s2 = 0.0f;
#pragma unroll
        for (int i = 0; i < 32; ++i) {
            float r = fmaxf(x[i] - tau, 0.0f);
            s1 += r;
            s2 = fmaf(r, r, s2);
        }
#pragma unroll
        for (int off = 1; off < 32; off <<= 1) {
            s1 += __shfl_xor(s1, off);
            s2 += __shfl_xor(s2, off);
        }
        tau += (s2 - 1.0f) / (2.0f * s1);
    }

#pragma unroll
    for (int j = 0; j < 8; ++j) {
        ushort4 pk;
        float r0 = fmaxf(x[4 * j + 0] - tau, 0.0f);
        float r1 = fmaxf(x[4 * j + 1] - tau, 0.0f);
        float r2 = fmaxf(x[4 * j + 2] - tau, 0.0f);
        float r3 = fmaxf(x[4 * j + 3] - tau, 0.0f);
        pk.x = f2bf(r0 * r0); pk.y = f2bf(r1 * r1);
        pk.z = f2bf(r2 * r2); pk.w = f2bf(r3 * r3);
        // x[4j+m] corresponds to column c*8 + (within the uint4 order):
        // x index 4j+m with j'=j>>1, m'=(j&1)*4+m -> col c*8 + 256*j' + m'
        *(ushort4*)&P[erow * PSTR + c * 8 + 256 * (j >> 1) + (j & 1) * 4] = pk;
    }
    __syncthreads();

    // ---- Phase 3: PV ----
    const int fb = w & 3;
    const int kh2 = w >> 2;
    const size_t vtoff = (size_t)bh * DK * L;
    f32x4 pacc = {};
#pragma unroll
    for (int s = 0; s < 16; ++s) {
        int kstep = kh2 * 16 + s;
        int k0 = kstep * 32 + qg * 8;
        bf16x8 pa = *(const bf16x8*)&P[lr * PSTR + k0];
        bf16x8 vb = *(const bf16x8*)&Vt[vtoff + (size_t)(fb * 16 + lr) * L + k0];
        pacc = MFMA(pa, vb, pacc);
    }
    if (kh2 == 1)
        *(f32x4*)&Red[(fb * 64 + lane) * 4] = pacc;
    __syncthreads();
    if (kh2 == 0) {
        f32x4 o = *(const f32x4*)&Red[(fb * 64 + lane) * 4];
#pragma unroll
        for (int r = 0; r < 4; ++r) {
            float vv = pacc[r] + o[r];
            int qrow = qg * 4 + r;
            int m = b * L + qt * 16 + qrow;
            int d = fb * 16 + lr;
            AO[(size_t)m * DM + h * DK + d] = f2bf(vv);
        }
    }
}

// ---------------------------------------------------------------------------
// Out projection: out = AO(bf16) @ Wo^T(bf16), fp32 out.
// BM=64, BN=64, BK=64, 4 waves (32x32 wave tile). grid (16,32)=512 blocks.
// ---------------------------------------------------------------------------
__global__ __launch_bounds__(256) void out_kernel(
    const unsigned short* __restrict__ A, const unsigned short* __restrict__ W,
    float* __restrict__ O)
{
    __shared__ unsigned short Ab[64][72];
    __shared__ unsigned short Bb[64][72];

    const int t = threadIdx.x;
    const int w = t >> 6, lane = t & 63, qg = lane >> 4, lr = lane & 15;
    const int wr = w >> 1, wc = w & 1;
    const int mbase = blockIdx.y * 64, nbase = blockIdx.x * 64;

    f32x4 acc[2][2] = {};

    for (int kt = 0; kt < 16; ++kt) {
        const int kb = kt * 64;
#pragma unroll
        for (int rr = 0; rr < 2; ++rr) {
            int f = t + 256 * rr;
            int row = f >> 3;                // 0..63
            int c8 = (f & 7) << 3;
            *(bf16x8*)&Ab[row][c8] = *(const bf16x8*)&A[(size_t)(mbase + row) * DM + kb + c8];
        }
#pragma unroll
        for (int rr = 0; rr < 2; ++rr) {
            int f = t + 256 * rr;
            int row = f >> 3;
            int c8 = (f & 7) << 3;
            *(bf16x8*)&Bb[row][c8] = *(const bf16x8*)&W[(size_t)(nbase + row) * DM + kb + c8];
        }
        __syncthreads();
#pragma unroll
        for (int ks = 0; ks < 2; ++ks) {
            const int k0 = ks * 32 + qg * 8;
            bf16x8 a[2], bfr[2];
#pragma unroll
            for (int i = 0; i < 2; ++i)
                a[i] = *(const bf16x8*)&Ab[wr * 32 + i * 16 + lr][k0];
#pragma unroll
            for (int j = 0; j < 2; ++j)
                bfr[j] = *(const bf16x8*)&Bb[wc * 32 + j * 16 + lr][k0];
#pragma unroll
            for (int i = 0; i < 2; ++i)
#pragma unroll
                for (int j = 0; j < 2; ++j)
                    acc[i][j] = MFMA(a[i], bfr[j], acc[i][j]);
        }
        __syncthreads();
    }

#pragma unroll
    for (int i = 0; i < 2; ++i)
#pragma unroll
        for (int j = 0; j < 2; ++j)
#pragma unroll
            for (int r = 0; r < 4; ++r) {
                int m = mbase + wr * 32 + i * 16 + qg * 4 + r;
                int n = nbase + wc * 32 + j * 16 + lr;
                O[(size_t)m * DM + n] = acc[i][j][r];
            }
}

extern "C" void kernel_launch(void* const* d_in, const int* in_sizes, int n_in,
                              void* d_out, int out_size, void* d_ws, size_t ws_size,
                              hipStream_t stream)
{
    const float* q  = (const float*)d_in[0];
    const float* k  = (const float*)d_in[1];
    const float* v  = (const float*)d_in[2];
    const int* mask = (const int*)d_in[3];
    const float* wq = (const float*)d_in[4];
    const float* wk = (const float*)d_in[5];
    const float* wv = (const float*)d_in[6];
    const float* wo = (const float*)d_in[7];

    char* wsb = (char*)d_ws;
    const size_t MB = (size_t)1 << 20;
    unsigned short* Qh  = (unsigned short*)(wsb + 0 * MB);
    unsigned short* Ql  = (unsigned short*)(wsb + 4 * MB);
    unsigned short* Kh  = (unsigned short*)(wsb + 8 * MB);
    unsigned short* Kl  = (unsigned short*)(wsb + 12 * MB);
    unsigned short* Vt  = (unsigned short*)(wsb + 16 * MB);
    unsigned short* AO  = (unsigned short*)(wsb + 20 * MB);
    unsigned short* Xqb = (unsigned short*)(wsb + 24 * MB);
    unsigned short* Xkb = (unsigned short*)(wsb + 28 * MB);
    unsigned short* Xvb = (unsigned short*)(wsb + 32 * MB);
    unsigned short* Wqb = (unsigned short*)(wsb + 36 * MB);
    unsigned short* Wkb = (unsigned short*)(wsb + 38 * MB);
    unsigned short* Wvb = (unsigned short*)(wsb + 40 * MB);
    unsigned short* Wob = (unsigned short*)(wsb + 42 * MB);

    convert_bf16<<<dim3(1024), 256, 0, stream>>>(q, k, v, wq, wk, wv, wo,
                                                 Xqb, Xkb, Xvb, Wqb, Wkb, Wvb, Wob);
    proj_kernel<<<dim3(16, 16, 3), 256, 0, stream>>>(Xqb, Xkb, Xvb, Wqb, Wkb, Wvb,
                                                     Qh, Ql, Kh, Kl, Vt);
    attn_kernel<<<dim3(64, 32), 512, 0, stream>>>(Qh, Ql, Kh, Kl, Vt, mask, AO);
    out_kernel<<<dim3(16, 32), 256, 0, stream>>>(AO, Wob, (float*)d_out);
}

// Round 6
// 152.260 us; speedup vs baseline: 3.1967x; 1.1131x over previous
//
#include <hip/hip_runtime.h>

#define L 1024
#define DM 1024
#define NH 16
#define DK 64

typedef __attribute__((ext_vector_type(8))) short bf16x8;
typedef __attribute__((ext_vector_type(4))) float f32x4;

#define MFMA(a, b, c) __builtin_amdgcn_mfma_f32_16x16x32_bf16(a, b, c, 0, 0, 0)

__device__ inline unsigned short f2bf(float f) {
    unsigned int u = __builtin_bit_cast(unsigned int, f);
    u += 0x7FFFu + ((u >> 16) & 1u);
    return (unsigned short)(u >> 16);
}
__device__ inline float bf2f(unsigned short h) {
    unsigned int u = ((unsigned int)h) << 16;
    return __builtin_bit_cast(float, u);
}
__device__ inline unsigned short f2h(float f) {
    return __builtin_bit_cast(unsigned short, (_Float16)f);
}
__device__ inline float h2f(unsigned short u) {
    return (float)__builtin_bit_cast(_Float16, u);
}

// ---------------------------------------------------------------------------
// One-shot fp32 -> bf16 conversion of all GEMM inputs.
// ---------------------------------------------------------------------------
__global__ __launch_bounds__(256) void convert_bf16(
    const float* __restrict__ q, const float* __restrict__ k, const float* __restrict__ v,
    const float* __restrict__ wq, const float* __restrict__ wk,
    const float* __restrict__ wv, const float* __restrict__ wo,
    unsigned short* __restrict__ Xq, unsigned short* __restrict__ Xk,
    unsigned short* __restrict__ Xv, unsigned short* __restrict__ Wq,
    unsigned short* __restrict__ Wk, unsigned short* __restrict__ Wv,
    unsigned short* __restrict__ Wo)
{
    const size_t M2 = (size_t)1 << 21, M1 = (size_t)1 << 20;
    const size_t nchunks = (3 * M2 + 4 * M1) / 8;
    for (size_t c = (size_t)blockIdx.x * blockDim.x + threadIdx.x; c < nchunks;
         c += (size_t)gridDim.x * blockDim.x) {
        size_t e = c * 8;
        const float* src;
        unsigned short* dst;
        size_t off;
        if (e < 3 * M2) {
            size_t r = e / M2;
            off = e - r * M2;
            src = r == 0 ? q : (r == 1 ? k : v);
            dst = r == 0 ? Xq : (r == 1 ? Xk : Xv);
        } else {
            size_t e2 = e - 3 * M2;
            size_t r = e2 / M1;
            off = e2 - r * M1;
            src = r == 0 ? wq : (r == 1 ? wk : (r == 2 ? wv : wo));
            dst = r == 0 ? Wq : (r == 1 ? Wk : (r == 2 ? Wv : Wo));
        }
        float4 a = *(const float4*)&src[off];
        float4 b = *(const float4*)&src[off + 4];
        ushort4 o0, o1;
        o0.x = f2bf(a.x); o0.y = f2bf(a.y); o0.z = f2bf(a.z); o0.w = f2bf(a.w);
        o1.x = f2bf(b.x); o1.y = f2bf(b.y); o1.z = f2bf(b.z); o1.w = f2bf(b.w);
        *(ushort4*)&dst[off] = o0;
        *(ushort4*)&dst[off + 4] = o1;
    }
}

// ---------------------------------------------------------------------------
// Projections from pre-converted bf16: Y = X @ W^T.
// z=0: Q -> Qh/Ql hi/lo split (B,H,L,DK);  z=1: K -> Kh/Kl;
// z=2: V -> Vt (B,H,DK,L) transposed bf16.
// BM=128, BN=64, BK=64, 4 waves. grid (16,16,3)=768.
// ---------------------------------------------------------------------------
__global__ __launch_bounds__(256) void proj_kernel(
    const unsigned short* __restrict__ Xq, const unsigned short* __restrict__ Xk,
    const unsigned short* __restrict__ Xv, const unsigned short* __restrict__ Wq,
    const unsigned short* __restrict__ Wk, const unsigned short* __restrict__ Wv,
    unsigned short* __restrict__ Qh, unsigned short* __restrict__ Ql,
    unsigned short* __restrict__ Kh, unsigned short* __restrict__ Kl,
    unsigned short* __restrict__ Vt)
{
    const int z = blockIdx.z;
    const unsigned short* X = z == 0 ? Xq : (z == 1 ? Xk : Xv);
    const unsigned short* W = z == 0 ? Wq : (z == 1 ? Wk : Wv);

    __shared__ unsigned short Ab[128][72];
    __shared__ unsigned short Bb[64][72];

    const int t = threadIdx.x;
    const int w = t >> 6, lane = t & 63, qg = lane >> 4, lr = lane & 15;
    const int wr = w >> 1, wc = w & 1;
    const int mbase = blockIdx.y * 128, nbase = blockIdx.x * 64;

    f32x4 acc[4][2] = {};

    for (int kt = 0; kt < 16; ++kt) {
        const int kb = kt * 64;
#pragma unroll
        for (int rr = 0; rr < 4; ++rr) {
            int f = t + 256 * rr;
            int row = f >> 3;
            int c8 = (f & 7) << 3;
            *(bf16x8*)&Ab[row][c8] = *(const bf16x8*)&X[(size_t)(mbase + row) * DM + kb + c8];
        }
#pragma unroll
        for (int rr = 0; rr < 2; ++rr) {
            int f = t + 256 * rr;
            int row = f >> 3;
            int c8 = (f & 7) << 3;
            *(bf16x8*)&Bb[row][c8] = *(const bf16x8*)&W[(size_t)(nbase + row) * DM + kb + c8];
        }
        __syncthreads();
#pragma unroll
        for (int ks = 0; ks < 2; ++ks) {
            const int k0 = ks * 32 + qg * 8;
            bf16x8 a[4], bfr[2];
#pragma unroll
            for (int i = 0; i < 4; ++i)
                a[i] = *(const bf16x8*)&Ab[wr * 64 + i * 16 + lr][k0];
#pragma unroll
            for (int j = 0; j < 2; ++j)
                bfr[j] = *(const bf16x8*)&Bb[wc * 32 + j * 16 + lr][k0];
#pragma unroll
            for (int i = 0; i < 4; ++i)
#pragma unroll
                for (int j = 0; j < 2; ++j)
                    acc[i][j] = MFMA(a[i], bfr[j], acc[i][j]);
        }
        __syncthreads();
    }

    if (z < 2) {
        unsigned short* Oh = z ? Kh : Qh;
        unsigned short* Ol = z ? Kl : Ql;
#pragma unroll
        for (int i = 0; i < 4; ++i)
#pragma unroll
            for (int j = 0; j < 2; ++j)
#pragma unroll
                for (int r = 0; r < 4; ++r) {
                    int m = mbase + wr * 64 + i * 16 + qg * 4 + r;
                    int n = nbase + wc * 32 + j * 16 + lr;
                    int b = m >> 10, lp = m & 1023;
                    int h = n >> 6, d = n & 63;
                    float vv = acc[i][j][r];
                    unsigned short hi_ = f2bf(vv);
                    size_t idx = ((size_t)((b * NH + h) * L + lp)) * DK + d;
                    Oh[idx] = hi_;
                    Ol[idx] = f2bf(vv - bf2f(hi_));
                }
    } else {
        __syncthreads();
        unsigned short (*T)[136] = (unsigned short (*)[136])&Ab[0][0];
#pragma unroll
        for (int i = 0; i < 4; ++i)
#pragma unroll
            for (int j = 0; j < 2; ++j)
#pragma unroll
                for (int r = 0; r < 4; ++r) {
                    int ml = wr * 64 + i * 16 + qg * 4 + r;
                    int d  = wc * 32 + j * 16 + lr;
                    T[d][ml] = f2bf(acc[i][j][r]);
                }
        __syncthreads();
        int b = mbase >> 10, h = blockIdx.x;
        int lp0 = mbase & 1023;
        int d = t >> 2, mc = (t & 3) * 32;
        unsigned short* dst = &Vt[((size_t)((b * NH + h) * DK + d)) * L + lp0 + mc];
#pragma unroll
        for (int s = 0; s < 4; ++s)
            *(uint4*)&dst[s * 8] = *(const uint4*)&T[d][mc + s * 8];
    }
}

// ---------------------------------------------------------------------------
// Fused attention, restructured. Block = (32 Q-rows, one bh). 512 thr, 8 waves.
// grid (32, 32) = 1024 blocks.
// Phase 1: S^T-free transposed QK^T: mfma(K,Q) -> lane holds 4 consecutive
//          kcols of ONE qrow -> one packed-fp16 ds_write_b64 per (j,i).
//          K frags shared across 2 Q-tiles (12 MFMA per 4 K loads).
// Phase 2: entmax, two independent 32-lane row-group solves per wave,
//          interleaved for ILP. P (bf16) overwrites S in place, wave-local.
// Phase 3: per-wave full-K PV sweep, fully unrolled, no cross-wave reduce.
// LDS: 32 x 1048 x 2B = 67 KB -> 2 blocks/CU; launch_bounds(512,4) -> 128 VGPR.
// ---------------------------------------------------------------------------
#define SSTR 1048
__global__ __launch_bounds__(512, 4) void attn_kernel(
    const unsigned short* __restrict__ Qh, const unsigned short* __restrict__ Ql,
    const unsigned short* __restrict__ Kh, const unsigned short* __restrict__ Kl,
    const unsigned short* __restrict__ Vt, const int* __restrict__ mask,
    unsigned short* __restrict__ AO)
{
    __shared__ unsigned short Sb[32 * SSTR];   // fp16 scores, then bf16 probs

    const int t = threadIdx.x;
    const int w = t >> 6, lane = t & 63, qg = lane >> 4, lr = lane & 15;
    const int bh = blockIdx.y;
    const int b = bh >> 4, h = bh & 15;
    const int qt = blockIdx.x;                 // 32-row tile
    const size_t qkoff = (size_t)bh * L * DK;

    // ---- Phase 1: transposed QK^T ----
    bf16x8 qh_[2][2], ql_[2][2];
#pragma unroll
    for (int i = 0; i < 2; ++i)
#pragma unroll
        for (int ks = 0; ks < 2; ++ks) {
            size_t qa = qkoff + (size_t)(qt * 32 + i * 16 + lr) * DK + ks * 32 + qg * 8;
            qh_[i][ks] = *(const bf16x8*)&Qh[qa];
            ql_[i][ks] = *(const bf16x8*)&Ql[qa];
        }

#pragma unroll
    for (int j = 0; j < 8; ++j) {
        const int kblk = w * 8 + j;
        const size_t ka = qkoff + (size_t)(kblk * 16 + lr) * DK + qg * 8;
        bf16x8 kh0 = *(const bf16x8*)&Kh[ka];
        bf16x8 kh1 = *(const bf16x8*)&Kh[ka + 32];
        bf16x8 kl0 = *(const bf16x8*)&Kl[ka];
        bf16x8 kl1 = *(const bf16x8*)&Kl[ka + 32];
#pragma unroll
        for (int i = 0; i < 2; ++i) {
            f32x4 acc = {};
            acc = MFMA(kh0, qh_[i][0], acc);
            acc = MFMA(kl0, qh_[i][0], acc);
            acc = MFMA(kh0, ql_[i][0], acc);
            acc = MFMA(kh1, qh_[i][1], acc);
            acc = MFMA(kl1, qh_[i][1], acc);
            acc = MFMA(kh1, ql_[i][1], acc);
            // lane holds: qrow_local = i*16+lr, kcols = kblk*16 + qg*4 + {0..3}
            const int qabs = qt * 32 + i * 16 + lr;
            const int kcol0 = kblk * 16 + qg * 4;
            int4 mk = *(const int4*)&mask[(size_t)qabs * L + kcol0];
            float s0 = (mk.x == 0) ? -60000.0f : acc[0] * 0.0625f;
            float s1 = (mk.y == 0) ? -60000.0f : acc[1] * 0.0625f;
            float s2 = (mk.z == 0) ? -60000.0f : acc[2] * 0.0625f;
            float s3 = (mk.w == 0) ? -60000.0f : acc[3] * 0.0625f;
            ushort4 pk;
            pk.x = f2h(s0); pk.y = f2h(s1); pk.z = f2h(s2); pk.w = f2h(s3);
            *(ushort4*)&Sb[(i * 16 + lr) * SSTR + kcol0] = pk;
        }
    }
    __syncthreads();

    // ---- Phase 2: entmax-1.5, two interleaved row-group solves ----
    const int half = lane >> 5;
    const int c = lane & 31;
    const int r0 = w * 2 + half;        // rows 0..15
    const int r1 = 16 + r0;             // rows 16..31
    float x0[32], x1[32];
#pragma unroll
    for (int j = 0; j < 4; ++j) {
        uint4 u0 = *(const uint4*)&Sb[r0 * SSTR + c * 8 + 256 * j];
        uint4 u1 = *(const uint4*)&Sb[r1 * SSTR + c * 8 + 256 * j];
        const unsigned short* p0 = (const unsigned short*)&u0;
        const unsigned short* p1 = (const unsigned short*)&u1;
#pragma unroll
        for (int m = 0; m < 8; ++m) {
            x0[8 * j + m] = h2f(p0[m]);
            x1[8 * j + m] = h2f(p1[m]);
        }
    }
    // no barrier needed: each wave reads/writes only its own 4 rows

    float m0 = x0[0], m1 = x1[0];
#pragma unroll
    for (int i = 1; i < 32; ++i) { m0 = fmaxf(m0, x0[i]); m1 = fmaxf(m1, x1[i]); }
#pragma unroll
    for (int off = 1; off < 32; off <<= 1) {
        m0 = fmaxf(m0, __shfl_xor(m0, off));
        m1 = fmaxf(m1, __shfl_xor(m1, off));
    }
#pragma unroll
    for (int i = 0; i < 32; ++i) { x0[i] -= m0; x1[i] -= m1; }

    float lo0 = -1.0f, hi0 = 0.0f, lo1 = -1.0f, hi1 = 0.0f;
    for (int it = 0; it < 4; ++it) {
        float mid0 = 0.5f * (lo0 + hi0), mid1 = 0.5f * (lo1 + hi1);
        float f0 = 0.0f, f1 = 0.0f;
#pragma unroll
        for (int i = 0; i < 32; ++i) {
            float a = fmaxf(x0[i] - mid0, 0.0f);
            float bq = fmaxf(x1[i] - mid1, 0.0f);
            f0 = fmaf(a, a, f0);
            f1 = fmaf(bq, bq, f1);
        }
#pragma unroll
        for (int off = 1; off < 32; off <<= 1) {
            f0 += __shfl_xor(f0, off);
            f1 += __shfl_xor(f1, off);
        }
        if (f0 >= 1.0f) lo0 = mid0; else hi0 = mid0;
        if (f1 >= 1.0f) lo1 = mid1; else hi1 = mid1;
    }
    float tau0 = lo0, tau1 = lo1;
    for (int it = 0; it < 2; ++it) {
        float a1 = 0.0f, a2 = 0.0f, b1 = 0.0f, b2 = 0.0f;
#pragma unroll
        for (int i = 0; i < 32; ++i) {
            float a = fmaxf(x0[i] - tau0, 0.0f);
            float bq = fmaxf(x1[i] - tau1, 0.0f);
            a1 += a; a2 = fmaf(a, a, a2);
            b1 += bq; b2 = fmaf(bq, bq, b2);
        }
#pragma unroll
        for (int off = 1; off < 32; off <<= 1) {
            a1 += __shfl_xor(a1, off);
            a2 += __shfl_xor(a2, off);
            b1 += __shfl_xor(b1, off);
            b2 += __shfl_xor(b2, off);
        }
        tau0 += (a2 - 1.0f) / (2.0f * a1);
        tau1 += (b2 - 1.0f) / (2.0f * b1);
    }

#pragma unroll
    for (int j = 0; j < 4; ++j) {
        ushort4 o0a, o0b, o1a, o1b;
#pragma unroll
        for (int m = 0; m < 4; ++m) {
            float a = fmaxf(x0[8 * j + m] - tau0, 0.0f);
            float bq = fmaxf(x0[8 * j + 4 + m] - tau0, 0.0f);
            float cc = fmaxf(x1[8 * j + m] - tau1, 0.0f);
            float d = fmaxf(x1[8 * j + 4 + m] - tau1, 0.0f);
            ((unsigned short*)&o0a)[m] = f2bf(a * a);
            ((unsigned short*)&o0b)[m] = f2bf(bq * bq);
            ((unsigned short*)&o1a)[m] = f2bf(cc * cc);
            ((unsigned short*)&o1b)[m] = f2bf(d * d);
        }
        *(ushort4*)&Sb[r0 * SSTR + c * 8 + 256 * j] = o0a;
        *(ushort4*)&Sb[r0 * SSTR + c * 8 + 256 * j + 4] = o0b;
        *(ushort4*)&Sb[r1 * SSTR + c * 8 + 256 * j] = o1a;
        *(ushort4*)&Sb[r1 * SSTR + c * 8 + 256 * j + 4] = o1b;
    }
    __syncthreads();

    // ---- Phase 3: PV, per-wave full K sweep ----
    const int i3 = w >> 2;              // q row-tile (0/1)
    const int fb = w & 3;               // d block (16 cols)
    const size_t vtoff = (size_t)bh * DK * L + (size_t)(fb * 16 + lr) * L + qg * 8;
    const unsigned short* Prow = &Sb[(i3 * 16 + lr) * SSTR + qg * 8];
    f32x4 pacc = {};
#pragma unroll
    for (int s = 0; s < 32; ++s) {
        bf16x8 pa = *(const bf16x8*)&Prow[s * 32];
        bf16x8 vb = *(const bf16x8*)&Vt[vtoff + s * 32];
        pacc = MFMA(pa, vb, pacc);
    }
#pragma unroll
    for (int r = 0; r < 4; ++r) {
        int m = b * L + qt * 32 + i3 * 16 + qg * 4 + r;
        int d = fb * 16 + lr;
        AO[(size_t)m * DM + h * DK + d] = f2bf(pacc[r]);
    }
}

// ---------------------------------------------------------------------------
// Out projection: out = AO(bf16) @ Wo^T(bf16), fp32 out.
// BM=64, BN=64, BK=64, 4 waves. grid (16,32)=512 blocks.
// ---------------------------------------------------------------------------
__global__ __launch_bounds__(256) void out_kernel(
    const unsigned short* __restrict__ A, const unsigned short* __restrict__ W,
    float* __restrict__ O)
{
    __shared__ unsigned short Ab[64][72];
    __shared__ unsigned short Bb[64][72];

    const int t = threadIdx.x;
    const int w = t >> 6, lane = t & 63, qg = lane >> 4, lr = lane & 15;
    const int wr = w >> 1, wc = w & 1;
    const int mbase = blockIdx.y * 64, nbase = blockIdx.x * 64;

    f32x4 acc[2][2] = {};

    for (int kt = 0; kt < 16; ++kt) {
        const int kb = kt * 64;
#pragma unroll
        for (int rr = 0; rr < 2; ++rr) {
            int f = t + 256 * rr;
            int row = f >> 3;
            int c8 = (f & 7) << 3;
            *(bf16x8*)&Ab[row][c8] = *(const bf16x8*)&A[(size_t)(mbase + row) * DM + kb + c8];
        }
#pragma unroll
        for (int rr = 0; rr < 2; ++rr) {
            int f = t + 256 * rr;
            int row = f >> 3;
            int c8 = (f & 7) << 3;
            *(bf16x8*)&Bb[row][c8] = *(const bf16x8*)&W[(size_t)(nbase + row) * DM + kb + c8];
        }
        __syncthreads();
#pragma unroll
        for (int ks = 0; ks < 2; ++ks) {
            const int k0 = ks * 32 + qg * 8;
            bf16x8 a[2], bfr[2];
#pragma unroll
            for (int i = 0; i < 2; ++i)
                a[i] = *(const bf16x8*)&Ab[wr * 32 + i * 16 + lr][k0];
#pragma unroll
            for (int j = 0; j < 2; ++j)
                bfr[j] = *(const bf16x8*)&Bb[wc * 32 + j * 16 + lr][k0];
#pragma unroll
            for (int i = 0; i < 2; ++i)
#pragma unroll
                for (int j = 0; j < 2; ++j)
                    acc[i][j] = MFMA(a[i], bfr[j], acc[i][j]);
        }
        __syncthreads();
    }

#pragma unroll
    for (int i = 0; i < 2; ++i)
#pragma unroll
        for (int j = 0; j < 2; ++j)
#pragma unroll
            for (int r = 0; r < 4; ++r) {
                int m = mbase + wr * 32 + i * 16 + qg * 4 + r;
                int n = nbase + wc * 32 + j * 16 + lr;
                O[(size_t)m * DM + n] = acc[i][j][r];
            }
}

extern "C" void kernel_launch(void* const* d_in, const int* in_sizes, int n_in,
                              void* d_out, int out_size, void* d_ws, size_t ws_size,
                              hipStream_t stream)
{
    const float* q  = (const float*)d_in[0];
    const float* k  = (const float*)d_in[1];
    const float* v  = (const float*)d_in[2];
    const int* mask = (const int*)d_in[3];
    const float* wq = (const float*)d_in[4];
    const float* wk = (const float*)d_in[5];
    const float* wv = (const float*)d_in[6];
    const float* wo = (const float*)d_in[7];

    char* wsb = (char*)d_ws;
    const size_t MB = (size_t)1 << 20;
    unsigned short* Qh  = (unsigned short*)(wsb + 0 * MB);
    unsigned short* Ql  = (unsigned short*)(wsb + 4 * MB);
    unsigned short* Kh  = (unsigned short*)(wsb + 8 * MB);
    unsigned short* Kl  = (unsigned short*)(wsb + 12 * MB);
    unsigned short* Vt  = (unsigned short*)(wsb + 16 * MB);
    unsigned short* AO  = (unsigned short*)(wsb + 20 * MB);
    unsigned short* Xqb = (unsigned short*)(wsb + 24 * MB);
    unsigned short* Xkb = (unsigned short*)(wsb + 28 * MB);
    unsigned short* Xvb = (unsigned short*)(wsb + 32 * MB);
    unsigned short* Wqb = (unsigned short*)(wsb + 36 * MB);
    unsigned short* Wkb = (unsigned short*)(wsb + 38 * MB);
    unsigned short* Wvb = (unsigned short*)(wsb + 40 * MB);
    unsigned short* Wob = (unsigned short*)(wsb + 42 * MB);

    convert_bf16<<<dim3(1024), 256, 0, stream>>>(q, k, v, wq, wk, wv, wo,
                                                 Xqb, Xkb, Xvb, Wqb, Wkb, Wvb, Wob);
    proj_kernel<<<dim3(16, 16, 3), 256, 0, stream>>>(Xqb, Xkb, Xvb, Wqb, Wkb, Wvb,
                                                     Qh, Ql, Kh, Kl, Vt);
    attn_kernel<<<dim3(32, 32), 512, 0, stream>>>(Qh, Ql, Kh, Kl, Vt, mask, AO);
    out_kernel<<<dim3(16, 32), 256, 0, stream>>>(AO, Wob, (float*)d_out);
}

// Round 7
// 119.605 us; speedup vs baseline: 4.0695x; 1.2730x over previous
//
#include <hip/hip_runtime.h>

#define L 1024
#define DM 1024
#define NH 16
#define DK 64

typedef __attribute__((ext_vector_type(8))) short bf16x8;
typedef __attribute__((ext_vector_type(4))) float f32x4;

#define MFMA(a, b, c) __builtin_amdgcn_mfma_f32_16x16x32_bf16(a, b, c, 0, 0, 0)

__device__ inline unsigned short f2bf(float f) {
    unsigned int u = __builtin_bit_cast(unsigned int, f);
    u += 0x7FFFu + ((u >> 16) & 1u);
    return (unsigned short)(u >> 16);
}
__device__ inline float bf2f(unsigned short h) {
    unsigned int u = ((unsigned int)h) << 16;
    return __builtin_bit_cast(float, u);
}
__device__ inline unsigned short f2h(float f) {
    return __builtin_bit_cast(unsigned short, (_Float16)f);
}
__device__ inline float h2f(unsigned short u) {
    return (float)__builtin_bit_cast(_Float16, u);
}

// ---------------------------------------------------------------------------
// One-shot fp32 -> bf16 conversion of all GEMM inputs.
// ---------------------------------------------------------------------------
__global__ __launch_bounds__(256) void convert_bf16(
    const float* __restrict__ q, const float* __restrict__ k, const float* __restrict__ v,
    const float* __restrict__ wq, const float* __restrict__ wk,
    const float* __restrict__ wv, const float* __restrict__ wo,
    unsigned short* __restrict__ Xq, unsigned short* __restrict__ Xk,
    unsigned short* __restrict__ Xv, unsigned short* __restrict__ Wq,
    unsigned short* __restrict__ Wk, unsigned short* __restrict__ Wv,
    unsigned short* __restrict__ Wo)
{
    const size_t M2 = (size_t)1 << 21, M1 = (size_t)1 << 20;
    const size_t nchunks = (3 * M2 + 4 * M1) / 8;
    for (size_t c = (size_t)blockIdx.x * blockDim.x + threadIdx.x; c < nchunks;
         c += (size_t)gridDim.x * blockDim.x) {
        size_t e = c * 8;
        const float* src;
        unsigned short* dst;
        size_t off;
        if (e < 3 * M2) {
            size_t r = e / M2;
            off = e - r * M2;
            src = r == 0 ? q : (r == 1 ? k : v);
            dst = r == 0 ? Xq : (r == 1 ? Xk : Xv);
        } else {
            size_t e2 = e - 3 * M2;
            size_t r = e2 / M1;
            off = e2 - r * M1;
            src = r == 0 ? wq : (r == 1 ? wk : (r == 2 ? wv : wo));
            dst = r == 0 ? Wq : (r == 1 ? Wk : (r == 2 ? Wv : Wo));
        }
        float4 a = *(const float4*)&src[off];
        float4 b = *(const float4*)&src[off + 4];
        ushort4 o0, o1;
        o0.x = f2bf(a.x); o0.y = f2bf(a.y); o0.z = f2bf(a.z); o0.w = f2bf(a.w);
        o1.x = f2bf(b.x); o1.y = f2bf(b.y); o1.z = f2bf(b.z); o1.w = f2bf(b.w);
        *(ushort4*)&dst[off] = o0;
        *(ushort4*)&dst[off + 4] = o1;
    }
}

// ---------------------------------------------------------------------------
// Mask -> packed fp16 additive-bias fragments.
// Mp[qtile(64)][kblk(64)][lane(64)][4], lane=(qg,lr): qrow=qtile*16+lr,
// kcol=kblk*16+qg*4+c. Launched AFTER proj (Mp overlaps dead Xq scratch).
// ---------------------------------------------------------------------------
__global__ __launch_bounds__(256) void pack_mask(const int* __restrict__ mask,
                                                 unsigned short* __restrict__ Mp)
{
    int id = blockIdx.x * 256 + threadIdx.x;     // 0 .. 262143
    int lane = id & 63;
    int kblk = (id >> 6) & 63;
    int qtile = id >> 12;                        // 0..63
    int qabs = qtile * 16 + (lane & 15);
    int kcol = kblk * 16 + (lane >> 4) * 4;
    int4 m = *(const int4*)&mask[(size_t)qabs * L + kcol];
    unsigned short neg = f2h(-60000.0f);
    ushort4 o;
    o.x = (m.x == 0) ? neg : (unsigned short)0;
    o.y = (m.y == 0) ? neg : (unsigned short)0;
    o.z = (m.z == 0) ? neg : (unsigned short)0;
    o.w = (m.w == 0) ? neg : (unsigned short)0;
    *(ushort4*)&Mp[(size_t)id * 4] = o;
}

// ---------------------------------------------------------------------------
// Projections from pre-converted bf16: Y = X @ W^T.
// Epilogues write MFMA-fragment-linear layouts:
//  z=0/1: Q/K hi+lo  [bh][tile(64)][ks(2)][lane(64)][8]   (1024 elems/tile)
//  z=2:   V          [bh][fb(4)][s(32)][lane(64)][8]
// BM=128, BN=64, BK=64, 4 waves. grid (16,16,3)=768.
// ---------------------------------------------------------------------------
__global__ __launch_bounds__(256) void proj_kernel(
    const unsigned short* __restrict__ Xq, const unsigned short* __restrict__ Xk,
    const unsigned short* __restrict__ Xv, const unsigned short* __restrict__ Wq,
    const unsigned short* __restrict__ Wk, const unsigned short* __restrict__ Wv,
    unsigned short* __restrict__ Qh, unsigned short* __restrict__ Ql,
    unsigned short* __restrict__ Kh, unsigned short* __restrict__ Kl,
    unsigned short* __restrict__ Vt)
{
    const int z = blockIdx.z;
    const unsigned short* X = z == 0 ? Xq : (z == 1 ? Xk : Xv);
    const unsigned short* W = z == 0 ? Wq : (z == 1 ? Wk : Wv);

    __shared__ unsigned short Ab[128][72];
    __shared__ unsigned short Bb[64][72];

    const int t = threadIdx.x;
    const int w = t >> 6, lane = t & 63, qg = lane >> 4, lr = lane & 15;
    const int wr = w >> 1, wc = w & 1;
    const int mbase = blockIdx.y * 128, nbase = blockIdx.x * 64;

    f32x4 acc[4][2] = {};

    for (int kt = 0; kt < 16; ++kt) {
        const int kb = kt * 64;
#pragma unroll
        for (int rr = 0; rr < 4; ++rr) {
            int f = t + 256 * rr;
            int row = f >> 3;
            int c8 = (f & 7) << 3;
            *(bf16x8*)&Ab[row][c8] = *(const bf16x8*)&X[(size_t)(mbase + row) * DM + kb + c8];
        }
#pragma unroll
        for (int rr = 0; rr < 2; ++rr) {
            int f = t + 256 * rr;
            int row = f >> 3;
            int c8 = (f & 7) << 3;
            *(bf16x8*)&Bb[row][c8] = *(const bf16x8*)&W[(size_t)(nbase + row) * DM + kb + c8];
        }
        __syncthreads();
#pragma unroll
        for (int ks = 0; ks < 2; ++ks) {
            const int k0 = ks * 32 + qg * 8;
            bf16x8 a[4], bfr[2];
#pragma unroll
            for (int i = 0; i < 4; ++i)
                a[i] = *(const bf16x8*)&Ab[wr * 64 + i * 16 + lr][k0];
#pragma unroll
            for (int j = 0; j < 2; ++j)
                bfr[j] = *(const bf16x8*)&Bb[wc * 32 + j * 16 + lr][k0];
#pragma unroll
            for (int i = 0; i < 4; ++i)
#pragma unroll
                for (int j = 0; j < 2; ++j)
                    acc[i][j] = MFMA(a[i], bfr[j], acc[i][j]);
        }
        __syncthreads();
    }

    if (z < 2) {
        unsigned short* Oh = z ? Kh : Qh;
        unsigned short* Ol = z ? Kl : Ql;
#pragma unroll
        for (int i = 0; i < 4; ++i)
#pragma unroll
            for (int j = 0; j < 2; ++j) {
                int n = nbase + wc * 32 + j * 16 + lr;
                int h = n >> 6, d = n & 63;
                int ks = (d >> 5) & 1, qg2 = (d >> 3) & 3, e = d & 7;
                int m0 = mbase + wr * 64 + i * 16 + qg * 4;
                int b = m0 >> 10, l0 = m0 & 1023;
                int tile = l0 >> 4;
                int bh = b * NH + h;
                size_t base = ((size_t)bh * 64 + tile) * 1024 + ks * 512 + qg2 * 128 + e;
#pragma unroll
                for (int r = 0; r < 4; ++r) {
                    float vv = acc[i][j][r];
                    unsigned short hi_ = f2bf(vv);
                    size_t idx = base + (size_t)(qg * 4 + r) * 8;
                    Oh[idx] = hi_;
                    Ol[idx] = f2bf(vv - bf2f(hi_));
                }
            }
    } else {
#pragma unroll
        for (int i = 0; i < 4; ++i)
#pragma unroll
            for (int j = 0; j < 2; ++j) {
                int n = nbase + wc * 32 + j * 16 + lr;
                int h = n >> 6, d = n & 63;
                int fb = d >> 4, lr2 = d & 15;
                int m0 = mbase + wr * 64 + i * 16 + qg * 4;
                int b = m0 >> 10, l0 = m0 & 1023;
                int s = l0 >> 5, qg2 = (l0 >> 3) & 3, e0 = l0 & 7;  // e0 = (qg&1)*4
                int bh = b * NH + h;
                size_t idx = (((size_t)bh * 4 + fb) * 32 + s) * 512 + qg2 * 128 + lr2 * 8 + e0;
                ushort4 o;
                o.x = f2bf(acc[i][j][0]); o.y = f2bf(acc[i][j][1]);
                o.z = f2bf(acc[i][j][2]); o.w = f2bf(acc[i][j][3]);
                *(ushort4*)&Vt[idx] = o;
            }
    }
}

// ---------------------------------------------------------------------------
// Fused attention. Block = (32 Q-rows, one bh). 512 thr, 8 waves. grid (32,32).
// ALL global loads are fragment-linear (lane*16B coalesced):
//  Phase 1: transposed QK^T (mfma(K,Q)), mask bias from packed Mp, S fp16->LDS
//  Phase 2: entmax-1.5, two interleaved 32-lane row solves per wave
//  Phase 3: PV full-K sweep from packed Vt; AO bf16 out
// LDS 32*1048*2 = 67 KB -> 2 blocks/CU.
// ---------------------------------------------------------------------------
#define SSTR 1048
__global__ __launch_bounds__(512, 4) void attn_kernel(
    const unsigned short* __restrict__ Qh, const unsigned short* __restrict__ Ql,
    const unsigned short* __restrict__ Kh, const unsigned short* __restrict__ Kl,
    const unsigned short* __restrict__ Vt, const unsigned short* __restrict__ Mp,
    unsigned short* __restrict__ AO)
{
    __shared__ unsigned short Sb[32 * SSTR];   // fp16 scores, then bf16 probs

    const int t = threadIdx.x;
    const int w = t >> 6, lane = t & 63, qg = lane >> 4, lr = lane & 15;
    const int bh = blockIdx.y;
    const int b = bh >> 4, h = bh & 15;
    const int qt = blockIdx.x;                 // 32-row tile
    const size_t plane = (size_t)bh << 16;     // 64 tiles * 1024 elems

    // ---- Phase 1: transposed QK^T ----
    bf16x8 qh_[2][2], ql_[2][2];
#pragma unroll
    for (int i = 0; i < 2; ++i)
#pragma unroll
        for (int ks = 0; ks < 2; ++ks) {
            size_t qa = plane + (size_t)(qt * 2 + i) * 1024 + ks * 512 + lane * 8;
            qh_[i][ks] = *(const bf16x8*)&Qh[qa];
            ql_[i][ks] = *(const bf16x8*)&Ql[qa];
        }

#pragma unroll
    for (int j = 0; j < 8; ++j) {
        const int kblk = w * 8 + j;
        const size_t ka = plane + (size_t)kblk * 1024 + lane * 8;
        bf16x8 kh0 = *(const bf16x8*)&Kh[ka];
        bf16x8 kh1 = *(const bf16x8*)&Kh[ka + 512];
        bf16x8 kl0 = *(const bf16x8*)&Kl[ka];
        bf16x8 kl1 = *(const bf16x8*)&Kl[ka + 512];
#pragma unroll
        for (int i = 0; i < 2; ++i) {
            f32x4 acc = {};
            acc = MFMA(kh0, qh_[i][0], acc);
            acc = MFMA(kl0, qh_[i][0], acc);
            acc = MFMA(kh0, ql_[i][0], acc);
            acc = MFMA(kh1, qh_[i][1], acc);
            acc = MFMA(kl1, qh_[i][1], acc);
            acc = MFMA(kh1, ql_[i][1], acc);
            ushort4 mb = *(const ushort4*)&Mp[(((size_t)(qt * 2 + i) * 64 + kblk) * 64 + lane) * 4];
            float s0 = fmaf(acc[0], 0.0625f, h2f(mb.x));
            float s1 = fmaf(acc[1], 0.0625f, h2f(mb.y));
            float s2 = fmaf(acc[2], 0.0625f, h2f(mb.z));
            float s3 = fmaf(acc[3], 0.0625f, h2f(mb.w));
            ushort4 pk;
            pk.x = f2h(s0); pk.y = f2h(s1); pk.z = f2h(s2); pk.w = f2h(s3);
            *(ushort4*)&Sb[(i * 16 + lr) * SSTR + kblk * 16 + qg * 4] = pk;
        }
    }
    __syncthreads();

    // ---- Phase 2: entmax-1.5, two interleaved row-group solves ----
    const int half = lane >> 5;
    const int c = lane & 31;
    const int r0 = w * 2 + half;        // rows 0..15
    const int r1 = 16 + r0;             // rows 16..31
    float x0[32], x1[32];
#pragma unroll
    for (int j = 0; j < 4; ++j) {
        uint4 u0 = *(const uint4*)&Sb[r0 * SSTR + c * 8 + 256 * j];
        uint4 u1 = *(const uint4*)&Sb[r1 * SSTR + c * 8 + 256 * j];
        const unsigned short* p0 = (const unsigned short*)&u0;
        const unsigned short* p1 = (const unsigned short*)&u1;
#pragma unroll
        for (int m = 0; m < 8; ++m) {
            x0[8 * j + m] = h2f(p0[m]);
            x1[8 * j + m] = h2f(p1[m]);
        }
    }

    float m0 = x0[0], m1 = x1[0];
#pragma unroll
    for (int i = 1; i < 32; ++i) { m0 = fmaxf(m0, x0[i]); m1 = fmaxf(m1, x1[i]); }
#pragma unroll
    for (int off = 1; off < 32; off <<= 1) {
        m0 = fmaxf(m0, __shfl_xor(m0, off));
        m1 = fmaxf(m1, __shfl_xor(m1, off));
    }
#pragma unroll
    for (int i = 0; i < 32; ++i) { x0[i] -= m0; x1[i] -= m1; }

    float lo0 = -1.0f, hi0 = 0.0f, lo1 = -1.0f, hi1 = 0.0f;
    for (int it = 0; it < 4; ++it) {
        float mid0 = 0.5f * (lo0 + hi0), mid1 = 0.5f * (lo1 + hi1);
        float f0 = 0.0f, f1 = 0.0f;
#pragma unroll
        for (int i = 0; i < 32; ++i) {
            float a = fmaxf(x0[i] - mid0, 0.0f);
            float bq = fmaxf(x1[i] - mid1, 0.0f);
            f0 = fmaf(a, a, f0);
            f1 = fmaf(bq, bq, f1);
        }
#pragma unroll
        for (int off = 1; off < 32; off <<= 1) {
            f0 += __shfl_xor(f0, off);
            f1 += __shfl_xor(f1, off);
        }
        if (f0 >= 1.0f) lo0 = mid0; else hi0 = mid0;
        if (f1 >= 1.0f) lo1 = mid1; else hi1 = mid1;
    }
    float tau0 = lo0, tau1 = lo1;
    for (int it = 0; it < 2; ++it) {
        float a1 = 0.0f, a2 = 0.0f, b1 = 0.0f, b2 = 0.0f;
#pragma unroll
        for (int i = 0; i < 32; ++i) {
            float a = fmaxf(x0[i] - tau0, 0.0f);
            float bq = fmaxf(x1[i] - tau1, 0.0f);
            a1 += a; a2 = fmaf(a, a, a2);
            b1 += bq; b2 = fmaf(bq, bq, b2);
        }
#pragma unroll
        for (int off = 1; off < 32; off <<= 1) {
            a1 += __shfl_xor(a1, off);
            a2 += __shfl_xor(a2, off);
            b1 += __shfl_xor(b1, off);
            b2 += __shfl_xor(b2, off);
        }
        tau0 += (a2 - 1.0f) / (2.0f * a1);
        tau1 += (b2 - 1.0f) / (2.0f * b1);
    }

#pragma unroll
    for (int j = 0; j < 4; ++j) {
        ushort4 o0a, o0b, o1a, o1b;
#pragma unroll
        for (int m = 0; m < 4; ++m) {
            float a = fmaxf(x0[8 * j + m] - tau0, 0.0f);
            float bq = fmaxf(x0[8 * j + 4 + m] - tau0, 0.0f);
            float cc = fmaxf(x1[8 * j + m] - tau1, 0.0f);
            float d = fmaxf(x1[8 * j + 4 + m] - tau1, 0.0f);
            ((unsigned short*)&o0a)[m] = f2bf(a * a);
            ((unsigned short*)&o0b)[m] = f2bf(bq * bq);
            ((unsigned short*)&o1a)[m] = f2bf(cc * cc);
            ((unsigned short*)&o1b)[m] = f2bf(d * d);
        }
        *(ushort4*)&Sb[r0 * SSTR + c * 8 + 256 * j] = o0a;
        *(ushort4*)&Sb[r0 * SSTR + c * 8 + 256 * j + 4] = o0b;
        *(ushort4*)&Sb[r1 * SSTR + c * 8 + 256 * j] = o1a;
        *(ushort4*)&Sb[r1 * SSTR + c * 8 + 256 * j + 4] = o1b;
    }
    __syncthreads();

    // ---- Phase 3: PV from packed Vt ----
    const int i3 = w >> 2;              // q row-tile (0/1)
    const int fb = w & 3;               // d block (16 cols)
    const unsigned short* VtB = Vt + ((size_t)bh * 4 + fb) * 32 * 512 + lane * 8;
    const unsigned short* Prow = &Sb[(i3 * 16 + lr) * SSTR + qg * 8];
    f32x4 pacc = {};
#pragma unroll
    for (int s = 0; s < 32; ++s) {
        bf16x8 pa = *(const bf16x8*)&Prow[s * 32];
        bf16x8 vb = *(const bf16x8*)&VtB[s * 512];
        pacc = MFMA(pa, vb, pacc);
    }
#pragma unroll
    for (int r = 0; r < 4; ++r) {
        int m = b * L + qt * 32 + i3 * 16 + qg * 4 + r;
        int d = fb * 16 + lr;
        AO[(size_t)m * DM + h * DK + d] = f2bf(pacc[r]);
    }
}

// ---------------------------------------------------------------------------
// Out projection: out = AO(bf16) @ Wo^T(bf16), fp32 out.
// BM=64, BN=64, BK=64, 4 waves. grid (16,32)=512 blocks.
// ---------------------------------------------------------------------------
__global__ __launch_bounds__(256) void out_kernel(
    const unsigned short* __restrict__ A, const unsigned short* __restrict__ W,
    float* __restrict__ O)
{
    __shared__ unsigned short Ab[64][72];
    __shared__ unsigned short Bb[64][72];

    const int t = threadIdx.x;
    const int w = t >> 6, lane = t & 63, qg = lane >> 4, lr = lane & 15;
    const int wr = w >> 1, wc = w & 1;
    const int mbase = blockIdx.y * 64, nbase = blockIdx.x * 64;

    f32x4 acc[2][2] = {};

    for (int kt = 0; kt < 16; ++kt) {
        const int kb = kt * 64;
#pragma unroll
        for (int rr = 0; rr < 2; ++rr) {
            int f = t + 256 * rr;
            int row = f >> 3;
            int c8 = (f & 7) << 3;
            *(bf16x8*)&Ab[row][c8] = *(const bf16x8*)&A[(size_t)(mbase + row) * DM + kb + c8];
        }
#pragma unroll
        for (int rr = 0; rr < 2; ++rr) {
            int f = t + 256 * rr;
            int row = f >> 3;
            int c8 = (f & 7) << 3;
            *(bf16x8*)&Bb[row][c8] = *(const bf16x8*)&W[(size_t)(nbase + row) * DM + kb + c8];
        }
        __syncthreads();
#pragma unroll
        for (int ks = 0; ks < 2; ++ks) {
            const int k0 = ks * 32 + qg * 8;
            bf16x8 a[2], bfr[2];
#pragma unroll
            for (int i = 0; i < 2; ++i)
                a[i] = *(const bf16x8*)&Ab[wr * 32 + i * 16 + lr][k0];
#pragma unroll
            for (int j = 0; j < 2; ++j)
                bfr[j] = *(const bf16x8*)&Bb[wc * 32 + j * 16 + lr][k0];
#pragma unroll
            for (int i = 0; i < 2; ++i)
#pragma unroll
                for (int j = 0; j < 2; ++j)
                    acc[i][j] = MFMA(a[i], bfr[j], acc[i][j]);
        }
        __syncthreads();
    }

#pragma unroll
    for (int i = 0; i < 2; ++i)
#pragma unroll
        for (int j = 0; j < 2; ++j)
#pragma unroll
            for (int r = 0; r < 4; ++r) {
                int m = mbase + wr * 32 + i * 16 + qg * 4 + r;
                int n = nbase + wc * 32 + j * 16 + lr;
                O[(size_t)m * DM + n] = acc[i][j][r];
            }
}

extern "C" void kernel_launch(void* const* d_in, const int* in_sizes, int n_in,
                              void* d_out, int out_size, void* d_ws, size_t ws_size,
                              hipStream_t stream)
{
    const float* q  = (const float*)d_in[0];
    const float* k  = (const float*)d_in[1];
    const float* v  = (const float*)d_in[2];
    const int* mask = (const int*)d_in[3];
    const float* wq = (const float*)d_in[4];
    const float* wk = (const float*)d_in[5];
    const float* wv = (const float*)d_in[6];
    const float* wo = (const float*)d_in[7];

    char* wsb = (char*)d_ws;
    const size_t MB = (size_t)1 << 20;
    unsigned short* Qh  = (unsigned short*)(wsb + 0 * MB);
    unsigned short* Ql  = (unsigned short*)(wsb + 4 * MB);
    unsigned short* Kh  = (unsigned short*)(wsb + 8 * MB);
    unsigned short* Kl  = (unsigned short*)(wsb + 12 * MB);
    unsigned short* Vt  = (unsigned short*)(wsb + 16 * MB);
    unsigned short* AO  = (unsigned short*)(wsb + 20 * MB);
    unsigned short* Xqb = (unsigned short*)(wsb + 24 * MB);
    unsigned short* Xkb = (unsigned short*)(wsb + 28 * MB);
    unsigned short* Xvb = (unsigned short*)(wsb + 32 * MB);
    unsigned short* Wqb = (unsigned short*)(wsb + 36 * MB);
    unsigned short* Wkb = (unsigned short*)(wsb + 38 * MB);
    unsigned short* Wvb = (unsigned short*)(wsb + 40 * MB);
    unsigned short* Wob = (unsigned short*)(wsb + 42 * MB);
    unsigned short* Mp  = Xqb;   // 2 MB, written AFTER proj consumes Xqb

    convert_bf16<<<dim3(1024), 256, 0, stream>>>(q, k, v, wq, wk, wv, wo,
                                                 Xqb, Xkb, Xvb, Wqb, Wkb, Wvb, Wob);
    proj_kernel<<<dim3(16, 16, 3), 256, 0, stream>>>(Xqb, Xkb, Xvb, Wqb, Wkb, Wvb,
                                                     Qh, Ql, Kh, Kl, Vt);
    pack_mask<<<dim3(1024), 256, 0, stream>>>(mask, Mp);
    attn_kernel<<<dim3(32, 32), 512, 0, stream>>>(Qh, Ql, Kh, Kl, Vt, Mp, AO);
    out_kernel<<<dim3(16, 32), 256, 0, stream>>>(AO, Wob, (float*)d_out);
}

// Round 9
// 113.745 us; speedup vs baseline: 4.2792x; 1.0515x over previous
//
#include <hip/hip_runtime.h>

#define L 1024
#define DM 1024
#define NH 16
#define DK 64

typedef __attribute__((ext_vector_type(8))) short bf16x8;
typedef __attribute__((ext_vector_type(4))) float f32x4;
typedef _Float16 h2 __attribute__((ext_vector_type(2)));

#define MFMA(a, b, c) __builtin_amdgcn_mfma_f32_16x16x32_bf16(a, b, c, 0, 0, 0)

__device__ inline unsigned short f2bf(float f) {
    unsigned int u = __builtin_bit_cast(unsigned int, f);
    u += 0x7FFFu + ((u >> 16) & 1u);
    return (unsigned short)(u >> 16);
}
__device__ inline float bf2f(unsigned short h) {
    unsigned int u = ((unsigned int)h) << 16;
    return __builtin_bit_cast(float, u);
}
__device__ inline unsigned short f2h(float f) {
    return __builtin_bit_cast(unsigned short, (_Float16)f);
}
__device__ inline float h2f(unsigned short u) {
    return (float)__builtin_bit_cast(_Float16, u);
}

__device__ inline h2 h2splat(float v) {
    h2 r; r[0] = (_Float16)v; r[1] = (_Float16)v; return r;
}
__device__ inline h2 h2max(h2 a, h2 b) {
#if defined(__has_builtin)
#if __has_builtin(__builtin_elementwise_max)
    return __builtin_elementwise_max(a, b);
#else
    h2 r; r[0] = a[0] > b[0] ? a[0] : b[0]; r[1] = a[1] > b[1] ? a[1] : b[1]; return r;
#endif
#else
    h2 r; r[0] = a[0] > b[0] ? a[0] : b[0]; r[1] = a[1] > b[1] ? a[1] : b[1]; return r;
#endif
}

// f32-accumulating fp16 pair dot: a[0]*b[0] + a[1]*b[1] + c
__device__ inline float dot2acc(h2 a, h2 b, float c) {
#if defined(__has_builtin)
#if __has_builtin(__builtin_amdgcn_fdot2)
    return __builtin_amdgcn_fdot2(a, b, c, false);
#else
    return c + (float)a[0] * (float)b[0] + (float)a[1] * (float)b[1];
#endif
#else
    return c + (float)a[0] * (float)b[0] + (float)a[1] * (float)b[1];
#endif
}

// ---------------------------------------------------------------------------
// One-shot fp32 -> bf16 conversion of all GEMM inputs.
// ---------------------------------------------------------------------------
__global__ __launch_bounds__(256) void convert_bf16(
    const float* __restrict__ q, const float* __restrict__ k, const float* __restrict__ v,
    const float* __restrict__ wq, const float* __restrict__ wk,
    const float* __restrict__ wv, const float* __restrict__ wo,
    unsigned short* __restrict__ Xq, unsigned short* __restrict__ Xk,
    unsigned short* __restrict__ Xv, unsigned short* __restrict__ Wq,
    unsigned short* __restrict__ Wk, unsigned short* __restrict__ Wv,
    unsigned short* __restrict__ Wo)
{
    const size_t M2 = (size_t)1 << 21, M1 = (size_t)1 << 20;
    const size_t nchunks = (3 * M2 + 4 * M1) / 8;
    for (size_t c = (size_t)blockIdx.x * blockDim.x + threadIdx.x; c < nchunks;
         c += (size_t)gridDim.x * blockDim.x) {
        size_t e = c * 8;
        const float* src;
        unsigned short* dst;
        size_t off;
        if (e < 3 * M2) {
            size_t r = e / M2;
            off = e - r * M2;
            src = r == 0 ? q : (r == 1 ? k : v);
            dst = r == 0 ? Xq : (r == 1 ? Xk : Xv);
        } else {
            size_t e2 = e - 3 * M2;
            size_t r = e2 / M1;
            off = e2 - r * M1;
            src = r == 0 ? wq : (r == 1 ? wk : (r == 2 ? wv : wo));
            dst = r == 0 ? Wq : (r == 1 ? Wk : (r == 2 ? Wv : Wo));
        }
        float4 a = *(const float4*)&src[off];
        float4 b = *(const float4*)&src[off + 4];
        ushort4 o0, o1;
        o0.x = f2bf(a.x); o0.y = f2bf(a.y); o0.z = f2bf(a.z); o0.w = f2bf(a.w);
        o1.x = f2bf(b.x); o1.y = f2bf(b.y); o1.z = f2bf(b.z); o1.w = f2bf(b.w);
        *(ushort4*)&dst[off] = o0;
        *(ushort4*)&dst[off + 4] = o1;
    }
}

// ---------------------------------------------------------------------------
// Mask -> packed fp16 additive-bias fragments.
// ---------------------------------------------------------------------------
__global__ __launch_bounds__(256) void pack_mask(const int* __restrict__ mask,
                                                 unsigned short* __restrict__ Mp)
{
    int id = blockIdx.x * 256 + threadIdx.x;     // 0 .. 262143
    int lane = id & 63;
    int kblk = (id >> 6) & 63;
    int qtile = id >> 12;                        // 0..63
    int qabs = qtile * 16 + (lane & 15);
    int kcol = kblk * 16 + (lane >> 4) * 4;
    int4 m = *(const int4*)&mask[(size_t)qabs * L + kcol];
    unsigned short neg = f2h(-60000.0f);
    ushort4 o;
    o.x = (m.x == 0) ? neg : (unsigned short)0;
    o.y = (m.y == 0) ? neg : (unsigned short)0;
    o.z = (m.z == 0) ? neg : (unsigned short)0;
    o.w = (m.w == 0) ? neg : (unsigned short)0;
    *(ushort4*)&Mp[(size_t)id * 4] = o;
}

// ---------------------------------------------------------------------------
// Projections: Y = X @ W^T. Fragment-linear outputs.
//  z=0/1: Q/K hi+lo  [bh][tile(64)][ks(2)][lane(64)][8] -- LDS-repacked,
//         coalesced bf16x8 stores.
//  z=2:   V          [bh][fb(4)][s(32)][lane(64)][8]
// BM=128, BN=64, BK=64, 4 waves. grid (16,16,3)=768.
// ---------------------------------------------------------------------------
__global__ __launch_bounds__(256) void proj_kernel(
    const unsigned short* __restrict__ Xq, const unsigned short* __restrict__ Xk,
    const unsigned short* __restrict__ Xv, const unsigned short* __restrict__ Wq,
    const unsigned short* __restrict__ Wk, const unsigned short* __restrict__ Wv,
    unsigned short* __restrict__ Qh, unsigned short* __restrict__ Ql,
    unsigned short* __restrict__ Kh, unsigned short* __restrict__ Kl,
    unsigned short* __restrict__ Vt)
{
    const int z = blockIdx.z;
    const unsigned short* X = z == 0 ? Xq : (z == 1 ? Xk : Xv);
    const unsigned short* W = z == 0 ? Wq : (z == 1 ? Wk : Wv);

    __shared__ unsigned short Ab[128][72];
    __shared__ unsigned short Bb[64][72];

    const int t = threadIdx.x;
    const int w = t >> 6, lane = t & 63, qg = lane >> 4, lr = lane & 15;
    const int wr = w >> 1, wc = w & 1;
    const int mbase = blockIdx.y * 128, nbase = blockIdx.x * 64;

    f32x4 acc[4][2] = {};

    for (int kt = 0; kt < 16; ++kt) {
        const int kb = kt * 64;
#pragma unroll
        for (int rr = 0; rr < 4; ++rr) {
            int f = t + 256 * rr;
            int row = f >> 3;
            int c8 = (f & 7) << 3;
            *(bf16x8*)&Ab[row][c8] = *(const bf16x8*)&X[(size_t)(mbase + row) * DM + kb + c8];
        }
#pragma unroll
        for (int rr = 0; rr < 2; ++rr) {
            int f = t + 256 * rr;
            int row = f >> 3;
            int c8 = (f & 7) << 3;
            *(bf16x8*)&Bb[row][c8] = *(const bf16x8*)&W[(size_t)(nbase + row) * DM + kb + c8];
        }
        __syncthreads();
#pragma unroll
        for (int ks = 0; ks < 2; ++ks) {
            const int k0 = ks * 32 + qg * 8;
            bf16x8 a[4], bfr[2];
#pragma unroll
            for (int i = 0; i < 4; ++i)
                a[i] = *(const bf16x8*)&Ab[wr * 64 + i * 16 + lr][k0];
#pragma unroll
            for (int j = 0; j < 2; ++j)
                bfr[j] = *(const bf16x8*)&Bb[wc * 32 + j * 16 + lr][k0];
#pragma unroll
            for (int i = 0; i < 4; ++i)
#pragma unroll
                for (int j = 0; j < 2; ++j)
                    acc[i][j] = MFMA(a[i], bfr[j], acc[i][j]);
        }
        __syncthreads();
    }

    if (z < 2) {
        unsigned short* Oh = z ? Kh : Qh;
        unsigned short* Ol = z ? Kl : Ql;
        const int b = mbase >> 10, h = nbase >> 6;
        const int bh = b * NH + h;
        const int tile0 = (mbase & 1023) >> 4;
        const size_t plane = ((size_t)bh * 64 + tile0) * 1024;
        unsigned short* Lh = &Ab[0][0];   // 8192 halves = 16 KB repack buffer

        // pass 1: hi
#pragma unroll
        for (int i = 0; i < 4; ++i)
#pragma unroll
            for (int j = 0; j < 2; ++j) {
                int d = wc * 32 + j * 16 + lr;
                int ks = d >> 5, qg_p = (d >> 3) & 3, e = d & 7;
                int ti = wr * 4 + i;
#pragma unroll
                for (int r = 0; r < 4; ++r) {
                    int lane_p = qg_p * 16 + qg * 4 + r;
                    Lh[((ti * 2 + ks) * 64 + lane_p) * 8 + e] = f2bf(acc[i][j][r]);
                }
            }
        __syncthreads();
#pragma unroll
        for (int cch = 0; cch < 4; ++cch) {
            int f = cch * 2048 + t * 8;
            *(bf16x8*)&Oh[plane + f] = *(const bf16x8*)&Lh[f];
        }
        __syncthreads();
        // pass 2: lo
#pragma unroll
        for (int i = 0; i < 4; ++i)
#pragma unroll
            for (int j = 0; j < 2; ++j) {
                int d = wc * 32 + j * 16 + lr;
                int ks = d >> 5, qg_p = (d >> 3) & 3, e = d & 7;
                int ti = wr * 4 + i;
#pragma unroll
                for (int r = 0; r < 4; ++r) {
                    float vv = acc[i][j][r];
                    unsigned short hi_ = f2bf(vv);
                    int lane_p = qg_p * 16 + qg * 4 + r;
                    Lh[((ti * 2 + ks) * 64 + lane_p) * 8 + e] = f2bf(vv - bf2f(hi_));
                }
            }
        __syncthreads();
#pragma unroll
        for (int cch = 0; cch < 4; ++cch) {
            int f = cch * 2048 + t * 8;
            *(bf16x8*)&Ol[plane + f] = *(const bf16x8*)&Lh[f];
        }
    } else {
#pragma unroll
        for (int i = 0; i < 4; ++i)
#pragma unroll
            for (int j = 0; j < 2; ++j) {
                int n = nbase + wc * 32 + j * 16 + lr;
                int h = n >> 6, d = n & 63;
                int fb = d >> 4, lr2 = d & 15;
                int m0 = mbase + wr * 64 + i * 16 + qg * 4;
                int b = m0 >> 10, l0 = m0 & 1023;
                int s = l0 >> 5, qg2 = (l0 >> 3) & 3, e0 = l0 & 7;
                int bh = b * NH + h;
                size_t idx = (((size_t)bh * 4 + fb) * 32 + s) * 512 + qg2 * 128 + lr2 * 8 + e0;
                ushort4 o;
                o.x = f2bf(acc[i][j][0]); o.y = f2bf(acc[i][j][1]);
                o.z = f2bf(acc[i][j][2]); o.w = f2bf(acc[i][j][3]);
                *(ushort4*)&Vt[idx] = o;
            }
    }
}

// ---------------------------------------------------------------------------
// Fused attention. Block = (32 Q-rows, one bh). 512 thr, 8 waves. grid (32,32).
// Phase 2 entmax packed fp16 via native h2 vectors (v_pk_* + v_dot2_f32_f16).
// ---------------------------------------------------------------------------
#define SSTR 1048
__global__ __launch_bounds__(512, 4) void attn_kernel(
    const unsigned short* __restrict__ Qh, const unsigned short* __restrict__ Ql,
    const unsigned short* __restrict__ Kh, const unsigned short* __restrict__ Kl,
    const unsigned short* __restrict__ Vt, const unsigned short* __restrict__ Mp,
    unsigned short* __restrict__ AO)
{
    __shared__ unsigned short Sb[32 * SSTR];   // fp16 scores, then bf16 probs

    const int t = threadIdx.x;
    const int w = t >> 6, lane = t & 63, qg = lane >> 4, lr = lane & 15;
    const int bh = blockIdx.y;
    const int b = bh >> 4, h = bh & 15;
    const int qt = blockIdx.x;
    const size_t plane = (size_t)bh << 16;

    // ---- Phase 1: transposed QK^T ----
    bf16x8 qh_[2][2], ql_[2][2];
#pragma unroll
    for (int i = 0; i < 2; ++i)
#pragma unroll
        for (int ks = 0; ks < 2; ++ks) {
            size_t qa = plane + (size_t)(qt * 2 + i) * 1024 + ks * 512 + lane * 8;
            qh_[i][ks] = *(const bf16x8*)&Qh[qa];
            ql_[i][ks] = *(const bf16x8*)&Ql[qa];
        }

#pragma unroll
    for (int j = 0; j < 8; ++j) {
        const int kblk = w * 8 + j;
        const size_t ka = plane + (size_t)kblk * 1024 + lane * 8;
        bf16x8 kh0 = *(const bf16x8*)&Kh[ka];
        bf16x8 kh1 = *(const bf16x8*)&Kh[ka + 512];
        bf16x8 kl0 = *(const bf16x8*)&Kl[ka];
        bf16x8 kl1 = *(const bf16x8*)&Kl[ka + 512];
#pragma unroll
        for (int i = 0; i < 2; ++i) {
            f32x4 acc = {};
            acc = MFMA(kh0, qh_[i][0], acc);
            acc = MFMA(kl0, qh_[i][0], acc);
            acc = MFMA(kh0, ql_[i][0], acc);
            acc = MFMA(kh1, qh_[i][1], acc);
            acc = MFMA(kl1, qh_[i][1], acc);
            acc = MFMA(kh1, ql_[i][1], acc);
            ushort4 mb = *(const ushort4*)&Mp[(((size_t)(qt * 2 + i) * 64 + kblk) * 64 + lane) * 4];
            float s0 = fmaf(acc[0], 0.0625f, h2f(mb.x));
            float s1 = fmaf(acc[1], 0.0625f, h2f(mb.y));
            float s2 = fmaf(acc[2], 0.0625f, h2f(mb.z));
            float s3 = fmaf(acc[3], 0.0625f, h2f(mb.w));
            ushort4 pk;
            pk.x = f2h(s0); pk.y = f2h(s1); pk.z = f2h(s2); pk.w = f2h(s3);
            *(ushort4*)&Sb[(i * 16 + lr) * SSTR + kblk * 16 + qg * 4] = pk;
        }
    }
    __syncthreads();

    // ---- Phase 2: entmax-1.5, packed fp16, two interleaved solves ----
    const int half_id = lane >> 5;
    const int c = lane & 31;
    const int r0 = w * 2 + half_id;
    const int r1 = 16 + r0;
    h2 x0[16], x1[16];
#pragma unroll
    for (int j = 0; j < 4; ++j) {
        uint4 u0 = *(const uint4*)&Sb[r0 * SSTR + c * 8 + 256 * j];
        uint4 u1 = *(const uint4*)&Sb[r1 * SSTR + c * 8 + 256 * j];
        const h2* p0 = (const h2*)&u0;
        const h2* p1 = (const h2*)&u1;
#pragma unroll
        for (int m = 0; m < 4; ++m) {
            x0[4 * j + m] = p0[m];
            x1[4 * j + m] = p1[m];
        }
    }

    h2 mp0 = x0[0], mp1 = x1[0];
#pragma unroll
    for (int i = 1; i < 16; ++i) {
        mp0 = h2max(mp0, x0[i]);
        mp1 = h2max(mp1, x1[i]);
    }
    float m0 = fmaxf((float)mp0[0], (float)mp0[1]);
    float m1 = fmaxf((float)mp1[0], (float)mp1[1]);
#pragma unroll
    for (int off = 1; off < 32; off <<= 1) {
        m0 = fmaxf(m0, __shfl_xor(m0, off));
        m1 = fmaxf(m1, __shfl_xor(m1, off));
    }
    {
        h2 m02 = h2splat(m0), m12 = h2splat(m1);
#pragma unroll
        for (int i = 0; i < 16; ++i) {
            x0[i] = x0[i] - m02;
            x1[i] = x1[i] - m12;
        }
    }

    const h2 zero2 = h2splat(0.0f);
    const h2 one2 = h2splat(1.0f);
    float lo0 = -1.0f, hi0 = 0.0f, lo1 = -1.0f, hi1 = 0.0f;
    for (int it = 0; it < 4; ++it) {
        float mid0 = 0.5f * (lo0 + hi0), mid1 = 0.5f * (lo1 + hi1);
        h2 mid02 = h2splat(mid0), mid12 = h2splat(mid1);
        float f0 = 0.0f, f1 = 0.0f;
#pragma unroll
        for (int i = 0; i < 16; ++i) {
            h2 a = h2max(x0[i] - mid02, zero2);
            h2 bq = h2max(x1[i] - mid12, zero2);
            f0 = dot2acc(a, a, f0);
            f1 = dot2acc(bq, bq, f1);
        }
#pragma unroll
        for (int off = 1; off < 32; off <<= 1) {
            f0 += __shfl_xor(f0, off);
            f1 += __shfl_xor(f1, off);
        }
        if (f0 >= 1.0f) lo0 = mid0; else hi0 = mid0;
        if (f1 >= 1.0f) lo1 = mid1; else hi1 = mid1;
    }
    float tau0 = lo0, tau1 = lo1;
    for (int it = 0; it < 2; ++it) {
        h2 t02 = h2splat(tau0), t12 = h2splat(tau1);
        float a1 = 0.0f, a2 = 0.0f, b1 = 0.0f, b2 = 0.0f;
#pragma unroll
        for (int i = 0; i < 16; ++i) {
            h2 a = h2max(x0[i] - t02, zero2);
            h2 bq = h2max(x1[i] - t12, zero2);
            a1 = dot2acc(a, one2, a1);
            a2 = dot2acc(a, a, a2);
            b1 = dot2acc(bq, one2, b1);
            b2 = dot2acc(bq, bq, b2);
        }
#pragma unroll
        for (int off = 1; off < 32; off <<= 1) {
            a1 += __shfl_xor(a1, off);
            a2 += __shfl_xor(a2, off);
            b1 += __shfl_xor(b1, off);
            b2 += __shfl_xor(b2, off);
        }
        tau0 += (a2 - 1.0f) / (2.0f * a1);
        tau1 += (b2 - 1.0f) / (2.0f * b1);
    }

    {
        h2 t02 = h2splat(tau0), t12 = h2splat(tau1);
#pragma unroll
        for (int j = 0; j < 4; ++j) {
            ushort4 oa, ob, oc, od;
            unsigned short* pa = (unsigned short*)&oa;
            unsigned short* pb = (unsigned short*)&ob;
            unsigned short* pc = (unsigned short*)&oc;
            unsigned short* pd = (unsigned short*)&od;
#pragma unroll
            for (int qq = 0; qq < 2; ++qq) {
                h2 ra = h2max(x0[4 * j + qq] - t02, zero2);
                h2 rb = h2max(x0[4 * j + 2 + qq] - t02, zero2);
                h2 rc = h2max(x1[4 * j + qq] - t12, zero2);
                h2 rd = h2max(x1[4 * j + 2 + qq] - t12, zero2);
                float al = (float)ra[0], ah = (float)ra[1];
                float bl = (float)rb[0], bhf = (float)rb[1];
                float cl = (float)rc[0], ch = (float)rc[1];
                float dl = (float)rd[0], dh = (float)rd[1];
                pa[2 * qq] = f2bf(al * al); pa[2 * qq + 1] = f2bf(ah * ah);
                pb[2 * qq] = f2bf(bl * bl); pb[2 * qq + 1] = f2bf(bhf * bhf);
                pc[2 * qq] = f2bf(cl * cl); pc[2 * qq + 1] = f2bf(ch * ch);
                pd[2 * qq] = f2bf(dl * dl); pd[2 * qq + 1] = f2bf(dh * dh);
            }
            *(ushort4*)&Sb[r0 * SSTR + c * 8 + 256 * j] = oa;
            *(ushort4*)&Sb[r0 * SSTR + c * 8 + 256 * j + 4] = ob;
            *(ushort4*)&Sb[r1 * SSTR + c * 8 + 256 * j] = oc;
            *(ushort4*)&Sb[r1 * SSTR + c * 8 + 256 * j + 4] = od;
        }
    }
    __syncthreads();

    // ---- Phase 3: PV from packed Vt ----
    const int i3 = w >> 2;
    const int fb = w & 3;
    const unsigned short* VtB = Vt + ((size_t)bh * 4 + fb) * 32 * 512 + lane * 8;
    const unsigned short* Prow = &Sb[(i3 * 16 + lr) * SSTR + qg * 8];
    f32x4 pacc = {};
#pragma unroll
    for (int s = 0; s < 32; ++s) {
        bf16x8 pa = *(const bf16x8*)&Prow[s * 32];
        bf16x8 vb = *(const bf16x8*)&VtB[s * 512];
        pacc = MFMA(pa, vb, pacc);
    }
#pragma unroll
    for (int r = 0; r < 4; ++r) {
        int m = b * L + qt * 32 + i3 * 16 + qg * 4 + r;
        int d = fb * 16 + lr;
        AO[(size_t)m * DM + h * DK + d] = f2bf(pacc[r]);
    }
}

// ---------------------------------------------------------------------------
// Out projection: out = AO(bf16) @ Wo^T(bf16), fp32 out.
// BM=64, BN=64, BK=64, 4 waves. grid (16,32)=512 blocks.
// ---------------------------------------------------------------------------
__global__ __launch_bounds__(256) void out_kernel(
    const unsigned short* __restrict__ A, const unsigned short* __restrict__ W,
    float* __restrict__ O)
{
    __shared__ unsigned short Ab[64][72];
    __shared__ unsigned short Bb[64][72];

    const int t = threadIdx.x;
    const int w = t >> 6, lane = t & 63, qg = lane >> 4, lr = lane & 15;
    const int wr = w >> 1, wc = w & 1;
    const int mbase = blockIdx.y * 64, nbase = blockIdx.x * 64;

    f32x4 acc[2][2] = {};

    for (int kt = 0; kt < 16; ++kt) {
        const int kb = kt * 64;
#pragma unroll
        for (int rr = 0; rr < 2; ++rr) {
            int f = t + 256 * rr;
            int row = f >> 3;
            int c8 = (f & 7) << 3;
            *(bf16x8*)&Ab[row][c8] = *(const bf16x8*)&A[(size_t)(mbase + row) * DM + kb + c8];
        }
#pragma unroll
        for (int rr = 0; rr < 2; ++rr) {
            int f = t + 256 * rr;
            int row = f >> 3;
            int c8 = (f & 7) << 3;
            *(bf16x8*)&Bb[row][c8] = *(const bf16x8*)&W[(size_t)(nbase + row) * DM + kb + c8];
        }
        __syncthreads();
#pragma unroll
        for (int ks = 0; ks < 2; ++ks) {
            const int k0 = ks * 32 + qg * 8;
            bf16x8 a[2], bfr[2];
#pragma unroll
            for (int i = 0; i < 2; ++i)
                a[i] = *(const bf16x8*)&Ab[wr * 32 + i * 16 + lr][k0];
#pragma unroll
            for (int j = 0; j < 2; ++j)
                bfr[j] = *(const bf16x8*)&Bb[wc * 32 + j * 16 + lr][k0];
#pragma unroll
            for (int i = 0; i < 2; ++i)
#pragma unroll
                for (int j = 0; j < 2; ++j)
                    acc[i][j] = MFMA(a[i], bfr[j], acc[i][j]);
        }
        __syncthreads();
    }

#pragma unroll
    for (int i = 0; i < 2; ++i)
#pragma unroll
        for (int j = 0; j < 2; ++j)
#pragma unroll
            for (int r = 0; r < 4; ++r) {
                int m = mbase + wr * 32 + i * 16 + qg * 4 + r;
                int n = nbase + wc * 32 + j * 16 + lr;
                O[(size_t)m * DM + n] = acc[i][j][r];
            }
}

extern "C" void kernel_launch(void* const* d_in, const int* in_sizes, int n_in,
                              void* d_out, int out_size, void* d_ws, size_t ws_size,
                              hipStream_t stream)
{
    const float* q  = (const float*)d_in[0];
    const float* k  = (const float*)d_in[1];
    const float* v  = (const float*)d_in[2];
    const int* mask = (const int*)d_in[3];
    const float* wq = (const float*)d_in[4];
    const float* wk = (const float*)d_in[5];
    const float* wv = (const float*)d_in[6];
    const float* wo = (const float*)d_in[7];

    char* wsb = (char*)d_ws;
    const size_t MB = (size_t)1 << 20;
    unsigned short* Qh  = (unsigned short*)(wsb + 0 * MB);
    unsigned short* Ql  = (unsigned short*)(wsb + 4 * MB);
    unsigned short* Kh  = (unsigned short*)(wsb + 8 * MB);
    unsigned short* Kl  = (unsigned short*)(wsb + 12 * MB);
    unsigned short* Vt  = (unsigned short*)(wsb + 16 * MB);
    unsigned short* AO  = (unsigned short*)(wsb + 20 * MB);
    unsigned short* Xqb = (unsigned short*)(wsb + 24 * MB);
    unsigned short* Xkb = (unsigned short*)(wsb + 28 * MB);
    unsigned short* Xvb = (unsigned short*)(wsb + 32 * MB);
    unsigned short* Wqb = (unsigned short*)(wsb + 36 * MB);
    unsigned short* Wkb = (unsigned short*)(wsb + 38 * MB);
    unsigned short* Wvb = (unsigned short*)(wsb + 40 * MB);
    unsigned short* Wob = (unsigned short*)(wsb + 42 * MB);
    unsigned short* Mp  = Xqb;   // 2 MB, written AFTER proj consumes Xqb

    convert_bf16<<<dim3(1024), 256, 0, stream>>>(q, k, v, wq, wk, wv, wo,
                                                 Xqb, Xkb, Xvb, Wqb, Wkb, Wvb, Wob);
    proj_kernel<<<dim3(16, 16, 3), 256, 0, stream>>>(Xqb, Xkb, Xvb, Wqb, Wkb, Wvb,
                                                     Qh, Ql, Kh, Kl, Vt);
    pack_mask<<<dim3(1024), 256, 0, stream>>>(mask, Mp);
    attn_kernel<<<dim3(32, 32), 512, 0, stream>>>(Qh, Ql, Kh, Kl, Vt, Mp, AO);
    out_kernel<<<dim3(16, 32), 256, 0, stream>>>(AO, Wob, (float*)d_out);
}

// Round 10
// 108.713 us; speedup vs baseline: 4.4772x; 1.0463x over previous
//
#include <hip/hip_runtime.h>

#define L 1024
#define DM 1024
#define NH 16
#define DK 64

typedef __attribute__((ext_vector_type(8))) short bf16x8;
typedef __attribute__((ext_vector_type(4))) float f32x4;
typedef _Float16 h2 __attribute__((ext_vector_type(2)));

#define MFMA(a, b, c) __builtin_amdgcn_mfma_f32_16x16x32_bf16(a, b, c, 0, 0, 0)

__device__ inline unsigned short f2bf(float f) {
    unsigned int u = __builtin_bit_cast(unsigned int, f);
    u += 0x7FFFu + ((u >> 16) & 1u);
    return (unsigned short)(u >> 16);
}
__device__ inline float bf2f(unsigned short h) {
    unsigned int u = ((unsigned int)h) << 16;
    return __builtin_bit_cast(float, u);
}
__device__ inline unsigned short f2h(float f) {
    return __builtin_bit_cast(unsigned short, (_Float16)f);
}
__device__ inline float h2f(unsigned short u) {
    return (float)__builtin_bit_cast(_Float16, u);
}

__device__ inline h2 h2splat(float v) {
    h2 r; r[0] = (_Float16)v; r[1] = (_Float16)v; return r;
}
__device__ inline h2 h2max(h2 a, h2 b) {
#if defined(__has_builtin)
#if __has_builtin(__builtin_elementwise_max)
    return __builtin_elementwise_max(a, b);
#else
    h2 r; r[0] = a[0] > b[0] ? a[0] : b[0]; r[1] = a[1] > b[1] ? a[1] : b[1]; return r;
#endif
#else
    h2 r; r[0] = a[0] > b[0] ? a[0] : b[0]; r[1] = a[1] > b[1] ? a[1] : b[1]; return r;
#endif
}

// f32-accumulating fp16 pair dot: a[0]*b[0] + a[1]*b[1] + c
__device__ inline float dot2acc(h2 a, h2 b, float c) {
#if defined(__has_builtin)
#if __has_builtin(__builtin_amdgcn_fdot2)
    return __builtin_amdgcn_fdot2(a, b, c, false);
#else
    return c + (float)a[0] * (float)b[0] + (float)a[1] * (float)b[1];
#endif
#else
    return c + (float)a[0] * (float)b[0] + (float)a[1] * (float)b[1];
#endif
}

// ---------------------------------------------------------------------------
// One-shot fp32 -> bf16 conversion of all GEMM inputs.
// ---------------------------------------------------------------------------
__global__ __launch_bounds__(256) void convert_bf16(
    const float* __restrict__ q, const float* __restrict__ k, const float* __restrict__ v,
    const float* __restrict__ wq, const float* __restrict__ wk,
    const float* __restrict__ wv, const float* __restrict__ wo,
    unsigned short* __restrict__ Xq, unsigned short* __restrict__ Xk,
    unsigned short* __restrict__ Xv, unsigned short* __restrict__ Wq,
    unsigned short* __restrict__ Wk, unsigned short* __restrict__ Wv,
    unsigned short* __restrict__ Wo)
{
    const size_t M2 = (size_t)1 << 21, M1 = (size_t)1 << 20;
    const size_t nchunks = (3 * M2 + 4 * M1) / 8;
    for (size_t c = (size_t)blockIdx.x * blockDim.x + threadIdx.x; c < nchunks;
         c += (size_t)gridDim.x * blockDim.x) {
        size_t e = c * 8;
        const float* src;
        unsigned short* dst;
        size_t off;
        if (e < 3 * M2) {
            size_t r = e / M2;
            off = e - r * M2;
            src = r == 0 ? q : (r == 1 ? k : v);
            dst = r == 0 ? Xq : (r == 1 ? Xk : Xv);
        } else {
            size_t e2 = e - 3 * M2;
            size_t r = e2 / M1;
            off = e2 - r * M1;
            src = r == 0 ? wq : (r == 1 ? wk : (r == 2 ? wv : wo));
            dst = r == 0 ? Wq : (r == 1 ? Wk : (r == 2 ? Wv : Wo));
        }
        float4 a = *(const float4*)&src[off];
        float4 b = *(const float4*)&src[off + 4];
        ushort4 o0, o1;
        o0.x = f2bf(a.x); o0.y = f2bf(a.y); o0.z = f2bf(a.z); o0.w = f2bf(a.w);
        o1.x = f2bf(b.x); o1.y = f2bf(b.y); o1.z = f2bf(b.z); o1.w = f2bf(b.w);
        *(ushort4*)&dst[off] = o0;
        *(ushort4*)&dst[off + 4] = o1;
    }
}

// ---------------------------------------------------------------------------
// Mask -> packed fp16 additive-bias fragments.
// ---------------------------------------------------------------------------
__global__ __launch_bounds__(256) void pack_mask(const int* __restrict__ mask,
                                                 unsigned short* __restrict__ Mp)
{
    int id = blockIdx.x * 256 + threadIdx.x;     // 0 .. 262143
    int lane = id & 63;
    int kblk = (id >> 6) & 63;
    int qtile = id >> 12;                        // 0..63
    int qabs = qtile * 16 + (lane & 15);
    int kcol = kblk * 16 + (lane >> 4) * 4;
    int4 m = *(const int4*)&mask[(size_t)qabs * L + kcol];
    unsigned short neg = f2h(-60000.0f);
    ushort4 o;
    o.x = (m.x == 0) ? neg : (unsigned short)0;
    o.y = (m.y == 0) ? neg : (unsigned short)0;
    o.z = (m.z == 0) ? neg : (unsigned short)0;
    o.w = (m.w == 0) ? neg : (unsigned short)0;
    *(ushort4*)&Mp[(size_t)id * 4] = o;
}

// ---------------------------------------------------------------------------
// Projections: Y = X @ W^T. Fragment-linear outputs.
//  z=0/1: Q/K hi+lo  [bh][tile(64)][ks(2)][lane(64)][8] -- LDS-repacked,
//         coalesced bf16x8 stores.
//  z=2:   V          [bh][fb(4)][s(32)][lane(64)][8]
// BM=128, BN=64, BK=64, 4 waves. grid (16,16,3)=768.
// ---------------------------------------------------------------------------
__global__ __launch_bounds__(256) void proj_kernel(
    const unsigned short* __restrict__ Xq, const unsigned short* __restrict__ Xk,
    const unsigned short* __restrict__ Xv, const unsigned short* __restrict__ Wq,
    const unsigned short* __restrict__ Wk, const unsigned short* __restrict__ Wv,
    unsigned short* __restrict__ Qh, unsigned short* __restrict__ Ql,
    unsigned short* __restrict__ Kh, unsigned short* __restrict__ Kl,
    unsigned short* __restrict__ Vt)
{
    const int z = blockIdx.z;
    const unsigned short* X = z == 0 ? Xq : (z == 1 ? Xk : Xv);
    const unsigned short* W = z == 0 ? Wq : (z == 1 ? Wk : Wv);

    __shared__ unsigned short Ab[128][72];
    __shared__ unsigned short Bb[64][72];

    const int t = threadIdx.x;
    const int w = t >> 6, lane = t & 63, qg = lane >> 4, lr = lane & 15;
    const int wr = w >> 1, wc = w & 1;
    const int mbase = blockIdx.y * 128, nbase = blockIdx.x * 64;

    f32x4 acc[4][2] = {};

    for (int kt = 0; kt < 16; ++kt) {
        const int kb = kt * 64;
#pragma unroll
        for (int rr = 0; rr < 4; ++rr) {
            int f = t + 256 * rr;
            int row = f >> 3;
            int c8 = (f & 7) << 3;
            *(bf16x8*)&Ab[row][c8] = *(const bf16x8*)&X[(size_t)(mbase + row) * DM + kb + c8];
        }
#pragma unroll
        for (int rr = 0; rr < 2; ++rr) {
            int f = t + 256 * rr;
            int row = f >> 3;
            int c8 = (f & 7) << 3;
            *(bf16x8*)&Bb[row][c8] = *(const bf16x8*)&W[(size_t)(nbase + row) * DM + kb + c8];
        }
        __syncthreads();
#pragma unroll
        for (int ks = 0; ks < 2; ++ks) {
            const int k0 = ks * 32 + qg * 8;
            bf16x8 a[4], bfr[2];
#pragma unroll
            for (int i = 0; i < 4; ++i)
                a[i] = *(const bf16x8*)&Ab[wr * 64 + i * 16 + lr][k0];
#pragma unroll
            for (int j = 0; j < 2; ++j)
                bfr[j] = *(const bf16x8*)&Bb[wc * 32 + j * 16 + lr][k0];
#pragma unroll
            for (int i = 0; i < 4; ++i)
#pragma unroll
                for (int j = 0; j < 2; ++j)
                    acc[i][j] = MFMA(a[i], bfr[j], acc[i][j]);
        }
        __syncthreads();
    }

    if (z < 2) {
        unsigned short* Oh = z ? Kh : Qh;
        unsigned short* Ol = z ? Kl : Ql;
        const int b = mbase >> 10, h = nbase >> 6;
        const int bh = b * NH + h;
        const int tile0 = (mbase & 1023) >> 4;
        const size_t plane = ((size_t)bh * 64 + tile0) * 1024;
        unsigned short* Lh = &Ab[0][0];   // 8192 halves = 16 KB repack buffer

        // pass 1: hi
#pragma unroll
        for (int i = 0; i < 4; ++i)
#pragma unroll
            for (int j = 0; j < 2; ++j) {
                int d = wc * 32 + j * 16 + lr;
                int ks = d >> 5, qg_p = (d >> 3) & 3, e = d & 7;
                int ti = wr * 4 + i;
#pragma unroll
                for (int r = 0; r < 4; ++r) {
                    int lane_p = qg_p * 16 + qg * 4 + r;
                    Lh[((ti * 2 + ks) * 64 + lane_p) * 8 + e] = f2bf(acc[i][j][r]);
                }
            }
        __syncthreads();
#pragma unroll
        for (int cch = 0; cch < 4; ++cch) {
            int f = cch * 2048 + t * 8;
            *(bf16x8*)&Oh[plane + f] = *(const bf16x8*)&Lh[f];
        }
        __syncthreads();
        // pass 2: lo
#pragma unroll
        for (int i = 0; i < 4; ++i)
#pragma unroll
            for (int j = 0; j < 2; ++j) {
                int d = wc * 32 + j * 16 + lr;
                int ks = d >> 5, qg_p = (d >> 3) & 3, e = d & 7;
                int ti = wr * 4 + i;
#pragma unroll
                for (int r = 0; r < 4; ++r) {
                    float vv = acc[i][j][r];
                    unsigned short hi_ = f2bf(vv);
                    int lane_p = qg_p * 16 + qg * 4 + r;
                    Lh[((ti * 2 + ks) * 64 + lane_p) * 8 + e] = f2bf(vv - bf2f(hi_));
                }
            }
        __syncthreads();
#pragma unroll
        for (int cch = 0; cch < 4; ++cch) {
            int f = cch * 2048 + t * 8;
            *(bf16x8*)&Ol[plane + f] = *(const bf16x8*)&Lh[f];
        }
    } else {
#pragma unroll
        for (int i = 0; i < 4; ++i)
#pragma unroll
            for (int j = 0; j < 2; ++j) {
                int n = nbase + wc * 32 + j * 16 + lr;
                int h = n >> 6, d = n & 63;
                int fb = d >> 4, lr2 = d & 15;
                int m0 = mbase + wr * 64 + i * 16 + qg * 4;
                int b = m0 >> 10, l0 = m0 & 1023;
                int s = l0 >> 5, qg2 = (l0 >> 3) & 3, e0 = l0 & 7;
                int bh = b * NH + h;
                size_t idx = (((size_t)bh * 4 + fb) * 32 + s) * 512 + qg2 * 128 + lr2 * 8 + e0;
                ushort4 o;
                o.x = f2bf(acc[i][j][0]); o.y = f2bf(acc[i][j][1]);
                o.z = f2bf(acc[i][j][2]); o.w = f2bf(acc[i][j][3]);
                *(ushort4*)&Vt[idx] = o;
            }
    }
}

// ---------------------------------------------------------------------------
// Fused attention. Block = (32 Q-rows, one bh). 512 thr, 8 waves. grid 1024.
// XCD-locality remap: all 32 qt-blocks of one bh land on the SAME XCD so the
// bh's K/V/Q planes (~640 KB) stay resident in that XCD's 4 MB L2 (4 bh/XCD
// = 2.5 MB). Consecutive dispatch ids round-robin XCDs (id&7).
// ---------------------------------------------------------------------------
#define SSTR 1048
__global__ __launch_bounds__(512, 4) void attn_kernel(
    const unsigned short* __restrict__ Qh, const unsigned short* __restrict__ Ql,
    const unsigned short* __restrict__ Kh, const unsigned short* __restrict__ Kl,
    const unsigned short* __restrict__ Vt, const unsigned short* __restrict__ Mp,
    unsigned short* __restrict__ AO)
{
    __shared__ unsigned short Sb[32 * SSTR];   // fp16 scores, then bf16 probs

    const int t = threadIdx.x;
    const int w = t >> 6, lane = t & 63, qg = lane >> 4, lr = lane & 15;
    // XCD-locality remap (bijective on [0,1024))
    const int lid = blockIdx.y * 32 + blockIdx.x;
    const int xcd = lid & 7;
    const int rest = lid >> 3;          // 0..127
    const int qt = rest & 31;
    const int bh = xcd * 4 + (rest >> 5);
    const int b = bh >> 4, h = bh & 15;
    const size_t plane = (size_t)bh << 16;

    // ---- Phase 1: transposed QK^T ----
    bf16x8 qh_[2][2], ql_[2][2];
#pragma unroll
    for (int i = 0; i < 2; ++i)
#pragma unroll
        for (int ks = 0; ks < 2; ++ks) {
            size_t qa = plane + (size_t)(qt * 2 + i) * 1024 + ks * 512 + lane * 8;
            qh_[i][ks] = *(const bf16x8*)&Qh[qa];
            ql_[i][ks] = *(const bf16x8*)&Ql[qa];
        }

#pragma unroll
    for (int j = 0; j < 8; ++j) {
        const int kblk = w * 8 + j;
        const size_t ka = plane + (size_t)kblk * 1024 + lane * 8;
        bf16x8 kh0 = *(const bf16x8*)&Kh[ka];
        bf16x8 kh1 = *(const bf16x8*)&Kh[ka + 512];
        bf16x8 kl0 = *(const bf16x8*)&Kl[ka];
        bf16x8 kl1 = *(const bf16x8*)&Kl[ka + 512];
#pragma unroll
        for (int i = 0; i < 2; ++i) {
            f32x4 acc = {};
            acc = MFMA(kh0, qh_[i][0], acc);
            acc = MFMA(kl0, qh_[i][0], acc);
            acc = MFMA(kh0, ql_[i][0], acc);
            acc = MFMA(kh1, qh_[i][1], acc);
            acc = MFMA(kl1, qh_[i][1], acc);
            acc = MFMA(kh1, ql_[i][1], acc);
            ushort4 mb = *(const ushort4*)&Mp[(((size_t)(qt * 2 + i) * 64 + kblk) * 64 + lane) * 4];
            float s0 = fmaf(acc[0], 0.0625f, h2f(mb.x));
            float s1 = fmaf(acc[1], 0.0625f, h2f(mb.y));
            float s2 = fmaf(acc[2], 0.0625f, h2f(mb.z));
            float s3 = fmaf(acc[3], 0.0625f, h2f(mb.w));
            ushort4 pk;
            pk.x = f2h(s0); pk.y = f2h(s1); pk.z = f2h(s2); pk.w = f2h(s3);
            *(ushort4*)&Sb[(i * 16 + lr) * SSTR + kblk * 16 + qg * 4] = pk;
        }
    }
    __syncthreads();

    // ---- Phase 2: entmax-1.5, packed fp16, two interleaved solves ----
    const int half_id = lane >> 5;
    const int c = lane & 31;
    const int r0 = w * 2 + half_id;
    const int r1 = 16 + r0;
    h2 x0[16], x1[16];
#pragma unroll
    for (int j = 0; j < 4; ++j) {
        uint4 u0 = *(const uint4*)&Sb[r0 * SSTR + c * 8 + 256 * j];
        uint4 u1 = *(const uint4*)&Sb[r1 * SSTR + c * 8 + 256 * j];
        const h2* p0 = (const h2*)&u0;
        const h2* p1 = (const h2*)&u1;
#pragma unroll
        for (int m = 0; m < 4; ++m) {
            x0[4 * j + m] = p0[m];
            x1[4 * j + m] = p1[m];
        }
    }

    h2 mp0 = x0[0], mp1 = x1[0];
#pragma unroll
    for (int i = 1; i < 16; ++i) {
        mp0 = h2max(mp0, x0[i]);
        mp1 = h2max(mp1, x1[i]);
    }
    float m0 = fmaxf((float)mp0[0], (float)mp0[1]);
    float m1 = fmaxf((float)mp1[0], (float)mp1[1]);
#pragma unroll
    for (int off = 1; off < 32; off <<= 1) {
        m0 = fmaxf(m0, __shfl_xor(m0, off));
        m1 = fmaxf(m1, __shfl_xor(m1, off));
    }
    {
        h2 m02 = h2splat(m0), m12 = h2splat(m1);
#pragma unroll
        for (int i = 0; i < 16; ++i) {
            x0[i] = x0[i] - m02;
            x1[i] = x1[i] - m12;
        }
    }

    const h2 zero2 = h2splat(0.0f);
    const h2 one2 = h2splat(1.0f);
    float lo0 = -1.0f, hi0 = 0.0f, lo1 = -1.0f, hi1 = 0.0f;
    for (int it = 0; it < 4; ++it) {
        float mid0 = 0.5f * (lo0 + hi0), mid1 = 0.5f * (lo1 + hi1);
        h2 mid02 = h2splat(mid0), mid12 = h2splat(mid1);
        float f0 = 0.0f, f1 = 0.0f;
#pragma unroll
        for (int i = 0; i < 16; ++i) {
            h2 a = h2max(x0[i] - mid02, zero2);
            h2 bq = h2max(x1[i] - mid12, zero2);
            f0 = dot2acc(a, a, f0);
            f1 = dot2acc(bq, bq, f1);
        }
#pragma unroll
        for (int off = 1; off < 32; off <<= 1) {
            f0 += __shfl_xor(f0, off);
            f1 += __shfl_xor(f1, off);
        }
        if (f0 >= 1.0f) lo0 = mid0; else hi0 = mid0;
        if (f1 >= 1.0f) lo1 = mid1; else hi1 = mid1;
    }
    float tau0 = lo0, tau1 = lo1;
    for (int it = 0; it < 2; ++it) {
        h2 t02 = h2splat(tau0), t12 = h2splat(tau1);
        float a1 = 0.0f, a2 = 0.0f, b1 = 0.0f, b2 = 0.0f;
#pragma unroll
        for (int i = 0; i < 16; ++i) {
            h2 a = h2max(x0[i] - t02, zero2);
            h2 bq = h2max(x1[i] - t12, zero2);
            a1 = dot2acc(a, one2, a1);
            a2 = dot2acc(a, a, a2);
            b1 = dot2acc(bq, one2, b1);
            b2 = dot2acc(bq, bq, b2);
        }
#pragma unroll
        for (int off = 1; off < 32; off <<= 1) {
            a1 += __shfl_xor(a1, off);
            a2 += __shfl_xor(a2, off);
            b1 += __shfl_xor(b1, off);
            b2 += __shfl_xor(b2, off);
        }
        tau0 += (a2 - 1.0f) / (2.0f * a1);
        tau1 += (b2 - 1.0f) / (2.0f * b1);
    }

    {
        h2 t02 = h2splat(tau0), t12 = h2splat(tau1);
#pragma unroll
        for (int j = 0; j < 4; ++j) {
            ushort4 oa, ob, oc, od;
            unsigned short* pa = (unsigned short*)&oa;
            unsigned short* pb = (unsigned short*)&ob;
            unsigned short* pc = (unsigned short*)&oc;
            unsigned short* pd = (unsigned short*)&od;
#pragma unroll
            for (int qq = 0; qq < 2; ++qq) {
                h2 ra = h2max(x0[4 * j + qq] - t02, zero2);
                h2 rb = h2max(x0[4 * j + 2 + qq] - t02, zero2);
                h2 rc = h2max(x1[4 * j + qq] - t12, zero2);
                h2 rd = h2max(x1[4 * j + 2 + qq] - t12, zero2);
                float al = (float)ra[0], ah = (float)ra[1];
                float bl = (float)rb[0], bhf = (float)rb[1];
                float cl = (float)rc[0], ch = (float)rc[1];
                float dl = (float)rd[0], dh = (float)rd[1];
                pa[2 * qq] = f2bf(al * al); pa[2 * qq + 1] = f2bf(ah * ah);
                pb[2 * qq] = f2bf(bl * bl); pb[2 * qq + 1] = f2bf(bhf * bhf);
                pc[2 * qq] = f2bf(cl * cl); pc[2 * qq + 1] = f2bf(ch * ch);
                pd[2 * qq] = f2bf(dl * dl); pd[2 * qq + 1] = f2bf(dh * dh);
            }
            *(ushort4*)&Sb[r0 * SSTR + c * 8 + 256 * j] = oa;
            *(ushort4*)&Sb[r0 * SSTR + c * 8 + 256 * j + 4] = ob;
            *(ushort4*)&Sb[r1 * SSTR + c * 8 + 256 * j] = oc;
            *(ushort4*)&Sb[r1 * SSTR + c * 8 + 256 * j + 4] = od;
        }
    }
    __syncthreads();

    // ---- Phase 3: PV from packed Vt ----
    const int i3 = w >> 2;
    const int fb = w & 3;
    const unsigned short* VtB = Vt + ((size_t)bh * 4 + fb) * 32 * 512 + lane * 8;
    const unsigned short* Prow = &Sb[(i3 * 16 + lr) * SSTR + qg * 8];
    f32x4 pacc = {};
#pragma unroll
    for (int s = 0; s < 32; ++s) {
        bf16x8 pa = *(const bf16x8*)&Prow[s * 32];
        bf16x8 vb = *(const bf16x8*)&VtB[s * 512];
        pacc = MFMA(pa, vb, pacc);
    }
#pragma unroll
    for (int r = 0; r < 4; ++r) {
        int m = b * L + qt * 32 + i3 * 16 + qg * 4 + r;
        int d = fb * 16 + lr;
        AO[(size_t)m * DM + h * DK + d] = f2bf(pacc[r]);
    }
}

// ---------------------------------------------------------------------------
// Out projection: out = AO(bf16) @ Wo^T(bf16), fp32 out.
// BM=64, BN=64, BK=64, 4 waves. grid (16,32)=512 blocks.
// ---------------------------------------------------------------------------
__global__ __launch_bounds__(256) void out_kernel(
    const unsigned short* __restrict__ A, const unsigned short* __restrict__ W,
    float* __restrict__ O)
{
    __shared__ unsigned short Ab[64][72];
    __shared__ unsigned short Bb[64][72];

    const int t = threadIdx.x;
    const int w = t >> 6, lane = t & 63, qg = lane >> 4, lr = lane & 15;
    const int wr = w >> 1, wc = w & 1;
    const int mbase = blockIdx.y * 64, nbase = blockIdx.x * 64;

    f32x4 acc[2][2] = {};

    for (int kt = 0; kt < 16; ++kt) {
        const int kb = kt * 64;
#pragma unroll
        for (int rr = 0; rr < 2; ++rr) {
            int f = t + 256 * rr;
            int row = f >> 3;
            int c8 = (f & 7) << 3;
            *(bf16x8*)&Ab[row][c8] = *(const bf16x8*)&A[(size_t)(mbase + row) * DM + kb + c8];
        }
#pragma unroll
        for (int rr = 0; rr < 2; ++rr) {
            int f = t + 256 * rr;
            int row = f >> 3;
            int c8 = (f & 7) << 3;
            *(bf16x8*)&Bb[row][c8] = *(const bf16x8*)&W[(size_t)(nbase + row) * DM + kb + c8];
        }
        __syncthreads();
#pragma unroll
        for (int ks = 0; ks < 2; ++ks) {
            const int k0 = ks * 32 + qg * 8;
            bf16x8 a[2], bfr[2];
#pragma unroll
            for (int i = 0; i < 2; ++i)
                a[i] = *(const bf16x8*)&Ab[wr * 32 + i * 16 + lr][k0];
#pragma unroll
            for (int j = 0; j < 2; ++j)
                bfr[j] = *(const bf16x8*)&Bb[wc * 32 + j * 16 + lr][k0];
#pragma unroll
            for (int i = 0; i < 2; ++i)
#pragma unroll
                for (int j = 0; j < 2; ++j)
                    acc[i][j] = MFMA(a[i], bfr[j], acc[i][j]);
        }
        __syncthreads();
    }

#pragma unroll
    for (int i = 0; i < 2; ++i)
#pragma unroll
        for (int j = 0; j < 2; ++j)
#pragma unroll
            for (int r = 0; r < 4; ++r) {
                int m = mbase + wr * 32 + i * 16 + qg * 4 + r;
                int n = nbase + wc * 32 + j * 16 + lr;
                O[(size_t)m * DM + n] = acc[i][j][r];
            }
}

extern "C" void kernel_launch(void* const* d_in, const int* in_sizes, int n_in,
                              void* d_out, int out_size, void* d_ws, size_t ws_size,
                              hipStream_t stream)
{
    const float* q  = (const float*)d_in[0];
    const float* k  = (const float*)d_in[1];
    const float* v  = (const float*)d_in[2];
    const int* mask = (const int*)d_in[3];
    const float* wq = (const float*)d_in[4];
    const float* wk = (const float*)d_in[5];
    const float* wv = (const float*)d_in[6];
    const float* wo = (const float*)d_in[7];

    char* wsb = (char*)d_ws;
    const size_t MB = (size_t)1 << 20;
    unsigned short* Qh  = (unsigned short*)(wsb + 0 * MB);
    unsigned short* Ql  = (unsigned short*)(wsb + 4 * MB);
    unsigned short* Kh  = (unsigned short*)(wsb + 8 * MB);
    unsigned short* Kl  = (unsigned short*)(wsb + 12 * MB);
    unsigned short* Vt  = (unsigned short*)(wsb + 16 * MB);
    unsigned short* AO  = (unsigned short*)(wsb + 20 * MB);
    unsigned short* Xqb = (unsigned short*)(wsb + 24 * MB);
    unsigned short* Xkb = (unsigned short*)(wsb + 28 * MB);
    unsigned short* Xvb = (unsigned short*)(wsb + 32 * MB);
    unsigned short* Wqb = (unsigned short*)(wsb + 36 * MB);
    unsigned short* Wkb = (unsigned short*)(wsb + 38 * MB);
    unsigned short* Wvb = (unsigned short*)(wsb + 40 * MB);
    unsigned short* Wob = (unsigned short*)(wsb + 42 * MB);
    unsigned short* Mp  = Xqb;   // 2 MB, written AFTER proj consumes Xqb

    convert_bf16<<<dim3(1024), 256, 0, stream>>>(q, k, v, wq, wk, wv, wo,
                                                 Xqb, Xkb, Xvb, Wqb, Wkb, Wvb, Wob);
    proj_kernel<<<dim3(16, 16, 3), 256, 0, stream>>>(Xqb, Xkb, Xvb, Wqb, Wkb, Wvb,
                                                     Qh, Ql, Kh, Kl, Vt);
    pack_mask<<<dim3(1024), 256, 0, stream>>>(mask, Mp);
    attn_kernel<<<dim3(32, 32), 512, 0, stream>>>(Qh, Ql, Kh, Kl, Vt, Mp, AO);
    out_kernel<<<dim3(16, 32), 256, 0, stream>>>(AO, Wob, (float*)d_out);
}

// Round 11
// 107.403 us; speedup vs baseline: 4.5318x; 1.0122x over previous
//
#include <hip/hip_runtime.h>

#define L 1024
#define DM 1024
#define NH 16
#define DK 64

typedef __attribute__((ext_vector_type(8))) short bf16x8;
typedef __attribute__((ext_vector_type(4))) float f32x4;
typedef _Float16 h2 __attribute__((ext_vector_type(2)));

#define MFMA(a, b, c) __builtin_amdgcn_mfma_f32_16x16x32_bf16(a, b, c, 0, 0, 0)

__device__ inline unsigned short f2bf(float f) {
    unsigned int u = __builtin_bit_cast(unsigned int, f);
    u += 0x7FFFu + ((u >> 16) & 1u);
    return (unsigned short)(u >> 16);
}
__device__ inline float bf2f(unsigned short h) {
    unsigned int u = ((unsigned int)h) << 16;
    return __builtin_bit_cast(float, u);
}
__device__ inline unsigned short f2h(float f) {
    return __builtin_bit_cast(unsigned short, (_Float16)f);
}
__device__ inline float h2f(unsigned short u) {
    return (float)__builtin_bit_cast(_Float16, u);
}

__device__ inline h2 h2splat(float v) {
    h2 r; r[0] = (_Float16)v; r[1] = (_Float16)v; return r;
}
__device__ inline h2 h2max(h2 a, h2 b) {
#if defined(__has_builtin)
#if __has_builtin(__builtin_elementwise_max)
    return __builtin_elementwise_max(a, b);
#else
    h2 r; r[0] = a[0] > b[0] ? a[0] : b[0]; r[1] = a[1] > b[1] ? a[1] : b[1]; return r;
#endif
#else
    h2 r; r[0] = a[0] > b[0] ? a[0] : b[0]; r[1] = a[1] > b[1] ? a[1] : b[1]; return r;
#endif
}

// f32-accumulating fp16 pair dot: a[0]*b[0] + a[1]*b[1] + c
__device__ inline float dot2acc(h2 a, h2 b, float c) {
#if defined(__has_builtin)
#if __has_builtin(__builtin_amdgcn_fdot2)
    return __builtin_amdgcn_fdot2(a, b, c, false);
#else
    return c + (float)a[0] * (float)b[0] + (float)a[1] * (float)b[1];
#endif
#else
    return c + (float)a[0] * (float)b[0] + (float)a[1] * (float)b[1];
#endif
}

// ---------------------------------------------------------------------------
// One-shot fp32 -> bf16 conversion of all GEMM inputs.
// ---------------------------------------------------------------------------
__global__ __launch_bounds__(256) void convert_bf16(
    const float* __restrict__ q, const float* __restrict__ k, const float* __restrict__ v,
    const float* __restrict__ wq, const float* __restrict__ wk,
    const float* __restrict__ wv, const float* __restrict__ wo,
    unsigned short* __restrict__ Xq, unsigned short* __restrict__ Xk,
    unsigned short* __restrict__ Xv, unsigned short* __restrict__ Wq,
    unsigned short* __restrict__ Wk, unsigned short* __restrict__ Wv,
    unsigned short* __restrict__ Wo)
{
    const size_t M2 = (size_t)1 << 21, M1 = (size_t)1 << 20;
    const size_t nchunks = (3 * M2 + 4 * M1) / 8;
    for (size_t c = (size_t)blockIdx.x * blockDim.x + threadIdx.x; c < nchunks;
         c += (size_t)gridDim.x * blockDim.x) {
        size_t e = c * 8;
        const float* src;
        unsigned short* dst;
        size_t off;
        if (e < 3 * M2) {
            size_t r = e / M2;
            off = e - r * M2;
            src = r == 0 ? q : (r == 1 ? k : v);
            dst = r == 0 ? Xq : (r == 1 ? Xk : Xv);
        } else {
            size_t e2 = e - 3 * M2;
            size_t r = e2 / M1;
            off = e2 - r * M1;
            src = r == 0 ? wq : (r == 1 ? wk : (r == 2 ? wv : wo));
            dst = r == 0 ? Wq : (r == 1 ? Wk : (r == 2 ? Wv : Wo));
        }
        float4 a = *(const float4*)&src[off];
        float4 b = *(const float4*)&src[off + 4];
        ushort4 o0, o1;
        o0.x = f2bf(a.x); o0.y = f2bf(a.y); o0.z = f2bf(a.z); o0.w = f2bf(a.w);
        o1.x = f2bf(b.x); o1.y = f2bf(b.y); o1.z = f2bf(b.z); o1.w = f2bf(b.w);
        *(ushort4*)&dst[off] = o0;
        *(ushort4*)&dst[off + 4] = o1;
    }
}

// ---------------------------------------------------------------------------
// Mask -> packed fp16 additive-bias fragments.
// ---------------------------------------------------------------------------
__global__ __launch_bounds__(256) void pack_mask(const int* __restrict__ mask,
                                                 unsigned short* __restrict__ Mp)
{
    int id = blockIdx.x * 256 + threadIdx.x;     // 0 .. 262143
    int lane = id & 63;
    int kblk = (id >> 6) & 63;
    int qtile = id >> 12;                        // 0..63
    int qabs = qtile * 16 + (lane & 15);
    int kcol = kblk * 16 + (lane >> 4) * 4;
    int4 m = *(const int4*)&mask[(size_t)qabs * L + kcol];
    unsigned short neg = f2h(-60000.0f);
    ushort4 o;
    o.x = (m.x == 0) ? neg : (unsigned short)0;
    o.y = (m.y == 0) ? neg : (unsigned short)0;
    o.z = (m.z == 0) ? neg : (unsigned short)0;
    o.w = (m.w == 0) ? neg : (unsigned short)0;
    *(ushort4*)&Mp[(size_t)id * 4] = o;
}

// ---------------------------------------------------------------------------
// Projections: Y = X @ W^T. Fragment-linear outputs.
//  z=0/1: Q/K hi+lo  [bh][tile(64)][ks(2)][lane(64)][8] -- LDS-repacked,
//         coalesced bf16x8 stores.
//  z=2:   V          [bh][fb(4)][s(32)][lane(64)][8]
// BM=128, BN=64, BK=64, 4 waves. grid 768 flat.
// XCD-locality remap: the 16 n-blocks sharing one A-tile (z,y group) run on
// the same XCD; per-XCD set = 6 A-tiles (1.5 MB) + 1-2 W (2-4 MB) ~ L2.
// ---------------------------------------------------------------------------
__global__ __launch_bounds__(256) void proj_kernel(
    const unsigned short* __restrict__ Xq, const unsigned short* __restrict__ Xk,
    const unsigned short* __restrict__ Xv, const unsigned short* __restrict__ Wq,
    const unsigned short* __restrict__ Wk, const unsigned short* __restrict__ Wv,
    unsigned short* __restrict__ Qh, unsigned short* __restrict__ Ql,
    unsigned short* __restrict__ Kh, unsigned short* __restrict__ Kl,
    unsigned short* __restrict__ Vt)
{
    // bijective remap lid -> (xcd, group g=(z,y), x)
    const int lid0 = blockIdx.x;          // 0..767
    const int xcd = lid0 & 7;
    const int jj = lid0 >> 3;             // 0..95
    const int g = xcd * 6 + (jj >> 4);    // 0..47
    const int xb = jj & 15;
    const int z = g >> 4;                 // 0..2
    const int yb = g & 15;

    const unsigned short* X = z == 0 ? Xq : (z == 1 ? Xk : Xv);
    const unsigned short* W = z == 0 ? Wq : (z == 1 ? Wk : Wv);

    __shared__ unsigned short Ab[128][72];
    __shared__ unsigned short Bb[64][72];

    const int t = threadIdx.x;
    const int w = t >> 6, lane = t & 63, qg = lane >> 4, lr = lane & 15;
    const int wr = w >> 1, wc = w & 1;
    const int mbase = yb * 128, nbase = xb * 64;

    f32x4 acc[4][2] = {};

    for (int kt = 0; kt < 16; ++kt) {
        const int kb = kt * 64;
#pragma unroll
        for (int rr = 0; rr < 4; ++rr) {
            int f = t + 256 * rr;
            int row = f >> 3;
            int c8 = (f & 7) << 3;
            *(bf16x8*)&Ab[row][c8] = *(const bf16x8*)&X[(size_t)(mbase + row) * DM + kb + c8];
        }
#pragma unroll
        for (int rr = 0; rr < 2; ++rr) {
            int f = t + 256 * rr;
            int row = f >> 3;
            int c8 = (f & 7) << 3;
            *(bf16x8*)&Bb[row][c8] = *(const bf16x8*)&W[(size_t)(nbase + row) * DM + kb + c8];
        }
        __syncthreads();
#pragma unroll
        for (int ks = 0; ks < 2; ++ks) {
            const int k0 = ks * 32 + qg * 8;
            bf16x8 a[4], bfr[2];
#pragma unroll
            for (int i = 0; i < 4; ++i)
                a[i] = *(const bf16x8*)&Ab[wr * 64 + i * 16 + lr][k0];
#pragma unroll
            for (int j = 0; j < 2; ++j)
                bfr[j] = *(const bf16x8*)&Bb[wc * 32 + j * 16 + lr][k0];
#pragma unroll
            for (int i = 0; i < 4; ++i)
#pragma unroll
                for (int j = 0; j < 2; ++j)
                    acc[i][j] = MFMA(a[i], bfr[j], acc[i][j]);
        }
        __syncthreads();
    }

    if (z < 2) {
        unsigned short* Oh = z ? Kh : Qh;
        unsigned short* Ol = z ? Kl : Ql;
        const int b = mbase >> 10, h = nbase >> 6;
        const int bh = b * NH + h;
        const int tile0 = (mbase & 1023) >> 4;
        const size_t plane = ((size_t)bh * 64 + tile0) * 1024;
        unsigned short* Lh = &Ab[0][0];   // 8192 halves = 16 KB repack buffer

        // pass 1: hi
#pragma unroll
        for (int i = 0; i < 4; ++i)
#pragma unroll
            for (int j = 0; j < 2; ++j) {
                int d = wc * 32 + j * 16 + lr;
                int ks = d >> 5, qg_p = (d >> 3) & 3, e = d & 7;
                int ti = wr * 4 + i;
#pragma unroll
                for (int r = 0; r < 4; ++r) {
                    int lane_p = qg_p * 16 + qg * 4 + r;
                    Lh[((ti * 2 + ks) * 64 + lane_p) * 8 + e] = f2bf(acc[i][j][r]);
                }
            }
        __syncthreads();
#pragma unroll
        for (int cch = 0; cch < 4; ++cch) {
            int f = cch * 2048 + t * 8;
            *(bf16x8*)&Oh[plane + f] = *(const bf16x8*)&Lh[f];
        }
        __syncthreads();
        // pass 2: lo
#pragma unroll
        for (int i = 0; i < 4; ++i)
#pragma unroll
            for (int j = 0; j < 2; ++j) {
                int d = wc * 32 + j * 16 + lr;
                int ks = d >> 5, qg_p = (d >> 3) & 3, e = d & 7;
                int ti = wr * 4 + i;
#pragma unroll
                for (int r = 0; r < 4; ++r) {
                    float vv = acc[i][j][r];
                    unsigned short hi_ = f2bf(vv);
                    int lane_p = qg_p * 16 + qg * 4 + r;
                    Lh[((ti * 2 + ks) * 64 + lane_p) * 8 + e] = f2bf(vv - bf2f(hi_));
                }
            }
        __syncthreads();
#pragma unroll
        for (int cch = 0; cch < 4; ++cch) {
            int f = cch * 2048 + t * 8;
            *(bf16x8*)&Ol[plane + f] = *(const bf16x8*)&Lh[f];
        }
    } else {
#pragma unroll
        for (int i = 0; i < 4; ++i)
#pragma unroll
            for (int j = 0; j < 2; ++j) {
                int n = nbase + wc * 32 + j * 16 + lr;
                int h = n >> 6, d = n & 63;
                int fb = d >> 4, lr2 = d & 15;
                int m0 = mbase + wr * 64 + i * 16 + qg * 4;
                int b = m0 >> 10, l0 = m0 & 1023;
                int s = l0 >> 5, qg2 = (l0 >> 3) & 3, e0 = l0 & 7;
                int bh = b * NH + h;
                size_t idx = (((size_t)bh * 4 + fb) * 32 + s) * 512 + qg2 * 128 + lr2 * 8 + e0;
                ushort4 o;
                o.x = f2bf(acc[i][j][0]); o.y = f2bf(acc[i][j][1]);
                o.z = f2bf(acc[i][j][2]); o.w = f2bf(acc[i][j][3]);
                *(ushort4*)&Vt[idx] = o;
            }
    }
}

// ---------------------------------------------------------------------------
// Fused attention. Block = (32 Q-rows, one bh). 512 thr, 8 waves. grid 1024.
// XCD-locality remap (validated r10: FETCH 56->21 GB). 3 bisect + 2 Newton.
// ---------------------------------------------------------------------------
#define SSTR 1048
__global__ __launch_bounds__(512, 4) void attn_kernel(
    const unsigned short* __restrict__ Qh, const unsigned short* __restrict__ Ql,
    const unsigned short* __restrict__ Kh, const unsigned short* __restrict__ Kl,
    const unsigned short* __restrict__ Vt, const unsigned short* __restrict__ Mp,
    unsigned short* __restrict__ AO)
{
    __shared__ unsigned short Sb[32 * SSTR];   // fp16 scores, then bf16 probs

    const int t = threadIdx.x;
    const int w = t >> 6, lane = t & 63, qg = lane >> 4, lr = lane & 15;
    // XCD-locality remap (bijective on [0,1024))
    const int lid = blockIdx.y * 32 + blockIdx.x;
    const int xcd = lid & 7;
    const int rest = lid >> 3;          // 0..127
    const int qt = rest & 31;
    const int bh = xcd * 4 + (rest >> 5);
    const int b = bh >> 4, h = bh & 15;
    const size_t plane = (size_t)bh << 16;

    // ---- Phase 1: transposed QK^T ----
    bf16x8 qh_[2][2], ql_[2][2];
#pragma unroll
    for (int i = 0; i < 2; ++i)
#pragma unroll
        for (int ks = 0; ks < 2; ++ks) {
            size_t qa = plane + (size_t)(qt * 2 + i) * 1024 + ks * 512 + lane * 8;
            qh_[i][ks] = *(const bf16x8*)&Qh[qa];
            ql_[i][ks] = *(const bf16x8*)&Ql[qa];
        }

#pragma unroll
    for (int j = 0; j < 8; ++j) {
        const int kblk = w * 8 + j;
        const size_t ka = plane + (size_t)kblk * 1024 + lane * 8;
        bf16x8 kh0 = *(const bf16x8*)&Kh[ka];
        bf16x8 kh1 = *(const bf16x8*)&Kh[ka + 512];
        bf16x8 kl0 = *(const bf16x8*)&Kl[ka];
        bf16x8 kl1 = *(const bf16x8*)&Kl[ka + 512];
#pragma unroll
        for (int i = 0; i < 2; ++i) {
            f32x4 acc = {};
            acc = MFMA(kh0, qh_[i][0], acc);
            acc = MFMA(kl0, qh_[i][0], acc);
            acc = MFMA(kh0, ql_[i][0], acc);
            acc = MFMA(kh1, qh_[i][1], acc);
            acc = MFMA(kl1, qh_[i][1], acc);
            acc = MFMA(kh1, ql_[i][1], acc);
            ushort4 mb = *(const ushort4*)&Mp[(((size_t)(qt * 2 + i) * 64 + kblk) * 64 + lane) * 4];
            float s0 = fmaf(acc[0], 0.0625f, h2f(mb.x));
            float s1 = fmaf(acc[1], 0.0625f, h2f(mb.y));
            float s2 = fmaf(acc[2], 0.0625f, h2f(mb.z));
            float s3 = fmaf(acc[3], 0.0625f, h2f(mb.w));
            ushort4 pk;
            pk.x = f2h(s0); pk.y = f2h(s1); pk.z = f2h(s2); pk.w = f2h(s3);
            *(ushort4*)&Sb[(i * 16 + lr) * SSTR + kblk * 16 + qg * 4] = pk;
        }
    }
    __syncthreads();

    // ---- Phase 2: entmax-1.5, packed fp16, two interleaved solves ----
    const int half_id = lane >> 5;
    const int c = lane & 31;
    const int r0 = w * 2 + half_id;
    const int r1 = 16 + r0;
    h2 x0[16], x1[16];
#pragma unroll
    for (int j = 0; j < 4; ++j) {
        uint4 u0 = *(const uint4*)&Sb[r0 * SSTR + c * 8 + 256 * j];
        uint4 u1 = *(const uint4*)&Sb[r1 * SSTR + c * 8 + 256 * j];
        const h2* p0 = (const h2*)&u0;
        const h2* p1 = (const h2*)&u1;
#pragma unroll
        for (int m = 0; m < 4; ++m) {
            x0[4 * j + m] = p0[m];
            x1[4 * j + m] = p1[m];
        }
    }

    h2 mp0 = x0[0], mp1 = x1[0];
#pragma unroll
    for (int i = 1; i < 16; ++i) {
        mp0 = h2max(mp0, x0[i]);
        mp1 = h2max(mp1, x1[i]);
    }
    float m0 = fmaxf((float)mp0[0], (float)mp0[1]);
    float m1 = fmaxf((float)mp1[0], (float)mp1[1]);
#pragma unroll
    for (int off = 1; off < 32; off <<= 1) {
        m0 = fmaxf(m0, __shfl_xor(m0, off));
        m1 = fmaxf(m1, __shfl_xor(m1, off));
    }
    {
        h2 m02 = h2splat(m0), m12 = h2splat(m1);
#pragma unroll
        for (int i = 0; i < 16; ++i) {
            x0[i] = x0[i] - m02;
            x1[i] = x1[i] - m12;
        }
    }

    const h2 zero2 = h2splat(0.0f);
    const h2 one2 = h2splat(1.0f);
    float lo0 = -1.0f, hi0 = 0.0f, lo1 = -1.0f, hi1 = 0.0f;
    for (int it = 0; it < 3; ++it) {
        float mid0 = 0.5f * (lo0 + hi0), mid1 = 0.5f * (lo1 + hi1);
        h2 mid02 = h2splat(mid0), mid12 = h2splat(mid1);
        float f0 = 0.0f, f1 = 0.0f;
#pragma unroll
        for (int i = 0; i < 16; ++i) {
            h2 a = h2max(x0[i] - mid02, zero2);
            h2 bq = h2max(x1[i] - mid12, zero2);
            f0 = dot2acc(a, a, f0);
            f1 = dot2acc(bq, bq, f1);
        }
#pragma unroll
        for (int off = 1; off < 32; off <<= 1) {
            f0 += __shfl_xor(f0, off);
            f1 += __shfl_xor(f1, off);
        }
        if (f0 >= 1.0f) lo0 = mid0; else hi0 = mid0;
        if (f1 >= 1.0f) lo1 = mid1; else hi1 = mid1;
    }
    float tau0 = lo0, tau1 = lo1;
    for (int it = 0; it < 2; ++it) {
        h2 t02 = h2splat(tau0), t12 = h2splat(tau1);
        float a1 = 0.0f, a2 = 0.0f, b1 = 0.0f, b2 = 0.0f;
#pragma unroll
        for (int i = 0; i < 16; ++i) {
            h2 a = h2max(x0[i] - t02, zero2);
            h2 bq = h2max(x1[i] - t12, zero2);
            a1 = dot2acc(a, one2, a1);
            a2 = dot2acc(a, a, a2);
            b1 = dot2acc(bq, one2, b1);
            b2 = dot2acc(bq, bq, b2);
        }
#pragma unroll
        for (int off = 1; off < 32; off <<= 1) {
            a1 += __shfl_xor(a1, off);
            a2 += __shfl_xor(a2, off);
            b1 += __shfl_xor(b1, off);
            b2 += __shfl_xor(b2, off);
        }
        tau0 += (a2 - 1.0f) / (2.0f * a1);
        tau1 += (b2 - 1.0f) / (2.0f * b1);
    }

    {
        h2 t02 = h2splat(tau0), t12 = h2splat(tau1);
#pragma unroll
        for (int j = 0; j < 4; ++j) {
            ushort4 oa, ob, oc, od;
            unsigned short* pa = (unsigned short*)&oa;
            unsigned short* pb = (unsigned short*)&ob;
            unsigned short* pc = (unsigned short*)&oc;
            unsigned short* pd = (unsigned short*)&od;
#pragma unroll
            for (int qq = 0; qq < 2; ++qq) {
                h2 ra = h2max(x0[4 * j + qq] - t02, zero2);
                h2 rb = h2max(x0[4 * j + 2 + qq] - t02, zero2);
                h2 rc = h2max(x1[4 * j + qq] - t12, zero2);
                h2 rd = h2max(x1[4 * j + 2 + qq] - t12, zero2);
                float al = (float)ra[0], ah = (float)ra[1];
                float bl = (float)rb[0], bhf = (float)rb[1];
                float cl = (float)rc[0], ch = (float)rc[1];
                float dl = (float)rd[0], dh = (float)rd[1];
                pa[2 * qq] = f2bf(al * al); pa[2 * qq + 1] = f2bf(ah * ah);
                pb[2 * qq] = f2bf(bl * bl); pb[2 * qq + 1] = f2bf(bhf * bhf);
                pc[2 * qq] = f2bf(cl * cl); pc[2 * qq + 1] = f2bf(ch * ch);
                pd[2 * qq] = f2bf(dl * dl); pd[2 * qq + 1] = f2bf(dh * dh);
            }
            *(ushort4*)&Sb[r0 * SSTR + c * 8 + 256 * j] = oa;
            *(ushort4*)&Sb[r0 * SSTR + c * 8 + 256 * j + 4] = ob;
            *(ushort4*)&Sb[r1 * SSTR + c * 8 + 256 * j] = oc;
            *(ushort4*)&Sb[r1 * SSTR + c * 8 + 256 * j + 4] = od;
        }
    }
    __syncthreads();

    // ---- Phase 3: PV from packed Vt ----
    const int i3 = w >> 2;
    const int fb = w & 3;
    const unsigned short* VtB = Vt + ((size_t)bh * 4 + fb) * 32 * 512 + lane * 8;
    const unsigned short* Prow = &Sb[(i3 * 16 + lr) * SSTR + qg * 8];
    f32x4 pacc = {};
#pragma unroll
    for (int s = 0; s < 32; ++s) {
        bf16x8 pa = *(const bf16x8*)&Prow[s * 32];
        bf16x8 vb = *(const bf16x8*)&VtB[s * 512];
        pacc = MFMA(pa, vb, pacc);
    }
#pragma unroll
    for (int r = 0; r < 4; ++r) {
        int m = b * L + qt * 32 + i3 * 16 + qg * 4 + r;
        int d = fb * 16 + lr;
        AO[(size_t)m * DM + h * DK + d] = f2bf(pacc[r]);
    }
}

// ---------------------------------------------------------------------------
// Out projection: out = AO(bf16) @ Wo^T(bf16), fp32 out.
// BM=64, BN=64, BK=64, 4 waves. grid 512 flat.
// XCD remap: 16 n-blocks sharing an A row-tile on one XCD
// (4 A-tiles x 128 KB + Wo 2 MB = 2.5 MB per XCD L2).
// ---------------------------------------------------------------------------
__global__ __launch_bounds__(256) void out_kernel(
    const unsigned short* __restrict__ A, const unsigned short* __restrict__ W,
    float* __restrict__ O)
{
    __shared__ unsigned short Ab[64][72];
    __shared__ unsigned short Bb[64][72];

    const int lid0 = blockIdx.x;        // 0..511
    const int xcd = lid0 & 7;
    const int jj = lid0 >> 3;           // 0..63
    const int yb = xcd * 4 + (jj & 3);  // 0..31
    const int xb = jj >> 2;             // 0..15

    const int t = threadIdx.x;
    const int w = t >> 6, lane = t & 63, qg = lane >> 4, lr = lane & 15;
    const int wr = w >> 1, wc = w & 1;
    const int mbase = yb * 64, nbase = xb * 64;

    f32x4 acc[2][2] = {};

    for (int kt = 0; kt < 16; ++kt) {
        const int kb = kt * 64;
#pragma unroll
        for (int rr = 0; rr < 2; ++rr) {
            int f = t + 256 * rr;
            int row = f >> 3;
            int c8 = (f & 7) << 3;
            *(bf16x8*)&Ab[row][c8] = *(const bf16x8*)&A[(size_t)(mbase + row) * DM + kb + c8];
        }
#pragma unroll
        for (int rr = 0; rr < 2; ++rr) {
            int f = t + 256 * rr;
            int row = f >> 3;
            int c8 = (f & 7) << 3;
            *(bf16x8*)&Bb[row][c8] = *(const bf16x8*)&W[(size_t)(nbase + row) * DM + kb + c8];
        }
        __syncthreads();
#pragma unroll
        for (int ks = 0; ks < 2; ++ks) {
            const int k0 = ks * 32 + qg * 8;
            bf16x8 a[2], bfr[2];
#pragma unroll
            for (int i = 0; i < 2; ++i)
                a[i] = *(const bf16x8*)&Ab[wr * 32 + i * 16 + lr][k0];
#pragma unroll
            for (int j = 0; j < 2; ++j)
                bfr[j] = *(const bf16x8*)&Bb[wc * 32 + j * 16 + lr][k0];
#pragma unroll
            for (int i = 0; i < 2; ++i)
#pragma unroll
                for (int j = 0; j < 2; ++j)
                    acc[i][j] = MFMA(a[i], bfr[j], acc[i][j]);
        }
        __syncthreads();
    }

#pragma unroll
    for (int i = 0; i < 2; ++i)
#pragma unroll
        for (int j = 0; j < 2; ++j)
#pragma unroll
            for (int r = 0; r < 4; ++r) {
                int m = mbase + wr * 32 + i * 16 + qg * 4 + r;
                int n = nbase + wc * 32 + j * 16 + lr;
                O[(size_t)m * DM + n] = acc[i][j][r];
            }
}

extern "C" void kernel_launch(void* const* d_in, const int* in_sizes, int n_in,
                              void* d_out, int out_size, void* d_ws, size_t ws_size,
                              hipStream_t stream)
{
    const float* q  = (const float*)d_in[0];
    const float* k  = (const float*)d_in[1];
    const float* v  = (const float*)d_in[2];
    const int* mask = (const int*)d_in[3];
    const float* wq = (const float*)d_in[4];
    const float* wk = (const float*)d_in[5];
    const float* wv = (const float*)d_in[6];
    const float* wo = (const float*)d_in[7];

    char* wsb = (char*)d_ws;
    const size_t MB = (size_t)1 << 20;
    unsigned short* Qh  = (unsigned short*)(wsb + 0 * MB);
    unsigned short* Ql  = (unsigned short*)(wsb + 4 * MB);
    unsigned short* Kh  = (unsigned short*)(wsb + 8 * MB);
    unsigned short* Kl  = (unsigned short*)(wsb + 12 * MB);
    unsigned short* Vt  = (unsigned short*)(wsb + 16 * MB);
    unsigned short* AO  = (unsigned short*)(wsb + 20 * MB);
    unsigned short* Xqb = (unsigned short*)(wsb + 24 * MB);
    unsigned short* Xkb = (unsigned short*)(wsb + 28 * MB);
    unsigned short* Xvb = (unsigned short*)(wsb + 32 * MB);
    unsigned short* Wqb = (unsigned short*)(wsb + 36 * MB);
    unsigned short* Wkb = (unsigned short*)(wsb + 38 * MB);
    unsigned short* Wvb = (unsigned short*)(wsb + 40 * MB);
    unsigned short* Wob = (unsigned short*)(wsb + 42 * MB);
    unsigned short* Mp  = Xqb;   // 2 MB, written AFTER proj consumes Xqb

    convert_bf16<<<dim3(1024), 256, 0, stream>>>(q, k, v, wq, wk, wv, wo,
                                                 Xqb, Xkb, Xvb, Wqb, Wkb, Wvb, Wob);
    proj_kernel<<<dim3(768), 256, 0, stream>>>(Xqb, Xkb, Xvb, Wqb, Wkb, Wvb,
                                               Qh, Ql, Kh, Kl, Vt);
    pack_mask<<<dim3(1024), 256, 0, stream>>>(mask, Mp);
    attn_kernel<<<dim3(32, 32), 512, 0, stream>>>(Qh, Ql, Kh, Kl, Vt, Mp, AO);
    out_kernel<<<dim3(512), 256, 0, stream>>>(AO, Wob, (float*)d_out);
}

// Round 12
// 96.675 us; speedup vs baseline: 5.0347x; 1.1110x over previous
//
#include <hip/hip_runtime.h>

#define L 1024
#define DM 1024
#define NH 16
#define DK 64

typedef __attribute__((ext_vector_type(8))) short bf16x8;
typedef __attribute__((ext_vector_type(4))) float f32x4;
typedef _Float16 h2 __attribute__((ext_vector_type(2)));
typedef _Float16 f16x8 __attribute__((ext_vector_type(8)));

#define MFMA(a, b, c) __builtin_amdgcn_mfma_f32_16x16x32_bf16(a, b, c, 0, 0, 0)
#define MFMA16(a, b, c) __builtin_amdgcn_mfma_f32_16x16x32_f16(a, b, c, 0, 0, 0)

__device__ inline unsigned short f2bf(float f) {
    unsigned int u = __builtin_bit_cast(unsigned int, f);
    u += 0x7FFFu + ((u >> 16) & 1u);
    return (unsigned short)(u >> 16);
}
__device__ inline float bf2f(unsigned short h) {
    unsigned int u = ((unsigned int)h) << 16;
    return __builtin_bit_cast(float, u);
}
__device__ inline unsigned short f2h(float f) {
    return __builtin_bit_cast(unsigned short, (_Float16)f);
}
__device__ inline float h2f(unsigned short u) {
    return (float)__builtin_bit_cast(_Float16, u);
}

__device__ inline h2 h2splat(float v) {
    h2 r; r[0] = (_Float16)v; r[1] = (_Float16)v; return r;
}
__device__ inline h2 h2max(h2 a, h2 b) {
#if defined(__has_builtin)
#if __has_builtin(__builtin_elementwise_max)
    return __builtin_elementwise_max(a, b);
#else
    h2 r; r[0] = a[0] > b[0] ? a[0] : b[0]; r[1] = a[1] > b[1] ? a[1] : b[1]; return r;
#endif
#else
    h2 r; r[0] = a[0] > b[0] ? a[0] : b[0]; r[1] = a[1] > b[1] ? a[1] : b[1]; return r;
#endif
}

// f32-accumulating fp16 pair dot: a[0]*b[0] + a[1]*b[1] + c
__device__ inline float dot2acc(h2 a, h2 b, float c) {
#if defined(__has_builtin)
#if __has_builtin(__builtin_amdgcn_fdot2)
    return __builtin_amdgcn_fdot2(a, b, c, false);
#else
    return c + (float)a[0] * (float)b[0] + (float)a[1] * (float)b[1];
#endif
#else
    return c + (float)a[0] * (float)b[0] + (float)a[1] * (float)b[1];
#endif
}

// ---------------------------------------------------------------------------
// Prep: fp32 -> bf16 conversion of GEMM inputs + mask -> fp16 bias fragments.
// grid 1024 x 256: mask fragment id = global thread id (exactly 262144);
// conversion via grid-stride loop.
// ---------------------------------------------------------------------------
__global__ __launch_bounds__(256) void prep_kernel(
    const float* __restrict__ q, const float* __restrict__ k, const float* __restrict__ v,
    const float* __restrict__ wq, const float* __restrict__ wk,
    const float* __restrict__ wv, const float* __restrict__ wo,
    const int* __restrict__ mask,
    unsigned short* __restrict__ Xq, unsigned short* __restrict__ Xk,
    unsigned short* __restrict__ Xv, unsigned short* __restrict__ Wq,
    unsigned short* __restrict__ Wk, unsigned short* __restrict__ Wv,
    unsigned short* __restrict__ Wo, unsigned short* __restrict__ Mp)
{
    const int id = blockIdx.x * 256 + threadIdx.x;     // 0 .. 262143
    {   // mask packing: Mp[qtile][kblk][lane][4]
        int lane = id & 63;
        int kblk = (id >> 6) & 63;
        int qtile = id >> 12;
        int qabs = qtile * 16 + (lane & 15);
        int kcol = kblk * 16 + (lane >> 4) * 4;
        int4 m = *(const int4*)&mask[(size_t)qabs * L + kcol];
        unsigned short neg = f2h(-60000.0f);
        ushort4 o;
        o.x = (m.x == 0) ? neg : (unsigned short)0;
        o.y = (m.y == 0) ? neg : (unsigned short)0;
        o.z = (m.z == 0) ? neg : (unsigned short)0;
        o.w = (m.w == 0) ? neg : (unsigned short)0;
        *(ushort4*)&Mp[(size_t)id * 4] = o;
    }

    const size_t M2 = (size_t)1 << 21, M1 = (size_t)1 << 20;
    const size_t nchunks = (3 * M2 + 4 * M1) / 8;
    const size_t stride = (size_t)gridDim.x * blockDim.x;
    for (size_t c = (size_t)id; c < nchunks; c += stride) {
        size_t e = c * 8;
        const float* src;
        unsigned short* dst;
        size_t off;
        if (e < 3 * M2) {
            size_t r = e / M2;
            off = e - r * M2;
            src = r == 0 ? q : (r == 1 ? k : v);
            dst = r == 0 ? Xq : (r == 1 ? Xk : Xv);
        } else {
            size_t e2 = e - 3 * M2;
            size_t r = e2 / M1;
            off = e2 - r * M1;
            src = r == 0 ? wq : (r == 1 ? wk : (r == 2 ? wv : wo));
            dst = r == 0 ? Wq : (r == 1 ? Wk : (r == 2 ? Wv : Wo));
        }
        float4 a = *(const float4*)&src[off];
        float4 b = *(const float4*)&src[off + 4];
        ushort4 o0, o1;
        o0.x = f2bf(a.x); o0.y = f2bf(a.y); o0.z = f2bf(a.z); o0.w = f2bf(a.w);
        o1.x = f2bf(b.x); o1.y = f2bf(b.y); o1.z = f2bf(b.z); o1.w = f2bf(b.w);
        *(ushort4*)&dst[off] = o0;
        *(ushort4*)&dst[off + 4] = o1;
    }
}

// ---------------------------------------------------------------------------
// Projections: Y = X @ W^T. Fragment-linear outputs.
//  z=0/1: Q/K as SINGLE fp16 plane [bh][tile(64)][ks(2)][lane(64)][8]
//         (fp16 rel err 5e-4 << the 0.006 error already in q/k from the
//          bf16-input projection GEMM itself; LDS-repacked, coalesced).
//  z=2:   V bf16 [bh][fb(4)][s(32)][lane(64)][8]
// BM=128, BN=64, BK=64, 4 waves. grid 768 flat, XCD-locality remap.
// ---------------------------------------------------------------------------
__global__ __launch_bounds__(256) void proj_kernel(
    const unsigned short* __restrict__ Xq, const unsigned short* __restrict__ Xk,
    const unsigned short* __restrict__ Xv, const unsigned short* __restrict__ Wq,
    const unsigned short* __restrict__ Wk, const unsigned short* __restrict__ Wv,
    unsigned short* __restrict__ Qf, unsigned short* __restrict__ Kf,
    unsigned short* __restrict__ Vt)
{
    const int lid0 = blockIdx.x;          // 0..767
    const int xcd = lid0 & 7;
    const int jj = lid0 >> 3;             // 0..95
    const int g = xcd * 6 + (jj >> 4);    // 0..47
    const int xb = jj & 15;
    const int z = g >> 4;                 // 0..2
    const int yb = g & 15;

    const unsigned short* X = z == 0 ? Xq : (z == 1 ? Xk : Xv);
    const unsigned short* W = z == 0 ? Wq : (z == 1 ? Wk : Wv);

    __shared__ unsigned short Ab[128][72];
    __shared__ unsigned short Bb[64][72];

    const int t = threadIdx.x;
    const int w = t >> 6, lane = t & 63, qg = lane >> 4, lr = lane & 15;
    const int wr = w >> 1, wc = w & 1;
    const int mbase = yb * 128, nbase = xb * 64;

    f32x4 acc[4][2] = {};

    for (int kt = 0; kt < 16; ++kt) {
        const int kb = kt * 64;
#pragma unroll
        for (int rr = 0; rr < 4; ++rr) {
            int f = t + 256 * rr;
            int row = f >> 3;
            int c8 = (f & 7) << 3;
            *(bf16x8*)&Ab[row][c8] = *(const bf16x8*)&X[(size_t)(mbase + row) * DM + kb + c8];
        }
#pragma unroll
        for (int rr = 0; rr < 2; ++rr) {
            int f = t + 256 * rr;
            int row = f >> 3;
            int c8 = (f & 7) << 3;
            *(bf16x8*)&Bb[row][c8] = *(const bf16x8*)&W[(size_t)(nbase + row) * DM + kb + c8];
        }
        __syncthreads();
#pragma unroll
        for (int ks = 0; ks < 2; ++ks) {
            const int k0 = ks * 32 + qg * 8;
            bf16x8 a[4], bfr[2];
#pragma unroll
            for (int i = 0; i < 4; ++i)
                a[i] = *(const bf16x8*)&Ab[wr * 64 + i * 16 + lr][k0];
#pragma unroll
            for (int j = 0; j < 2; ++j)
                bfr[j] = *(const bf16x8*)&Bb[wc * 32 + j * 16 + lr][k0];
#pragma unroll
            for (int i = 0; i < 4; ++i)
#pragma unroll
                for (int j = 0; j < 2; ++j)
                    acc[i][j] = MFMA(a[i], bfr[j], acc[i][j]);
        }
        __syncthreads();
    }

    if (z < 2) {
        unsigned short* Of = z ? Kf : Qf;
        const int b = mbase >> 10, h = nbase >> 6;
        const int bh = b * NH + h;
        const int tile0 = (mbase & 1023) >> 4;
        const size_t plane = ((size_t)bh * 64 + tile0) * 1024;
        unsigned short* Lh = &Ab[0][0];   // 8192 halves = 16 KB repack buffer

#pragma unroll
        for (int i = 0; i < 4; ++i)
#pragma unroll
            for (int j = 0; j < 2; ++j) {
                int d = wc * 32 + j * 16 + lr;
                int ks = d >> 5, qg_p = (d >> 3) & 3, e = d & 7;
                int ti = wr * 4 + i;
#pragma unroll
                for (int r = 0; r < 4; ++r) {
                    int lane_p = qg_p * 16 + qg * 4 + r;
                    Lh[((ti * 2 + ks) * 64 + lane_p) * 8 + e] = f2h(acc[i][j][r]);
                }
            }
        __syncthreads();
#pragma unroll
        for (int cch = 0; cch < 4; ++cch) {
            int f = cch * 2048 + t * 8;
            *(bf16x8*)&Of[plane + f] = *(const bf16x8*)&Lh[f];
        }
    } else {
#pragma unroll
        for (int i = 0; i < 4; ++i)
#pragma unroll
            for (int j = 0; j < 2; ++j) {
                int n = nbase + wc * 32 + j * 16 + lr;
                int h = n >> 6, d = n & 63;
                int fb = d >> 4, lr2 = d & 15;
                int m0 = mbase + wr * 64 + i * 16 + qg * 4;
                int b = m0 >> 10, l0 = m0 & 1023;
                int s = l0 >> 5, qg2 = (l0 >> 3) & 3, e0 = l0 & 7;
                int bh = b * NH + h;
                size_t idx = (((size_t)bh * 4 + fb) * 32 + s) * 512 + qg2 * 128 + lr2 * 8 + e0;
                ushort4 o;
                o.x = f2bf(acc[i][j][0]); o.y = f2bf(acc[i][j][1]);
                o.z = f2bf(acc[i][j][2]); o.w = f2bf(acc[i][j][3]);
                *(ushort4*)&Vt[idx] = o;
            }
    }
}

// ---------------------------------------------------------------------------
// Fused attention. Block = (32 Q-rows, one bh). 512 thr, 8 waves. grid 1024.
// Q/K are fp16 single planes -> phase 1 is 2 f16-MFMA per (j,i) (was 6 bf16).
// XCD-locality remap (r10: FETCH 56->21 GB). Entmax 3 bisect + 2 Newton.
// ---------------------------------------------------------------------------
#define SSTR 1048
__global__ __launch_bounds__(512, 4) void attn_kernel(
    const unsigned short* __restrict__ Qf, const unsigned short* __restrict__ Kf,
    const unsigned short* __restrict__ Vt, const unsigned short* __restrict__ Mp,
    unsigned short* __restrict__ AO)
{
    __shared__ unsigned short Sb[32 * SSTR];   // fp16 scores, then bf16 probs

    const int t = threadIdx.x;
    const int w = t >> 6, lane = t & 63, qg = lane >> 4, lr = lane & 15;
    const int lid = blockIdx.y * 32 + blockIdx.x;
    const int xcd = lid & 7;
    const int rest = lid >> 3;
    const int qt = rest & 31;
    const int bh = xcd * 4 + (rest >> 5);
    const int b = bh >> 4, h = bh & 15;
    const size_t plane = (size_t)bh << 16;

    // ---- Phase 1: transposed QK^T (fp16) ----
    f16x8 qf_[2][2];
#pragma unroll
    for (int i = 0; i < 2; ++i)
#pragma unroll
        for (int ks = 0; ks < 2; ++ks) {
            size_t qa = plane + (size_t)(qt * 2 + i) * 1024 + ks * 512 + lane * 8;
            qf_[i][ks] = *(const f16x8*)&Qf[qa];
        }

#pragma unroll
    for (int j = 0; j < 8; ++j) {
        const int kblk = w * 8 + j;
        const size_t ka = plane + (size_t)kblk * 1024 + lane * 8;
        f16x8 kf0 = *(const f16x8*)&Kf[ka];
        f16x8 kf1 = *(const f16x8*)&Kf[ka + 512];
#pragma unroll
        for (int i = 0; i < 2; ++i) {
            f32x4 acc = {};
            acc = MFMA16(kf0, qf_[i][0], acc);
            acc = MFMA16(kf1, qf_[i][1], acc);
            ushort4 mb = *(const ushort4*)&Mp[(((size_t)(qt * 2 + i) * 64 + kblk) * 64 + lane) * 4];
            float s0 = fmaf(acc[0], 0.0625f, h2f(mb.x));
            float s1 = fmaf(acc[1], 0.0625f, h2f(mb.y));
            float s2 = fmaf(acc[2], 0.0625f, h2f(mb.z));
            float s3 = fmaf(acc[3], 0.0625f, h2f(mb.w));
            ushort4 pk;
            pk.x = f2h(s0); pk.y = f2h(s1); pk.z = f2h(s2); pk.w = f2h(s3);
            *(ushort4*)&Sb[(i * 16 + lr) * SSTR + kblk * 16 + qg * 4] = pk;
        }
    }
    __syncthreads();

    // ---- Phase 2: entmax-1.5, packed fp16, two interleaved solves ----
    const int half_id = lane >> 5;
    const int c = lane & 31;
    const int r0 = w * 2 + half_id;
    const int r1 = 16 + r0;
    h2 x0[16], x1[16];
#pragma unroll
    for (int j = 0; j < 4; ++j) {
        uint4 u0 = *(const uint4*)&Sb[r0 * SSTR + c * 8 + 256 * j];
        uint4 u1 = *(const uint4*)&Sb[r1 * SSTR + c * 8 + 256 * j];
        const h2* p0 = (const h2*)&u0;
        const h2* p1 = (const h2*)&u1;
#pragma unroll
        for (int m = 0; m < 4; ++m) {
            x0[4 * j + m] = p0[m];
            x1[4 * j + m] = p1[m];
        }
    }

    h2 mp0 = x0[0], mp1 = x1[0];
#pragma unroll
    for (int i = 1; i < 16; ++i) {
        mp0 = h2max(mp0, x0[i]);
        mp1 = h2max(mp1, x1[i]);
    }
    float m0 = fmaxf((float)mp0[0], (float)mp0[1]);
    float m1 = fmaxf((float)mp1[0], (float)mp1[1]);
#pragma unroll
    for (int off = 1; off < 32; off <<= 1) {
        m0 = fmaxf(m0, __shfl_xor(m0, off));
        m1 = fmaxf(m1, __shfl_xor(m1, off));
    }
    {
        h2 m02 = h2splat(m0), m12 = h2splat(m1);
#pragma unroll
        for (int i = 0; i < 16; ++i) {
            x0[i] = x0[i] - m02;
            x1[i] = x1[i] - m12;
        }
    }

    const h2 zero2 = h2splat(0.0f);
    const h2 one2 = h2splat(1.0f);
    float lo0 = -1.0f, hi0 = 0.0f, lo1 = -1.0f, hi1 = 0.0f;
    for (int it = 0; it < 3; ++it) {
        float mid0 = 0.5f * (lo0 + hi0), mid1 = 0.5f * (lo1 + hi1);
        h2 mid02 = h2splat(mid0), mid12 = h2splat(mid1);
        float f0 = 0.0f, f1 = 0.0f;
#pragma unroll
        for (int i = 0; i < 16; ++i) {
            h2 a = h2max(x0[i] - mid02, zero2);
            h2 bq = h2max(x1[i] - mid12, zero2);
            f0 = dot2acc(a, a, f0);
            f1 = dot2acc(bq, bq, f1);
        }
#pragma unroll
        for (int off = 1; off < 32; off <<= 1) {
            f0 += __shfl_xor(f0, off);
            f1 += __shfl_xor(f1, off);
        }
        if (f0 >= 1.0f) lo0 = mid0; else hi0 = mid0;
        if (f1 >= 1.0f) lo1 = mid1; else hi1 = mid1;
    }
    float tau0 = lo0, tau1 = lo1;
    for (int it = 0; it < 2; ++it) {
        h2 t02 = h2splat(tau0), t12 = h2splat(tau1);
        float a1 = 0.0f, a2 = 0.0f, b1 = 0.0f, b2 = 0.0f;
#pragma unroll
        for (int i = 0; i < 16; ++i) {
            h2 a = h2max(x0[i] - t02, zero2);
            h2 bq = h2max(x1[i] - t12, zero2);
            a1 = dot2acc(a, one2, a1);
            a2 = dot2acc(a, a, a2);
            b1 = dot2acc(bq, one2, b1);
            b2 = dot2acc(bq, bq, b2);
        }
#pragma unroll
        for (int off = 1; off < 32; off <<= 1) {
            a1 += __shfl_xor(a1, off);
            a2 += __shfl_xor(a2, off);
            b1 += __shfl_xor(b1, off);
            b2 += __shfl_xor(b2, off);
        }
        tau0 += (a2 - 1.0f) / (2.0f * a1);
        tau1 += (b2 - 1.0f) / (2.0f * b1);
    }

    {
        h2 t02 = h2splat(tau0), t12 = h2splat(tau1);
#pragma unroll
        for (int j = 0; j < 4; ++j) {
            ushort4 oa, ob, oc, od;
            unsigned short* pa = (unsigned short*)&oa;
            unsigned short* pb = (unsigned short*)&ob;
            unsigned short* pc = (unsigned short*)&oc;
            unsigned short* pd = (unsigned short*)&od;
#pragma unroll
            for (int qq = 0; qq < 2; ++qq) {
                h2 ra = h2max(x0[4 * j + qq] - t02, zero2);
                h2 rb = h2max(x0[4 * j + 2 + qq] - t02, zero2);
                h2 rc = h2max(x1[4 * j + qq] - t12, zero2);
                h2 rd = h2max(x1[4 * j + 2 + qq] - t12, zero2);
                float al = (float)ra[0], ah = (float)ra[1];
                float bl = (float)rb[0], bhf = (float)rb[1];
                float cl = (float)rc[0], ch = (float)rc[1];
                float dl = (float)rd[0], dh = (float)rd[1];
                pa[2 * qq] = f2bf(al * al); pa[2 * qq + 1] = f2bf(ah * ah);
                pb[2 * qq] = f2bf(bl * bl); pb[2 * qq + 1] = f2bf(bhf * bhf);
                pc[2 * qq] = f2bf(cl * cl); pc[2 * qq + 1] = f2bf(ch * ch);
                pd[2 * qq] = f2bf(dl * dl); pd[2 * qq + 1] = f2bf(dh * dh);
            }
            *(ushort4*)&Sb[r0 * SSTR + c * 8 + 256 * j] = oa;
            *(ushort4*)&Sb[r0 * SSTR + c * 8 + 256 * j + 4] = ob;
            *(ushort4*)&Sb[r1 * SSTR + c * 8 + 256 * j] = oc;
            *(ushort4*)&Sb[r1 * SSTR + c * 8 + 256 * j + 4] = od;
        }
    }
    __syncthreads();

    // ---- Phase 3: PV from packed Vt (bf16) ----
    const int i3 = w >> 2;
    const int fb = w & 3;
    const unsigned short* VtB = Vt + ((size_t)bh * 4 + fb) * 32 * 512 + lane * 8;
    const unsigned short* Prow = &Sb[(i3 * 16 + lr) * SSTR + qg * 8];
    f32x4 pacc = {};
#pragma unroll
    for (int s = 0; s < 32; ++s) {
        bf16x8 pa = *(const bf16x8*)&Prow[s * 32];
        bf16x8 vb = *(const bf16x8*)&VtB[s * 512];
        pacc = MFMA(pa, vb, pacc);
    }
#pragma unroll
    for (int r = 0; r < 4; ++r) {
        int m = b * L + qt * 32 + i3 * 16 + qg * 4 + r;
        int d = fb * 16 + lr;
        AO[(size_t)m * DM + h * DK + d] = f2bf(pacc[r]);
    }
}

// ---------------------------------------------------------------------------
// Out projection: out = AO(bf16) @ Wo^T(bf16), fp32 out.
// BM=64, BN=64, BK=64, 4 waves. grid 512 flat, XCD remap.
// ---------------------------------------------------------------------------
__global__ __launch_bounds__(256) void out_kernel(
    const unsigned short* __restrict__ A, const unsigned short* __restrict__ W,
    float* __restrict__ O)
{
    __shared__ unsigned short Ab[64][72];
    __shared__ unsigned short Bb[64][72];

    const int lid0 = blockIdx.x;        // 0..511
    const int xcd = lid0 & 7;
    const int jj = lid0 >> 3;           // 0..63
    const int yb = xcd * 4 + (jj & 3);  // 0..31
    const int xb = jj >> 2;             // 0..15

    const int t = threadIdx.x;
    const int w = t >> 6, lane = t & 63, qg = lane >> 4, lr = lane & 15;
    const int wr = w >> 1, wc = w & 1;
    const int mbase = yb * 64, nbase = xb * 64;

    f32x4 acc[2][2] = {};

    for (int kt = 0; kt < 16; ++kt) {
        const int kb = kt * 64;
#pragma unroll
        for (int rr = 0; rr < 2; ++rr) {
            int f = t + 256 * rr;
            int row = f >> 3;
            int c8 = (f & 7) << 3;
            *(bf16x8*)&Ab[row][c8] = *(const bf16x8*)&A[(size_t)(mbase + row) * DM + kb + c8];
        }
#pragma unroll
        for (int rr = 0; rr < 2; ++rr) {
            int f = t + 256 * rr;
            int row = f >> 3;
            int c8 = (f & 7) << 3;
            *(bf16x8*)&Bb[row][c8] = *(const bf16x8*)&W[(size_t)(nbase + row) * DM + kb + c8];
        }
        __syncthreads();
#pragma unroll
        for (int ks = 0; ks < 2; ++ks) {
            const int k0 = ks * 32 + qg * 8;
            bf16x8 a[2], bfr[2];
#pragma unroll
            for (int i = 0; i < 2; ++i)
                a[i] = *(const bf16x8*)&Ab[wr * 32 + i * 16 + lr][k0];
#pragma unroll
            for (int j = 0; j < 2; ++j)
                bfr[j] = *(const bf16x8*)&Bb[wc * 32 + j * 16 + lr][k0];
#pragma unroll
            for (int i = 0; i < 2; ++i)
#pragma unroll
                for (int j = 0; j < 2; ++j)
                    acc[i][j] = MFMA(a[i], bfr[j], acc[i][j]);
        }
        __syncthreads();
    }

#pragma unroll
    for (int i = 0; i < 2; ++i)
#pragma unroll
        for (int j = 0; j < 2; ++j)
#pragma unroll
            for (int r = 0; r < 4; ++r) {
                int m = mbase + wr * 32 + i * 16 + qg * 4 + r;
                int n = nbase + wc * 32 + j * 16 + lr;
                O[(size_t)m * DM + n] = acc[i][j][r];
            }
}

extern "C" void kernel_launch(void* const* d_in, const int* in_sizes, int n_in,
                              void* d_out, int out_size, void* d_ws, size_t ws_size,
                              hipStream_t stream)
{
    const float* q  = (const float*)d_in[0];
    const float* k  = (const float*)d_in[1];
    const float* v  = (const float*)d_in[2];
    const int* mask = (const int*)d_in[3];
    const float* wq = (const float*)d_in[4];
    const float* wk = (const float*)d_in[5];
    const float* wv = (const float*)d_in[6];
    const float* wo = (const float*)d_in[7];

    char* wsb = (char*)d_ws;
    const size_t MB = (size_t)1 << 20;
    unsigned short* Qf  = (unsigned short*)(wsb + 0 * MB);
    unsigned short* Kf  = (unsigned short*)(wsb + 4 * MB);
    unsigned short* Vt  = (unsigned short*)(wsb + 8 * MB);
    unsigned short* AO  = (unsigned short*)(wsb + 12 * MB);
    unsigned short* Xqb = (unsigned short*)(wsb + 16 * MB);
    unsigned short* Xkb = (unsigned short*)(wsb + 20 * MB);
    unsigned short* Xvb = (unsigned short*)(wsb + 24 * MB);
    unsigned short* Wqb = (unsigned short*)(wsb + 28 * MB);
    unsigned short* Wkb = (unsigned short*)(wsb + 30 * MB);
    unsigned short* Wvb = (unsigned short*)(wsb + 32 * MB);
    unsigned short* Wob = (unsigned short*)(wsb + 34 * MB);
    unsigned short* Mp  = (unsigned short*)(wsb + 36 * MB);

    prep_kernel<<<dim3(1024), 256, 0, stream>>>(q, k, v, wq, wk, wv, wo, mask,
                                                Xqb, Xkb, Xvb, Wqb, Wkb, Wvb, Wob, Mp);
    proj_kernel<<<dim3(768), 256, 0, stream>>>(Xqb, Xkb, Xvb, Wqb, Wkb, Wvb,
                                               Qf, Kf, Vt);
    attn_kernel<<<dim3(32, 32), 512, 0, stream>>>(Qf, Kf, Vt, Mp, AO);
    out_kernel<<<dim3(512), 256, 0, stream>>>(AO, Wob, (float*)d_out);
}